// Round 2
// baseline (18352.327 us; speedup 1.0000x reference)
//
#include <hip/hip_runtime.h>
#include <hip/hip_bf16.h>
#include <math.h>

#define DEV __device__ __forceinline__

DEV float sigmoidf_(float x) { return 1.f / (1.f + __expf(-x)); }

// ---------------- conv stem: (16,1,128,2048) -> (16,32,64,1024), 3x3 s2 p1 ----
__global__ __launch_bounds__(256) void conv_stem(const float* __restrict__ x,
    const float* __restrict__ w, const float* __restrict__ bias,
    float* __restrict__ out) {
  int idx = blockIdx.x * 256 + threadIdx.x;      // (n, oc, f, t) t fastest
  int t  = idx & 1023;
  int f  = (idx >> 10) & 63;
  int oc = (idx >> 16) & 31;
  int n  = idx >> 21;
  const float* xb = x + (size_t)n * 262144;      // 128*2048
  float acc = 0.f;
#pragma unroll
  for (int df = 0; df < 3; ++df) {
    int fi = 2 * f + df - 1;
    if (fi < 0 || fi >= 128) continue;
#pragma unroll
    for (int dt = 0; dt < 3; ++dt) {
      int ti = 2 * t + dt - 1;
      if (ti < 0 || ti >= 2048) continue;
      acc += w[oc * 9 + df * 3 + dt] * xb[fi * 2048 + ti];
    }
  }
  out[idx] = acc + bias[oc];
}

// ------------- residual conv 32->32 3x3 s1 p1 + BN (+res) + ReLU -------------
__global__ __launch_bounds__(256) void conv_bn_relu(const float* __restrict__ in,
    const float* __restrict__ w, const float* __restrict__ cb,
    const float* __restrict__ bg, const float* __restrict__ bb,
    const float* __restrict__ bm, const float* __restrict__ bv,
    float* __restrict__ out) {
  int idx = blockIdx.x * 256 + threadIdx.x;      // (n, oc, f, t4)
  int t4 = idx & 255;
  int f  = (idx >> 8) & 63;
  int oc = (idx >> 14) & 31;
  int n  = idx >> 19;
  int t0 = t4 * 4;
  float a0 = 0.f, a1 = 0.f, a2 = 0.f, a3 = 0.f;
  const float* ib = in + (size_t)n * 2097152;    // 32*64*1024
  const float* wb = w + oc * 288;
  for (int ic = 0; ic < 32; ++ic) {
#pragma unroll
    for (int df = 0; df < 3; ++df) {
      int fi = f + df - 1;
      if (fi < 0 || fi > 63) continue;           // wave-uniform branch
      const float* p = ib + ic * 65536 + fi * 1024 + t0;
      float v0 = (t0 > 0) ? p[-1] : 0.f;
      float v1 = p[0], v2 = p[1], v3 = p[2], v4 = p[3];
      float v5 = (t0 < 1020) ? p[4] : 0.f;
      float w0 = wb[ic * 9 + df * 3 + 0];
      float w1 = wb[ic * 9 + df * 3 + 1];
      float w2 = wb[ic * 9 + df * 3 + 2];
      a0 += w0 * v0 + w1 * v1 + w2 * v2;
      a1 += w0 * v1 + w1 * v2 + w2 * v3;
      a2 += w0 * v2 + w1 * v3 + w2 * v4;
      a3 += w0 * v3 + w1 * v4 + w2 * v5;
    }
  }
  float m = bm[oc], s = bg[oc] * rsqrtf(bv[oc] + 1e-5f);
  float bo = bb[oc], cbias = cb[oc];
  float4 o;
  o.x = fmaxf((a0 + cbias - m) * s + bo, 0.f);
  o.y = fmaxf((a1 + cbias - m) * s + bo, 0.f);
  o.z = fmaxf((a2 + cbias - m) * s + bo, 0.f);
  o.w = fmaxf((a3 + cbias - m) * s + bo, 0.f);
  *(float4*)&out[(size_t)idx * 4] = o;
}

__global__ __launch_bounds__(256) void conv_bn_add_relu(const float* __restrict__ in,
    const float* __restrict__ w, const float* __restrict__ cb,
    const float* __restrict__ bg, const float* __restrict__ bb,
    const float* __restrict__ bm, const float* __restrict__ bv,
    float* resout) {                             // residual in == out (same index)
  int idx = blockIdx.x * 256 + threadIdx.x;
  int t4 = idx & 255;
  int f  = (idx >> 8) & 63;
  int oc = (idx >> 14) & 31;
  int n  = idx >> 19;
  int t0 = t4 * 4;
  float a0 = 0.f, a1 = 0.f, a2 = 0.f, a3 = 0.f;
  const float* ib = in + (size_t)n * 2097152;
  const float* wb = w + oc * 288;
  for (int ic = 0; ic < 32; ++ic) {
#pragma unroll
    for (int df = 0; df < 3; ++df) {
      int fi = f + df - 1;
      if (fi < 0 || fi > 63) continue;
      const float* p = ib + ic * 65536 + fi * 1024 + t0;
      float v0 = (t0 > 0) ? p[-1] : 0.f;
      float v1 = p[0], v2 = p[1], v3 = p[2], v4 = p[3];
      float v5 = (t0 < 1020) ? p[4] : 0.f;
      float w0 = wb[ic * 9 + df * 3 + 0];
      float w1 = wb[ic * 9 + df * 3 + 1];
      float w2 = wb[ic * 9 + df * 3 + 2];
      a0 += w0 * v0 + w1 * v1 + w2 * v2;
      a1 += w0 * v1 + w1 * v2 + w2 * v3;
      a2 += w0 * v2 + w1 * v3 + w2 * v4;
      a3 += w0 * v3 + w1 * v4 + w2 * v5;
    }
  }
  float m = bm[oc], s = bg[oc] * rsqrtf(bv[oc] + 1e-5f);
  float bo = bb[oc], cbias = cb[oc];
  float4 r = *(float4*)&resout[(size_t)idx * 4];
  float4 o;
  o.x = fmaxf((a0 + cbias - m) * s + bo + r.x, 0.f);
  o.y = fmaxf((a1 + cbias - m) * s + bo + r.y, 0.f);
  o.z = fmaxf((a2 + cbias - m) * s + bo + r.z, 0.f);
  o.w = fmaxf((a3 + cbias - m) * s + bo + r.w, 0.f);
  *(float4*)&resout[(size_t)idx * 4] = o;
}

// -------- transpose (32768 x 1024) -> (1024 x 32768): s0[t][n*2048+cf] --------
__global__ __launch_bounds__(256) void transpose_k(const float* __restrict__ in,
                                                   float* __restrict__ out) {
  __shared__ float tile[32][33];
  int x = threadIdx.x;         // 0..31
  int y0 = threadIdx.y;        // 0..7
  int bx = blockIdx.x * 32;    // col (t)
  int by = blockIdx.y * 32;    // row (n*2048+cf)
#pragma unroll
  for (int i = 0; i < 4; ++i) {
    int yy = y0 + i * 8;
    tile[yy][x] = in[(size_t)(by + yy) * 1024 + bx + x];
  }
  __syncthreads();
#pragma unroll
  for (int i = 0; i < 4; ++i) {
    int yy = y0 + i * 8;
    out[(size_t)(bx + yy) * 32768 + by + x] = tile[x][yy];
  }
}

// ---------------- LayerNorm over rows of F = NV*1024 -------------------------
template <int NV>
__global__ __launch_bounds__(256) void ln_rows(const float* __restrict__ in,
    const float* __restrict__ g, const float* __restrict__ b,
    float* __restrict__ out) {
  constexpr int F = NV * 1024;
  int r = blockIdx.x;
  int tid = threadIdx.x;
  const float* row = in + (size_t)r * F;
  float* orow = out + (size_t)r * F;
  float4 v[NV];
  float sum = 0.f, ss = 0.f;
#pragma unroll
  for (int i = 0; i < NV; ++i) {
    v[i] = *(const float4*)&row[(i * 256 + tid) * 4];
    sum += v[i].x + v[i].y + v[i].z + v[i].w;
    ss += v[i].x * v[i].x + v[i].y * v[i].y + v[i].z * v[i].z + v[i].w * v[i].w;
  }
#pragma unroll
  for (int off = 32; off > 0; off >>= 1) {
    sum += __shfl_down(sum, off);
    ss  += __shfl_down(ss, off);
  }
  __shared__ float red[8];
  int lane = tid & 63, wave = tid >> 6;
  if (lane == 0) { red[wave] = sum; red[4 + wave] = ss; }
  __syncthreads();
  sum = red[0] + red[1] + red[2] + red[3];
  ss  = red[4] + red[5] + red[6] + red[7];
  float mean = sum * (1.f / F);
  float var = ss * (1.f / F) - mean * mean;
  float inv = rsqrtf(var + 1e-5f);
#pragma unroll
  for (int i = 0; i < NV; ++i) {
    int base = (i * 256 + tid) * 4;
    float4 gv = *(const float4*)&g[base];
    float4 bv = *(const float4*)&b[base];
    float4 o;
    o.x = (v[i].x - mean) * inv * gv.x + bv.x;
    o.y = (v[i].y - mean) * inv * gv.y + bv.y;
    o.z = (v[i].z - mean) * inv * gv.z + bv.z;
    o.w = (v[i].w - mean) * inv * gv.w + bv.w;
    *(float4*)&orow[base] = o;
  }
}

// ------------ fp32 SGEMM: C = A(MxK) @ B(KxN); BF16OUT stores bf16 -----------
template <int BF16OUT>
__global__ __launch_bounds__(256) void gemm_nn(const float* __restrict__ A,
    const float* __restrict__ B, void* __restrict__ Cv,
    int M, int N, int K) {
  __shared__ float As[16][68];
  __shared__ float Bs[16][68];
  int tid = threadIdx.x;
  int m0 = blockIdx.y * 64, n0 = blockIdx.x * 64;
  int tx = tid & 15, ty = tid >> 4;
  int a_m = tid >> 2, a_k = (tid & 3) * 4;
  int b_k = tid >> 4, b_n = (tid & 15) * 4;
  float acc[4][4] = {};
  for (int k0 = 0; k0 < K; k0 += 16) {
    float4 a4 = *(const float4*)&A[(size_t)(m0 + a_m) * K + k0 + a_k];
    float4 b4 = *(const float4*)&B[(size_t)(k0 + b_k) * N + n0 + b_n];
    __syncthreads();
    As[a_k + 0][a_m] = a4.x;
    As[a_k + 1][a_m] = a4.y;
    As[a_k + 2][a_m] = a4.z;
    As[a_k + 3][a_m] = a4.w;
    *(float4*)&Bs[b_k][b_n] = b4;
    __syncthreads();
#pragma unroll
    for (int kk = 0; kk < 16; ++kk) {
      float4 av = *(const float4*)&As[kk][ty * 4];
      float4 bv = *(const float4*)&Bs[kk][tx * 4];
      acc[0][0] += av.x * bv.x; acc[0][1] += av.x * bv.y;
      acc[0][2] += av.x * bv.z; acc[0][3] += av.x * bv.w;
      acc[1][0] += av.y * bv.x; acc[1][1] += av.y * bv.y;
      acc[1][2] += av.y * bv.z; acc[1][3] += av.y * bv.w;
      acc[2][0] += av.z * bv.x; acc[2][1] += av.z * bv.y;
      acc[2][2] += av.z * bv.z; acc[2][3] += av.z * bv.w;
      acc[3][0] += av.w * bv.x; acc[3][1] += av.w * bv.y;
      acc[3][2] += av.w * bv.z; acc[3][3] += av.w * bv.w;
    }
  }
#pragma unroll
  for (int i = 0; i < 4; ++i) {
    if (BF16OUT) {
      __hip_bfloat16* C = (__hip_bfloat16*)Cv;
      union { ushort4 u; __hip_bfloat16 h[4]; } cv;
      cv.h[0] = __float2bfloat16(acc[i][0]);
      cv.h[1] = __float2bfloat16(acc[i][1]);
      cv.h[2] = __float2bfloat16(acc[i][2]);
      cv.h[3] = __float2bfloat16(acc[i][3]);
      *(ushort4*)&C[(size_t)(m0 + ty * 4 + i) * N + n0 + tx * 4] = cv.u;
    } else {
      float* C = (float*)Cv;
      float4 o = make_float4(acc[i][0], acc[i][1], acc[i][2], acc[i][3]);
      *(float4*)&C[(size_t)(m0 + ty * 4 + i) * N + n0 + tx * 4] = o;
    }
  }
}

// ---------------- SRU bidirectional scan (U in bf16) -------------------------
__global__ __launch_bounds__(64) void sru_scan(const __hip_bfloat16* __restrict__ U,
    const float* __restrict__ resx, const float* __restrict__ vc,
    const float* __restrict__ bias, float* __restrict__ out, int k) {
  int gid = blockIdx.x * 64 + threadIdx.x;   // 16384
  int j = gid & 511;
  int n = (gid >> 9) & 15;
  int d = gid >> 13;
  float vf = vc[(d * 2 + 0) * 512 + j];
  float vr = vc[(d * 2 + 1) * 512 + j];
  float bf = bias[(d * 2 + 0) * 512 + j];
  float br = bias[(d * 2 + 1) * 512 + j];
  const bool k4 = (k == 4);
  const size_t tstride = (size_t)k * 16384;  // U elems per t
  const __hip_bfloat16* Ub = U + (size_t)(n * 2 + d) * k * 512 + j;
  const float* Rb = k4 ? nullptr : (resx + (size_t)n * 1024 + d * 512 + j);
  float* ob = out + (size_t)n * 1024 + d * 512 + j;
  const int PF = 8;
  float Aa0[PF], Aa1[PF], Aa2[PF], Arx[PF];
  float Ba0[PF], Ba1[PF], Ba2[PF], Brx[PF];
  float c = 0.f;

#define LOAD_CHUNK(CB, A0, A1, A2, RX)                                    \
  {                                                                       \
    _Pragma("unroll") for (int ss = 0; ss < PF; ++ss) {                   \
      int tt = (CB) * PF + ss;                                            \
      int t = d ? (1023 - tt) : tt;                                       \
      size_t off = (size_t)t * tstride;                                   \
      A0[ss] = __bfloat162float(Ub[off]);                                 \
      A1[ss] = __bfloat162float(Ub[off + 512]);                           \
      A2[ss] = __bfloat162float(Ub[off + 1024]);                          \
      RX[ss] = k4 ? __bfloat162float(Ub[off + 1536])                      \
                  : Rb[(size_t)t * 16384];                                \
    }                                                                     \
  }

#define COMP_CHUNK(CB, A0, A1, A2, RX)                                    \
  {                                                                       \
    _Pragma("unroll") for (int ss = 0; ss < PF; ++ss) {                   \
      int tt = (CB) * PF + ss;                                            \
      int t = d ? (1023 - tt) : tt;                                       \
      float f = sigmoidf_(A1[ss] + vf * c + bf);                          \
      float c2 = f * c + (1.f - f) * A0[ss];                              \
      float r = sigmoidf_(A2[ss] + vr * c2 + br);                         \
      ob[(size_t)t * 16384] = r * c2 + (1.f - r) * RX[ss];                \
      c = c2;                                                             \
    }                                                                     \
  }

  LOAD_CHUNK(0, Aa0, Aa1, Aa2, Arx);
  for (int cb = 0; cb < 128; cb += 2) {
    LOAD_CHUNK(cb + 1, Ba0, Ba1, Ba2, Brx);
    COMP_CHUNK(cb, Aa0, Aa1, Aa2, Arx);
    if (cb + 2 < 128) LOAD_CHUNK(cb + 2, Aa0, Aa1, Aa2, Arx);
    COMP_CHUNK(cb + 1, Ba0, Ba1, Ba2, Brx);
  }
#undef LOAD_CHUNK
#undef COMP_CHUNK
}

// ------------- final LN (1024) + classifier (1024x30), out (16,1024,30) ------
__global__ __launch_bounds__(256) void ln_cls(const float* __restrict__ s2,
    const float* __restrict__ g, const float* __restrict__ b,
    const float* __restrict__ W, float* __restrict__ out) {
  int r = blockIdx.x;        // t*16 + n
  int t = r >> 4, n = r & 15;
  int tid = threadIdx.x;
  const float* row = s2 + (size_t)r * 1024;
  float4 v = *(const float4*)&row[tid * 4];
  float sum = v.x + v.y + v.z + v.w;
  float ss = v.x * v.x + v.y * v.y + v.z * v.z + v.w * v.w;
#pragma unroll
  for (int off = 32; off > 0; off >>= 1) {
    sum += __shfl_down(sum, off);
    ss  += __shfl_down(ss, off);
  }
  __shared__ float red[128];
  int lane = tid & 63, wave = tid >> 6;
  if (lane == 0) { red[wave] = sum; red[4 + wave] = ss; }
  __syncthreads();
  sum = red[0] + red[1] + red[2] + red[3];
  ss  = red[4] + red[5] + red[6] + red[7];
  float mean = sum * (1.f / 1024.f);
  float var = ss * (1.f / 1024.f) - mean * mean;
  float inv = rsqrtf(var + 1e-5f);
  float4 gv = *(const float4*)&g[tid * 4];
  float4 bv = *(const float4*)&b[tid * 4];
  float y0 = (v.x - mean) * inv * gv.x + bv.x;
  float y1 = (v.y - mean) * inv * gv.y + bv.y;
  float y2 = (v.z - mean) * inv * gv.z + bv.z;
  float y3 = (v.w - mean) * inv * gv.w + bv.w;
  const float* wp = W + (size_t)tid * 120;   // rows tid*4 .. tid*4+3
  float acc[30];
#pragma unroll
  for (int jj = 0; jj < 30; ++jj)
    acc[jj] = y0 * wp[jj] + y1 * wp[30 + jj] + y2 * wp[60 + jj] + y3 * wp[90 + jj];
  __syncthreads();   // before reusing red[]
#pragma unroll
  for (int jj = 0; jj < 30; ++jj) {
    float vs = acc[jj];
    vs += __shfl_down(vs, 32);
    vs += __shfl_down(vs, 16);
    vs += __shfl_down(vs, 8);
    vs += __shfl_down(vs, 4);
    vs += __shfl_down(vs, 2);
    vs += __shfl_down(vs, 1);
    if (lane == 0) red[wave * 30 + jj] = vs;
  }
  __syncthreads();
  if (tid < 30) {
    float tot = red[tid] + red[30 + tid] + red[60 + tid] + red[90 + tid];
    out[(size_t)n * 30720 + t * 30 + tid] = tot;
  }
}

extern "C" void kernel_launch(void* const* d_in, const int* in_sizes, int n_in,
                              void* d_out, int out_size, void* d_ws, size_t ws_size,
                              hipStream_t stream) {
  const float* x        = (const float*)d_in[0];
  const float* conv0_w  = (const float*)d_in[1];
  const float* conv0_b  = (const float*)d_in[2];
  const float* rconv1_w = (const float*)d_in[3];
  const float* rconv1_b = (const float*)d_in[4];
  const float* rbn1_g   = (const float*)d_in[5];
  const float* rbn1_b   = (const float*)d_in[6];
  const float* rbn1_m   = (const float*)d_in[7];
  const float* rbn1_v   = (const float*)d_in[8];
  const float* rconv2_w = (const float*)d_in[9];
  const float* rconv2_b = (const float*)d_in[10];
  const float* rbn2_g   = (const float*)d_in[11];
  const float* rbn2_b   = (const float*)d_in[12];
  const float* rbn2_m   = (const float*)d_in[13];
  const float* rbn2_v   = (const float*)d_in[14];
  const float* ln0_g    = (const float*)d_in[15];
  const float* ln0_b    = (const float*)d_in[16];
  const float* wproj0   = (const float*)d_in[17];
  const float* w0       = (const float*)d_in[18];
  const float* vc0      = (const float*)d_in[19];
  const float* bias0    = (const float*)d_in[20];
  const float* ln_g     = (const float*)d_in[21];
  const float* ln_b     = (const float*)d_in[22];
  const float* wproj    = (const float*)d_in[23];
  const float* w        = (const float*)d_in[24];
  const float* vc       = (const float*)d_in[25];
  const float* bias     = (const float*)d_in[26];
  const float* cln_g    = (const float*)d_in[27];
  const float* cln_b    = (const float*)d_in[28];
  const float* cls_w    = (const float*)d_in[29];
  float* out = (float*)d_out;

  // Two 128 MiB arenas; total ws use = 256 MiB.
  float* Af = (float*)d_ws;                    // 33,554,432 floats
  float* Bf = Af + 33554432;                   // 33,554,432 floats
  __hip_bfloat16* Uh = (__hip_bfloat16*)Af;    // bf16 view of arena A
  float* tmp1  = Bf;                           // layer0 tmp (16384x256)
  float* s2    = Bf;                           // scan output (16384x1024, 64 MiB)
  float* xn_i  = Bf + 16777216;                // layers 1-3 LN out (64 MiB)
  float* tmp_i = Af + 25165824;                // layers 1-3 tmp (after 96 MiB U3)

  // conv stem + residual blocks (A = h, B = temp)
  conv_stem<<<131072, 256, 0, stream>>>(x, conv0_w, conv0_b, Af);
  for (int i = 0; i < 3; ++i) {
    conv_bn_relu<<<32768, 256, 0, stream>>>(Af, rconv1_w + i * 9216,
        rconv1_b + i * 32, rbn1_g + i * 32, rbn1_b + i * 32,
        rbn1_m + i * 32, rbn1_v + i * 32, Bf);
    conv_bn_add_relu<<<32768, 256, 0, stream>>>(Bf, rconv2_w + i * 9216,
        rconv2_b + i * 32, rbn2_g + i * 32, rbn2_b + i * 32,
        rbn2_m + i * 32, rbn2_v + i * 32, Af);
  }
  // (16,32,64,1024) -> s0 (1024, 16*2048) into B
  transpose_k<<<dim3(32, 1024), dim3(32, 8), 0, stream>>>(Af, Bf);

  // SRU layer 0 (k=4, F=2048): LN B->A; proj A->B(tmp); expand B->A(bf16 U)
  ln_rows<2><<<16384, 256, 0, stream>>>(Bf, ln0_g, ln0_b, Af);
  gemm_nn<0><<<dim3(4, 256), 256, 0, stream>>>(Af, wproj0, tmp1, 16384, 256, 2048);
  gemm_nn<1><<<dim3(64, 256), 256, 0, stream>>>(tmp1, w0, (void*)Uh, 16384, 4096, 256);
  sru_scan<<<256, 64, 0, stream>>>(Uh, nullptr, vc0, bias0, s2, 4);

  // SRU layers 1..3 (k=3, F=1024)
  for (int i = 0; i < 3; ++i) {
    ln_rows<1><<<16384, 256, 0, stream>>>(s2, ln_g + i * 1024, ln_b + i * 1024, xn_i);
    gemm_nn<0><<<dim3(4, 256), 256, 0, stream>>>(xn_i, wproj + i * 262144, tmp_i,
                                                 16384, 256, 1024);
    gemm_nn<1><<<dim3(48, 256), 256, 0, stream>>>(tmp_i, w + i * 786432, (void*)Uh,
                                                  16384, 3072, 256);
    sru_scan<<<256, 64, 0, stream>>>(Uh, xn_i, vc + i * 2048, bias + i * 2048, s2, 3);
  }

  // final LN + classifier
  ln_cls<<<16384, 256, 0, stream>>>(s2, cln_g, cln_b, cls_w, out);
}

// Round 3
// 6366.278 us; speedup vs baseline: 2.8827x; 2.8827x over previous
//
#include <hip/hip_runtime.h>
#include <hip/hip_bf16.h>
#include <math.h>

#define DEV __device__ __forceinline__

DEV float sigmoidf_(float x) { return 1.f / (1.f + __expf(-x)); }

// ---------------- conv stem: (16,1,128,2048) -> (16,32,64,1024), 3x3 s2 p1 ----
__global__ __launch_bounds__(256) void conv_stem(const float* __restrict__ x,
    const float* __restrict__ w, const float* __restrict__ bias,
    float* __restrict__ out) {
  int idx = blockIdx.x * 256 + threadIdx.x;      // (n, oc, f, t) t fastest
  int t  = idx & 1023;
  int f  = (idx >> 10) & 63;
  int oc = (idx >> 16) & 31;
  int n  = idx >> 21;
  const float* xb = x + (size_t)n * 262144;      // 128*2048
  float acc = 0.f;
#pragma unroll
  for (int df = 0; df < 3; ++df) {
    int fi = 2 * f + df - 1;
    if (fi < 0 || fi >= 128) continue;
#pragma unroll
    for (int dt = 0; dt < 3; ++dt) {
      int ti = 2 * t + dt - 1;
      if (ti < 0 || ti >= 2048) continue;
      acc += w[oc * 9 + df * 3 + dt] * xb[fi * 2048 + ti];
    }
  }
  out[idx] = acc + bias[oc];
}

// ------- residual conv 32->32 3x3 s1 p1 + BN (+res) + ReLU, LDS-tiled --------
// block = (tb, f, n); stages 32ic x 3rows x 130cols in LDS; thread = 4oc x 4t
template <int ADD>
__global__ __launch_bounds__(256) void conv3x3_tile(const float* __restrict__ in,
    const float* __restrict__ w, const float* __restrict__ cb,
    const float* __restrict__ bg, const float* __restrict__ bb,
    const float* __restrict__ bm, const float* __restrict__ bv,
    float* resout) {
  __shared__ float sIn[32 * 3 * 132];            // 49.5 KB
  const int tid = threadIdx.x;
  const int tb = blockIdx.x;                     // 0..7  (t-tile of 128)
  const int f  = blockIdx.y;                     // 0..63
  const int n  = blockIdx.z;                     // 0..15
  const int t0 = tb * 128;
  const float* ib = in + (size_t)n * 2097152;    // 32*64*1024

  // ---- stage input patch: rows r = ic*3+df, cols c -> t = t0 + c - 1 ----
  for (int i = tid; i < 12672; i += 256) {
    int r = i / 132;
    int c = i - r * 132;
    int ic = r / 3;
    int df = r - ic * 3;
    int fi = f + df - 1;
    int tg = t0 + c - 1;
    float v = 0.f;
    if (c < 130 && fi >= 0 && fi < 64 && tg >= 0 && tg < 1024)
      v = ib[ic * 65536 + fi * 1024 + tg];
    sIn[i] = v;
  }
  __syncthreads();

  const int og  = tid >> 5;                      // 0..7 -> oc0 = og*4
  const int tg  = tid & 31;                      // 0..31 -> tt0 = tg*4
  const int oc0 = og * 4;
  const int tt0 = tg * 4;

  float acc[4][4] = {};                          // [oc'][t']
  for (int ic = 0; ic < 32; ++ic) {
    float wreg[4][9];
#pragma unroll
    for (int o = 0; o < 4; ++o)
#pragma unroll
      for (int q = 0; q < 9; ++q)
        wreg[o][q] = w[(oc0 + o) * 288 + ic * 9 + q];
#pragma unroll
    for (int df = 0; df < 3; ++df) {
      const float* row = &sIn[(ic * 3 + df) * 132];
      float4 a = *(const float4*)&row[tt0];      // t = tt0-1 .. tt0+2
      float b0 = row[tt0 + 4];                   // t = tt0+3
      float b1 = row[tt0 + 5];                   // t = tt0+4
      float v[6] = {a.x, a.y, a.z, a.w, b0, b1}; // v[j] = input t = tt0 + j - 1
#pragma unroll
      for (int o = 0; o < 4; ++o) {
        float w0 = wreg[o][df * 3 + 0];
        float w1 = wreg[o][df * 3 + 1];
        float w2 = wreg[o][df * 3 + 2];
#pragma unroll
        for (int tt = 0; tt < 4; ++tt)
          acc[o][tt] += w0 * v[tt] + w1 * v[tt + 1] + w2 * v[tt + 2];
      }
    }
  }

#pragma unroll
  for (int o = 0; o < 4; ++o) {
    int oc = oc0 + o;
    float m = bm[oc], s = bg[oc] * rsqrtf(bv[oc] + 1e-5f);
    float bo = bb[oc], cbias = cb[oc];
    size_t outoff = (size_t)n * 2097152 + (size_t)oc * 65536 + f * 1024 + t0 + tt0;
    float4 o4;
    o4.x = (acc[o][0] + cbias - m) * s + bo;
    o4.y = (acc[o][1] + cbias - m) * s + bo;
    o4.z = (acc[o][2] + cbias - m) * s + bo;
    o4.w = (acc[o][3] + cbias - m) * s + bo;
    if (ADD) {
      float4 r = *(float4*)&resout[outoff];
      o4.x += r.x; o4.y += r.y; o4.z += r.z; o4.w += r.w;
    }
    o4.x = fmaxf(o4.x, 0.f); o4.y = fmaxf(o4.y, 0.f);
    o4.z = fmaxf(o4.z, 0.f); o4.w = fmaxf(o4.w, 0.f);
    *(float4*)&resout[outoff] = o4;
  }
}

// -------- transpose (32768 x 1024) -> (1024 x 32768): s0[t][n*2048+cf] --------
__global__ __launch_bounds__(256) void transpose_k(const float* __restrict__ in,
                                                   float* __restrict__ out) {
  __shared__ float tile[32][33];
  int x = threadIdx.x;         // 0..31
  int y0 = threadIdx.y;        // 0..7
  int bx = blockIdx.x * 32;    // col (t)
  int by = blockIdx.y * 32;    // row (n*2048+cf)
#pragma unroll
  for (int i = 0; i < 4; ++i) {
    int yy = y0 + i * 8;
    tile[yy][x] = in[(size_t)(by + yy) * 1024 + bx + x];
  }
  __syncthreads();
#pragma unroll
  for (int i = 0; i < 4; ++i) {
    int yy = y0 + i * 8;
    out[(size_t)(bx + yy) * 32768 + by + x] = tile[x][yy];
  }
}

// ---------------- LayerNorm over rows of F = NV*1024 -------------------------
template <int NV>
__global__ __launch_bounds__(256) void ln_rows(const float* __restrict__ in,
    const float* __restrict__ g, const float* __restrict__ b,
    float* __restrict__ out) {
  constexpr int F = NV * 1024;
  int r = blockIdx.x;
  int tid = threadIdx.x;
  const float* row = in + (size_t)r * F;
  float* orow = out + (size_t)r * F;
  float4 v[NV];
  float sum = 0.f, ss = 0.f;
#pragma unroll
  for (int i = 0; i < NV; ++i) {
    v[i] = *(const float4*)&row[(i * 256 + tid) * 4];
    sum += v[i].x + v[i].y + v[i].z + v[i].w;
    ss += v[i].x * v[i].x + v[i].y * v[i].y + v[i].z * v[i].z + v[i].w * v[i].w;
  }
#pragma unroll
  for (int off = 32; off > 0; off >>= 1) {
    sum += __shfl_down(sum, off);
    ss  += __shfl_down(ss, off);
  }
  __shared__ float red[8];
  int lane = tid & 63, wave = tid >> 6;
  if (lane == 0) { red[wave] = sum; red[4 + wave] = ss; }
  __syncthreads();
  sum = red[0] + red[1] + red[2] + red[3];
  ss  = red[4] + red[5] + red[6] + red[7];
  float mean = sum * (1.f / F);
  float var = ss * (1.f / F) - mean * mean;
  float inv = rsqrtf(var + 1e-5f);
#pragma unroll
  for (int i = 0; i < NV; ++i) {
    int base = (i * 256 + tid) * 4;
    float4 gv = *(const float4*)&g[base];
    float4 bv = *(const float4*)&b[base];
    float4 o;
    o.x = (v[i].x - mean) * inv * gv.x + bv.x;
    o.y = (v[i].y - mean) * inv * gv.y + bv.y;
    o.z = (v[i].z - mean) * inv * gv.z + bv.z;
    o.w = (v[i].w - mean) * inv * gv.w + bv.w;
    *(float4*)&orow[base] = o;
  }
}

// ------------ fp32 SGEMM: C = A(MxK) @ B(KxN); BF16OUT stores bf16 -----------
template <int BF16OUT>
__global__ __launch_bounds__(256) void gemm_nn(const float* __restrict__ A,
    const float* __restrict__ B, void* __restrict__ Cv,
    int M, int N, int K) {
  __shared__ float As[16][68];
  __shared__ float Bs[16][68];
  int tid = threadIdx.x;
  int m0 = blockIdx.y * 64, n0 = blockIdx.x * 64;
  int tx = tid & 15, ty = tid >> 4;
  int a_m = tid >> 2, a_k = (tid & 3) * 4;
  int b_k = tid >> 4, b_n = (tid & 15) * 4;
  float acc[4][4] = {};
  for (int k0 = 0; k0 < K; k0 += 16) {
    float4 a4 = *(const float4*)&A[(size_t)(m0 + a_m) * K + k0 + a_k];
    float4 b4 = *(const float4*)&B[(size_t)(k0 + b_k) * N + n0 + b_n];
    __syncthreads();
    As[a_k + 0][a_m] = a4.x;
    As[a_k + 1][a_m] = a4.y;
    As[a_k + 2][a_m] = a4.z;
    As[a_k + 3][a_m] = a4.w;
    *(float4*)&Bs[b_k][b_n] = b4;
    __syncthreads();
#pragma unroll
    for (int kk = 0; kk < 16; ++kk) {
      float4 av = *(const float4*)&As[kk][ty * 4];
      float4 bv = *(const float4*)&Bs[kk][tx * 4];
      acc[0][0] += av.x * bv.x; acc[0][1] += av.x * bv.y;
      acc[0][2] += av.x * bv.z; acc[0][3] += av.x * bv.w;
      acc[1][0] += av.y * bv.x; acc[1][1] += av.y * bv.y;
      acc[1][2] += av.y * bv.z; acc[1][3] += av.y * bv.w;
      acc[2][0] += av.z * bv.x; acc[2][1] += av.z * bv.y;
      acc[2][2] += av.z * bv.z; acc[2][3] += av.z * bv.w;
      acc[3][0] += av.w * bv.x; acc[3][1] += av.w * bv.y;
      acc[3][2] += av.w * bv.z; acc[3][3] += av.w * bv.w;
    }
  }
#pragma unroll
  for (int i = 0; i < 4; ++i) {
    if (BF16OUT) {
      __hip_bfloat16* C = (__hip_bfloat16*)Cv;
      union { ushort4 u; __hip_bfloat16 h[4]; } cv;
      cv.h[0] = __float2bfloat16(acc[i][0]);
      cv.h[1] = __float2bfloat16(acc[i][1]);
      cv.h[2] = __float2bfloat16(acc[i][2]);
      cv.h[3] = __float2bfloat16(acc[i][3]);
      *(ushort4*)&C[(size_t)(m0 + ty * 4 + i) * N + n0 + tx * 4] = cv.u;
    } else {
      float* C = (float*)Cv;
      float4 o = make_float4(acc[i][0], acc[i][1], acc[i][2], acc[i][3]);
      *(float4*)&C[(size_t)(m0 + ty * 4 + i) * N + n0 + tx * 4] = o;
    }
  }
}

// ---------------- SRU bidirectional scan (U in bf16) -------------------------
__global__ __launch_bounds__(64) void sru_scan(const __hip_bfloat16* __restrict__ U,
    const float* __restrict__ resx, const float* __restrict__ vc,
    const float* __restrict__ bias, float* __restrict__ out, int k) {
  int gid = blockIdx.x * 64 + threadIdx.x;   // 16384
  int j = gid & 511;
  int n = (gid >> 9) & 15;
  int d = gid >> 13;
  float vf = vc[(d * 2 + 0) * 512 + j];
  float vr = vc[(d * 2 + 1) * 512 + j];
  float bf = bias[(d * 2 + 0) * 512 + j];
  float br = bias[(d * 2 + 1) * 512 + j];
  const bool k4 = (k == 4);
  const size_t tstride = (size_t)k * 16384;  // U elems per t
  const __hip_bfloat16* Ub = U + (size_t)(n * 2 + d) * k * 512 + j;
  const float* Rb = k4 ? nullptr : (resx + (size_t)n * 1024 + d * 512 + j);
  float* ob = out + (size_t)n * 1024 + d * 512 + j;
  const int PF = 8;
  float Aa0[PF], Aa1[PF], Aa2[PF], Arx[PF];
  float Ba0[PF], Ba1[PF], Ba2[PF], Brx[PF];
  float c = 0.f;

#define LOAD_CHUNK(CB, A0, A1, A2, RX)                                    \
  {                                                                       \
    _Pragma("unroll") for (int ss = 0; ss < PF; ++ss) {                   \
      int tt = (CB) * PF + ss;                                            \
      int t = d ? (1023 - tt) : tt;                                       \
      size_t off = (size_t)t * tstride;                                   \
      A0[ss] = __bfloat162float(Ub[off]);                                 \
      A1[ss] = __bfloat162float(Ub[off + 512]);                           \
      A2[ss] = __bfloat162float(Ub[off + 1024]);                          \
      RX[ss] = k4 ? __bfloat162float(Ub[off + 1536])                      \
                  : Rb[(size_t)t * 16384];                                \
    }                                                                     \
  }

#define COMP_CHUNK(CB, A0, A1, A2, RX)                                    \
  {                                                                       \
    _Pragma("unroll") for (int ss = 0; ss < PF; ++ss) {                   \
      int tt = (CB) * PF + ss;                                            \
      int t = d ? (1023 - tt) : tt;                                       \
      float f = sigmoidf_(A1[ss] + vf * c + bf);                          \
      float c2 = f * c + (1.f - f) * A0[ss];                              \
      float r = sigmoidf_(A2[ss] + vr * c2 + br);                         \
      ob[(size_t)t * 16384] = r * c2 + (1.f - r) * RX[ss];                \
      c = c2;                                                             \
    }                                                                     \
  }

  LOAD_CHUNK(0, Aa0, Aa1, Aa2, Arx);
  for (int cb = 0; cb < 128; cb += 2) {
    LOAD_CHUNK(cb + 1, Ba0, Ba1, Ba2, Brx);
    COMP_CHUNK(cb, Aa0, Aa1, Aa2, Arx);
    if (cb + 2 < 128) LOAD_CHUNK(cb + 2, Aa0, Aa1, Aa2, Arx);
    COMP_CHUNK(cb + 1, Ba0, Ba1, Ba2, Brx);
  }
#undef LOAD_CHUNK
#undef COMP_CHUNK
}

// ------------- final LN (1024) + classifier (1024x30), out (16,1024,30) ------
__global__ __launch_bounds__(256) void ln_cls(const float* __restrict__ s2,
    const float* __restrict__ g, const float* __restrict__ b,
    const float* __restrict__ W, float* __restrict__ out) {
  int r = blockIdx.x;        // t*16 + n
  int t = r >> 4, n = r & 15;
  int tid = threadIdx.x;
  const float* row = s2 + (size_t)r * 1024;
  float4 v = *(const float4*)&row[tid * 4];
  float sum = v.x + v.y + v.z + v.w;
  float ss = v.x * v.x + v.y * v.y + v.z * v.z + v.w * v.w;
#pragma unroll
  for (int off = 32; off > 0; off >>= 1) {
    sum += __shfl_down(sum, off);
    ss  += __shfl_down(ss, off);
  }
  __shared__ float red[128];
  int lane = tid & 63, wave = tid >> 6;
  if (lane == 0) { red[wave] = sum; red[4 + wave] = ss; }
  __syncthreads();
  sum = red[0] + red[1] + red[2] + red[3];
  ss  = red[4] + red[5] + red[6] + red[7];
  float mean = sum * (1.f / 1024.f);
  float var = ss * (1.f / 1024.f) - mean * mean;
  float inv = rsqrtf(var + 1e-5f);
  float4 gv = *(const float4*)&g[tid * 4];
  float4 bv = *(const float4*)&b[tid * 4];
  float y0 = (v.x - mean) * inv * gv.x + bv.x;
  float y1 = (v.y - mean) * inv * gv.y + bv.y;
  float y2 = (v.z - mean) * inv * gv.z + bv.z;
  float y3 = (v.w - mean) * inv * gv.w + bv.w;
  const float* wp = W + (size_t)tid * 120;   // rows tid*4 .. tid*4+3
  float acc[30];
#pragma unroll
  for (int jj = 0; jj < 30; ++jj)
    acc[jj] = y0 * wp[jj] + y1 * wp[30 + jj] + y2 * wp[60 + jj] + y3 * wp[90 + jj];
  __syncthreads();   // before reusing red[]
#pragma unroll
  for (int jj = 0; jj < 30; ++jj) {
    float vs = acc[jj];
    vs += __shfl_down(vs, 32);
    vs += __shfl_down(vs, 16);
    vs += __shfl_down(vs, 8);
    vs += __shfl_down(vs, 4);
    vs += __shfl_down(vs, 2);
    vs += __shfl_down(vs, 1);
    if (lane == 0) red[wave * 30 + jj] = vs;
  }
  __syncthreads();
  if (tid < 30) {
    float tot = red[tid] + red[30 + tid] + red[60 + tid] + red[90 + tid];
    out[(size_t)n * 30720 + t * 30 + tid] = tot;
  }
}

extern "C" void kernel_launch(void* const* d_in, const int* in_sizes, int n_in,
                              void* d_out, int out_size, void* d_ws, size_t ws_size,
                              hipStream_t stream) {
  const float* x        = (const float*)d_in[0];
  const float* conv0_w  = (const float*)d_in[1];
  const float* conv0_b  = (const float*)d_in[2];
  const float* rconv1_w = (const float*)d_in[3];
  const float* rconv1_b = (const float*)d_in[4];
  const float* rbn1_g   = (const float*)d_in[5];
  const float* rbn1_b   = (const float*)d_in[6];
  const float* rbn1_m   = (const float*)d_in[7];
  const float* rbn1_v   = (const float*)d_in[8];
  const float* rconv2_w = (const float*)d_in[9];
  const float* rconv2_b = (const float*)d_in[10];
  const float* rbn2_g   = (const float*)d_in[11];
  const float* rbn2_b   = (const float*)d_in[12];
  const float* rbn2_m   = (const float*)d_in[13];
  const float* rbn2_v   = (const float*)d_in[14];
  const float* ln0_g    = (const float*)d_in[15];
  const float* ln0_b    = (const float*)d_in[16];
  const float* wproj0   = (const float*)d_in[17];
  const float* w0       = (const float*)d_in[18];
  const float* vc0      = (const float*)d_in[19];
  const float* bias0    = (const float*)d_in[20];
  const float* ln_g     = (const float*)d_in[21];
  const float* ln_b     = (const float*)d_in[22];
  const float* wproj    = (const float*)d_in[23];
  const float* w        = (const float*)d_in[24];
  const float* vc       = (const float*)d_in[25];
  const float* bias     = (const float*)d_in[26];
  const float* cln_g    = (const float*)d_in[27];
  const float* cln_b    = (const float*)d_in[28];
  const float* cls_w    = (const float*)d_in[29];
  float* out = (float*)d_out;

  // Two 128 MiB arenas; total ws use = 256 MiB.
  float* Af = (float*)d_ws;                    // 33,554,432 floats
  float* Bf = Af + 33554432;                   // 33,554,432 floats
  __hip_bfloat16* Uh = (__hip_bfloat16*)Af;    // bf16 view of arena A
  float* tmp1  = Bf;                           // layer0 tmp (16384x256)
  float* s2    = Bf;                           // scan output (16384x1024, 64 MiB)
  float* xn_i  = Bf + 16777216;                // layers 1-3 LN out (64 MiB)
  float* tmp_i = Af + 25165824;                // layers 1-3 tmp (after 96 MiB U3)

  // conv stem + residual blocks (A = h, B = temp)
  conv_stem<<<131072, 256, 0, stream>>>(x, conv0_w, conv0_b, Af);
  for (int i = 0; i < 3; ++i) {
    conv3x3_tile<0><<<dim3(8, 64, 16), 256, 0, stream>>>(Af, rconv1_w + i * 9216,
        rconv1_b + i * 32, rbn1_g + i * 32, rbn1_b + i * 32,
        rbn1_m + i * 32, rbn1_v + i * 32, Bf);
    conv3x3_tile<1><<<dim3(8, 64, 16), 256, 0, stream>>>(Bf, rconv2_w + i * 9216,
        rconv2_b + i * 32, rbn2_g + i * 32, rbn2_b + i * 32,
        rbn2_m + i * 32, rbn2_v + i * 32, Af);
  }
  // (16,32,64,1024) -> s0 (1024, 16*2048) into B
  transpose_k<<<dim3(32, 1024), dim3(32, 8), 0, stream>>>(Af, Bf);

  // SRU layer 0 (k=4, F=2048): LN B->A; proj A->B(tmp); expand B->A(bf16 U)
  ln_rows<2><<<16384, 256, 0, stream>>>(Bf, ln0_g, ln0_b, Af);
  gemm_nn<0><<<dim3(4, 256), 256, 0, stream>>>(Af, wproj0, tmp1, 16384, 256, 2048);
  gemm_nn<1><<<dim3(64, 256), 256, 0, stream>>>(tmp1, w0, (void*)Uh, 16384, 4096, 256);
  sru_scan<<<256, 64, 0, stream>>>(Uh, nullptr, vc0, bias0, s2, 4);

  // SRU layers 1..3 (k=3, F=1024)
  for (int i = 0; i < 3; ++i) {
    ln_rows<1><<<16384, 256, 0, stream>>>(s2, ln_g + i * 1024, ln_b + i * 1024, xn_i);
    gemm_nn<0><<<dim3(4, 256), 256, 0, stream>>>(xn_i, wproj + i * 262144, tmp_i,
                                                 16384, 256, 1024);
    gemm_nn<1><<<dim3(48, 256), 256, 0, stream>>>(tmp_i, w + i * 786432, (void*)Uh,
                                                  16384, 3072, 256);
    sru_scan<<<256, 64, 0, stream>>>(Uh, xn_i, vc + i * 2048, bias + i * 2048, s2, 3);
  }

  // final LN + classifier
  ln_cls<<<16384, 256, 0, stream>>>(s2, cln_g, cln_b, cls_w, out);
}

// Round 4
// 4378.820 us; speedup vs baseline: 4.1912x; 1.4539x over previous
//
#include <hip/hip_runtime.h>
#include <hip/hip_bf16.h>
#include <math.h>

#define DEV __device__ __forceinline__

typedef __attribute__((ext_vector_type(8))) short short8;
typedef __attribute__((ext_vector_type(4))) float floatx4;

DEV float sigmoidf_(float x) { return 1.f / (1.f + __expf(-x)); }

// ---------------- conv stem: (16,1,128,2048) -> (16,32,64,1024), 3x3 s2 p1 ----
__global__ __launch_bounds__(256) void conv_stem(const float* __restrict__ x,
    const float* __restrict__ w, const float* __restrict__ bias,
    float* __restrict__ out) {
  int idx = blockIdx.x * 256 + threadIdx.x;      // (n, oc, f, t) t fastest
  int t  = idx & 1023;
  int f  = (idx >> 10) & 63;
  int oc = (idx >> 16) & 31;
  int n  = idx >> 21;
  const float* xb = x + (size_t)n * 262144;      // 128*2048
  float acc = 0.f;
#pragma unroll
  for (int df = 0; df < 3; ++df) {
    int fi = 2 * f + df - 1;
    if (fi < 0 || fi >= 128) continue;
#pragma unroll
    for (int dt = 0; dt < 3; ++dt) {
      int ti = 2 * t + dt - 1;
      if (ti < 0 || ti >= 2048) continue;
      acc += w[oc * 9 + df * 3 + dt] * xb[fi * 2048 + ti];
    }
  }
  out[idx] = acc + bias[oc];
}

// ------- residual conv 32->32 3x3 s1 p1 + BN (+res) + ReLU, LDS-tiled --------
// block = (tb, f, n); stages 32ic x 3rows x 130cols in LDS.
// thread = 4oc x 4t with t STRIDED by 32 (conflict-free LDS reads).
template <int ADD>
__global__ __launch_bounds__(256) void conv3x3_tile(const float* __restrict__ in,
    const float* __restrict__ w, const float* __restrict__ cb,
    const float* __restrict__ bg, const float* __restrict__ bb,
    const float* __restrict__ bm, const float* __restrict__ bv,
    float* resout) {
  __shared__ float sIn[32 * 3 * 132];            // 49.5 KB
  const int tid = threadIdx.x;
  const int tb = blockIdx.x;                     // 0..7  (t-tile of 128)
  const int f  = blockIdx.y;                     // 0..63
  const int n  = blockIdx.z;                     // 0..15
  const int t0 = tb * 128;
  const float* ib = in + (size_t)n * 2097152;    // 32*64*1024

  for (int i = tid; i < 12672; i += 256) {
    int r = i / 132;
    int c = i - r * 132;
    int ic = r / 3;
    int df = r - ic * 3;
    int fi = f + df - 1;
    int tg = t0 + c - 1;
    float v = 0.f;
    if (c < 130 && fi >= 0 && fi < 64 && tg >= 0 && tg < 1024)
      v = ib[ic * 65536 + fi * 1024 + tg];
    sIn[i] = v;
  }
  __syncthreads();

  const int og  = tid >> 5;                      // 0..7 -> oc0 = og*4
  const int tg  = tid & 31;                      // output t = t0 + tg + 32*q
  const int oc0 = og * 4;

  float acc[4][4] = {};                          // [oc'][q]
  for (int ic = 0; ic < 32; ++ic) {
    float wreg[4][9];
#pragma unroll
    for (int o = 0; o < 4; ++o)
#pragma unroll
      for (int q = 0; q < 9; ++q)
        wreg[o][q] = w[(oc0 + o) * 288 + ic * 9 + q];
#pragma unroll
    for (int df = 0; df < 3; ++df) {
      const float* row = &sIn[(ic * 3 + df) * 132];
      float v[4][3];                             // v[q][dc] = row[tg + 32q + dc]
#pragma unroll
      for (int q = 0; q < 4; ++q)
#pragma unroll
        for (int dc = 0; dc < 3; ++dc)
          v[q][dc] = row[tg + 32 * q + dc];
#pragma unroll
      for (int o = 0; o < 4; ++o) {
        float w0 = wreg[o][df * 3 + 0];
        float w1 = wreg[o][df * 3 + 1];
        float w2 = wreg[o][df * 3 + 2];
#pragma unroll
        for (int q = 0; q < 4; ++q)
          acc[o][q] += w0 * v[q][0] + w1 * v[q][1] + w2 * v[q][2];
      }
    }
  }

#pragma unroll
  for (int o = 0; o < 4; ++o) {
    int oc = oc0 + o;
    float m = bm[oc], s = bg[oc] * rsqrtf(bv[oc] + 1e-5f);
    float bo = bb[oc], cbias = cb[oc];
    size_t base = (size_t)n * 2097152 + (size_t)oc * 65536 + f * 1024 + t0 + tg;
#pragma unroll
    for (int q = 0; q < 4; ++q) {
      float y = (acc[o][q] + cbias - m) * s + bo;
      if (ADD) y += resout[base + 32 * q];
      resout[base + 32 * q] = fmaxf(y, 0.f);
    }
  }
}

// -------- transpose (32768 x 1024) -> (1024 x 32768): s0[t][n*2048+cf] --------
__global__ __launch_bounds__(256) void transpose_k(const float* __restrict__ in,
                                                   float* __restrict__ out) {
  __shared__ float tile[32][33];
  int x = threadIdx.x;
  int y0 = threadIdx.y;
  int bx = blockIdx.x * 32;    // col (t)
  int by = blockIdx.y * 32;    // row (n*2048+cf)
#pragma unroll
  for (int i = 0; i < 4; ++i) {
    int yy = y0 + i * 8;
    tile[yy][x] = in[(size_t)(by + yy) * 1024 + bx + x];
  }
  __syncthreads();
#pragma unroll
  for (int i = 0; i < 4; ++i) {
    int yy = y0 + i * 8;
    out[(size_t)(bx + yy) * 32768 + by + x] = tile[x][yy];
  }
}

// -------- LayerNorm over rows of F = NV*1024, bf16 output --------------------
template <int NV>
__global__ __launch_bounds__(256) void ln_rows_h(const float* __restrict__ in,
    const float* __restrict__ g, const float* __restrict__ b,
    __hip_bfloat16* __restrict__ out) {
  constexpr int F = NV * 1024;
  int r = blockIdx.x;
  int tid = threadIdx.x;
  const float* row = in + (size_t)r * F;
  __hip_bfloat16* orow = out + (size_t)r * F;
  float4 v[NV];
  float sum = 0.f, ss = 0.f;
#pragma unroll
  for (int i = 0; i < NV; ++i) {
    v[i] = *(const float4*)&row[(i * 256 + tid) * 4];
    sum += v[i].x + v[i].y + v[i].z + v[i].w;
    ss += v[i].x * v[i].x + v[i].y * v[i].y + v[i].z * v[i].z + v[i].w * v[i].w;
  }
#pragma unroll
  for (int off = 32; off > 0; off >>= 1) {
    sum += __shfl_down(sum, off);
    ss  += __shfl_down(ss, off);
  }
  __shared__ float red[8];
  int lane = tid & 63, wave = tid >> 6;
  if (lane == 0) { red[wave] = sum; red[4 + wave] = ss; }
  __syncthreads();
  sum = red[0] + red[1] + red[2] + red[3];
  ss  = red[4] + red[5] + red[6] + red[7];
  float mean = sum * (1.f / F);
  float var = ss * (1.f / F) - mean * mean;
  float inv = rsqrtf(var + 1e-5f);
#pragma unroll
  for (int i = 0; i < NV; ++i) {
    int base = (i * 256 + tid) * 4;
    float4 gv = *(const float4*)&g[base];
    float4 bv = *(const float4*)&b[base];
    union { ushort4 u; __hip_bfloat16 h[4]; } o;
    o.h[0] = __float2bfloat16((v[i].x - mean) * inv * gv.x + bv.x);
    o.h[1] = __float2bfloat16((v[i].y - mean) * inv * gv.y + bv.y);
    o.h[2] = __float2bfloat16((v[i].z - mean) * inv * gv.z + bv.z);
    o.h[3] = __float2bfloat16((v[i].w - mean) * inv * gv.w + bv.w);
    *(ushort4*)&orow[base] = o.u;
  }
}

// ------- weight convert+transpose: in (K x N) fp32 -> out (N x K) bf16 -------
__global__ __launch_bounds__(256) void wt_bf16(const float* __restrict__ in,
    __hip_bfloat16* __restrict__ out, int K, int N) {
  __shared__ float tile[32][33];
  int x = threadIdx.x, y0 = threadIdx.y;
  int bn = blockIdx.x * 32;    // N
  int bk = blockIdx.y * 32;    // K
#pragma unroll
  for (int i = 0; i < 4; ++i) {
    int yy = y0 + i * 8;
    tile[yy][x] = in[(size_t)(bk + yy) * N + bn + x];   // tile[k'][n']
  }
  __syncthreads();
#pragma unroll
  for (int i = 0; i < 4; ++i) {
    int yy = y0 + i * 8;
    out[(size_t)(bn + yy) * K + bk + x] = __float2bfloat16(tile[x][yy]);
  }
}

// -------- bf16 MFMA GEMM: C(MxN) = A(MxK) @ Bt(NxK)^T, bf16 out --------------
// 128x128 tile, BK=32, 4 waves (2x2), each wave 64x64 = 4x4 MFMA 16x16x32
__global__ __launch_bounds__(256) void gemm_bf16(const __hip_bfloat16* __restrict__ A,
    const __hip_bfloat16* __restrict__ Bt, __hip_bfloat16* __restrict__ C,
    int M, int N, int K) {
  __shared__ __hip_bfloat16 As[128 * 40];    // row m, 32 k + pad8 (80B = 5x16B)
  __shared__ __hip_bfloat16 Bs[128 * 40];    // row n, 32 k + pad8
  const int tid = threadIdx.x;
  const int m0 = blockIdx.y * 128, n0 = blockIdx.x * 128;
  const int lane = tid & 63, wave = tid >> 6;
  const int wm = wave & 1, wn = wave >> 1;
  const int fr = lane & 15;                  // frag row (m or n)
  const int fq = lane >> 4;                  // frag quad
  floatx4 acc[4][4];
#pragma unroll
  for (int i = 0; i < 4; ++i)
#pragma unroll
    for (int j = 0; j < 4; ++j)
      acc[i][j] = (floatx4){0.f, 0.f, 0.f, 0.f};

  for (int k0 = 0; k0 < K; k0 += 32) {
    __syncthreads();
    // stage A (512 chunks of 16B) then Bt (512 chunks)
#pragma unroll
    for (int p = 0; p < 4; ++p) {
      int i = tid + p * 256;                 // 0..1023
      int half = i >> 9;
      int j = i & 511;
      int row = j >> 2, ch = j & 3;
      const __hip_bfloat16* src = half
          ? &Bt[(size_t)(n0 + row) * K + k0 + ch * 8]
          : &A[(size_t)(m0 + row) * K + k0 + ch * 8];
      __hip_bfloat16* dst = (half ? Bs : As) + row * 40 + ch * 8;
      *(uint4*)dst = *(const uint4*)src;
    }
    __syncthreads();

    short8 af[4], bf_[4];
#pragma unroll
    for (int i = 0; i < 4; ++i) {
      af[i]  = *(const short8*)&As[(wm * 64 + i * 16 + fr) * 40 + fq * 8];
      bf_[i] = *(const short8*)&Bs[(wn * 64 + i * 16 + fr) * 40 + fq * 8];
    }
#pragma unroll
    for (int i = 0; i < 4; ++i)
#pragma unroll
      for (int j = 0; j < 4; ++j)
        acc[i][j] = __builtin_amdgcn_mfma_f32_16x16x32_bf16(af[i], bf_[j],
                                                            acc[i][j], 0, 0, 0);
  }

  // epilogue: C[row = fq*4+reg (+tiles)][col = fr (+tiles)]
#pragma unroll
  for (int i = 0; i < 4; ++i) {
#pragma unroll
    for (int j = 0; j < 4; ++j) {
#pragma unroll
      for (int reg = 0; reg < 4; ++reg) {
        int row = m0 + wm * 64 + i * 16 + fq * 4 + reg;
        int col = n0 + wn * 64 + j * 16 + fr;
        C[(size_t)row * N + col] = __float2bfloat16(acc[i][j][reg]);
      }
    }
  }
}

// ---------------- SRU bidirectional scan (U bf16, res bf16) ------------------
__global__ __launch_bounds__(64) void sru_scan(const __hip_bfloat16* __restrict__ U,
    const __hip_bfloat16* __restrict__ resx, const float* __restrict__ vc,
    const float* __restrict__ bias, float* __restrict__ out, int k) {
  int gid = blockIdx.x * 64 + threadIdx.x;   // 16384
  int j = gid & 511;
  int n = (gid >> 9) & 15;
  int d = gid >> 13;
  float vf = vc[(d * 2 + 0) * 512 + j];
  float vr = vc[(d * 2 + 1) * 512 + j];
  float bf = bias[(d * 2 + 0) * 512 + j];
  float br = bias[(d * 2 + 1) * 512 + j];
  const bool k4 = (k == 4);
  const size_t tstride = (size_t)k * 16384;  // U elems per t
  const __hip_bfloat16* Ub = U + (size_t)(n * 2 + d) * k * 512 + j;
  const __hip_bfloat16* Rb = k4 ? nullptr : (resx + (size_t)n * 1024 + d * 512 + j);
  float* ob = out + (size_t)n * 1024 + d * 512 + j;
  const int PF = 8;
  float Aa0[PF], Aa1[PF], Aa2[PF], Arx[PF];
  float Ba0[PF], Ba1[PF], Ba2[PF], Brx[PF];
  float c = 0.f;

#define LOAD_CHUNK(CB, A0, A1, A2, RX)                                    \
  {                                                                       \
    _Pragma("unroll") for (int ss = 0; ss < PF; ++ss) {                   \
      int tt = (CB) * PF + ss;                                            \
      int t = d ? (1023 - tt) : tt;                                       \
      size_t off = (size_t)t * tstride;                                   \
      A0[ss] = __bfloat162float(Ub[off]);                                 \
      A1[ss] = __bfloat162float(Ub[off + 512]);                           \
      A2[ss] = __bfloat162float(Ub[off + 1024]);                          \
      RX[ss] = k4 ? __bfloat162float(Ub[off + 1536])                      \
                  : __bfloat162float(Rb[(size_t)t * 16384]);              \
    }                                                                     \
  }

#define COMP_CHUNK(CB, A0, A1, A2, RX)                                    \
  {                                                                       \
    _Pragma("unroll") for (int ss = 0; ss < PF; ++ss) {                   \
      int tt = (CB) * PF + ss;                                            \
      int t = d ? (1023 - tt) : tt;                                       \
      float f = sigmoidf_(A1[ss] + vf * c + bf);                          \
      float c2 = f * c + (1.f - f) * A0[ss];                              \
      float r = sigmoidf_(A2[ss] + vr * c2 + br);                         \
      ob[(size_t)t * 16384] = r * c2 + (1.f - r) * RX[ss];                \
      c = c2;                                                             \
    }                                                                     \
  }

  LOAD_CHUNK(0, Aa0, Aa1, Aa2, Arx);
  for (int cb = 0; cb < 128; cb += 2) {
    LOAD_CHUNK(cb + 1, Ba0, Ba1, Ba2, Brx);
    COMP_CHUNK(cb, Aa0, Aa1, Aa2, Arx);
    if (cb + 2 < 128) LOAD_CHUNK(cb + 2, Aa0, Aa1, Aa2, Arx);
    COMP_CHUNK(cb + 1, Ba0, Ba1, Ba2, Brx);
  }
#undef LOAD_CHUNK
#undef COMP_CHUNK
}

// ------------- final LN (1024) + classifier (1024x30), out (16,1024,30) ------
__global__ __launch_bounds__(256) void ln_cls(const float* __restrict__ s2,
    const float* __restrict__ g, const float* __restrict__ b,
    const float* __restrict__ W, float* __restrict__ out) {
  int r = blockIdx.x;        // t*16 + n
  int t = r >> 4, n = r & 15;
  int tid = threadIdx.x;
  const float* row = s2 + (size_t)r * 1024;
  float4 v = *(const float4*)&row[tid * 4];
  float sum = v.x + v.y + v.z + v.w;
  float ss = v.x * v.x + v.y * v.y + v.z * v.z + v.w * v.w;
#pragma unroll
  for (int off = 32; off > 0; off >>= 1) {
    sum += __shfl_down(sum, off);
    ss  += __shfl_down(ss, off);
  }
  __shared__ float red[128];
  int lane = tid & 63, wave = tid >> 6;
  if (lane == 0) { red[wave] = sum; red[4 + wave] = ss; }
  __syncthreads();
  sum = red[0] + red[1] + red[2] + red[3];
  ss  = red[4] + red[5] + red[6] + red[7];
  float mean = sum * (1.f / 1024.f);
  float var = ss * (1.f / 1024.f) - mean * mean;
  float inv = rsqrtf(var + 1e-5f);
  float4 gv = *(const float4*)&g[tid * 4];
  float4 bv = *(const float4*)&b[tid * 4];
  float y0 = (v.x - mean) * inv * gv.x + bv.x;
  float y1 = (v.y - mean) * inv * gv.y + bv.y;
  float y2 = (v.z - mean) * inv * gv.z + bv.z;
  float y3 = (v.w - mean) * inv * gv.w + bv.w;
  const float* wp = W + (size_t)tid * 120;
  float acc[30];
#pragma unroll
  for (int jj = 0; jj < 30; ++jj)
    acc[jj] = y0 * wp[jj] + y1 * wp[30 + jj] + y2 * wp[60 + jj] + y3 * wp[90 + jj];
  __syncthreads();
#pragma unroll
  for (int jj = 0; jj < 30; ++jj) {
    float vs = acc[jj];
    vs += __shfl_down(vs, 32);
    vs += __shfl_down(vs, 16);
    vs += __shfl_down(vs, 8);
    vs += __shfl_down(vs, 4);
    vs += __shfl_down(vs, 2);
    vs += __shfl_down(vs, 1);
    if (lane == 0) red[wave * 30 + jj] = vs;
  }
  __syncthreads();
  if (tid < 30) {
    float tot = red[tid] + red[30 + tid] + red[60 + tid] + red[90 + tid];
    out[(size_t)n * 30720 + t * 30 + tid] = tot;
  }
}

extern "C" void kernel_launch(void* const* d_in, const int* in_sizes, int n_in,
                              void* d_out, int out_size, void* d_ws, size_t ws_size,
                              hipStream_t stream) {
  const float* x        = (const float*)d_in[0];
  const float* conv0_w  = (const float*)d_in[1];
  const float* conv0_b  = (const float*)d_in[2];
  const float* rconv1_w = (const float*)d_in[3];
  const float* rconv1_b = (const float*)d_in[4];
  const float* rbn1_g   = (const float*)d_in[5];
  const float* rbn1_b   = (const float*)d_in[6];
  const float* rbn1_m   = (const float*)d_in[7];
  const float* rbn1_v   = (const float*)d_in[8];
  const float* rconv2_w = (const float*)d_in[9];
  const float* rconv2_b = (const float*)d_in[10];
  const float* rbn2_g   = (const float*)d_in[11];
  const float* rbn2_b   = (const float*)d_in[12];
  const float* rbn2_m   = (const float*)d_in[13];
  const float* rbn2_v   = (const float*)d_in[14];
  const float* ln0_g    = (const float*)d_in[15];
  const float* ln0_b    = (const float*)d_in[16];
  const float* wproj0   = (const float*)d_in[17];
  const float* w0       = (const float*)d_in[18];
  const float* vc0      = (const float*)d_in[19];
  const float* bias0    = (const float*)d_in[20];
  const float* ln_g     = (const float*)d_in[21];
  const float* ln_b     = (const float*)d_in[22];
  const float* wproj    = (const float*)d_in[23];
  const float* w        = (const float*)d_in[24];
  const float* vc       = (const float*)d_in[25];
  const float* bias     = (const float*)d_in[26];
  const float* cln_g    = (const float*)d_in[27];
  const float* cln_b    = (const float*)d_in[28];
  const float* cls_w    = (const float*)d_in[29];
  float* out = (float*)d_out;

  // Two 128 MiB arenas (256 MiB total).
  float* Af = (float*)d_ws;
  float* Bf = Af + 33554432;
  __hip_bfloat16* Ah = (__hip_bfloat16*)Af;    // 67.1M bf16 elems
  __hip_bfloat16* Bh = (__hip_bfloat16*)Bf;

  // conv stem + residual blocks (fp32, A = h, B = temp)
  conv_stem<<<131072, 256, 0, stream>>>(x, conv0_w, conv0_b, Af);
  for (int i = 0; i < 3; ++i) {
    conv3x3_tile<0><<<dim3(8, 64, 16), 256, 0, stream>>>(Af, rconv1_w + i * 9216,
        rconv1_b + i * 32, rbn1_g + i * 32, rbn1_b + i * 32,
        rbn1_m + i * 32, rbn1_v + i * 32, Bf);
    conv3x3_tile<1><<<dim3(8, 64, 16), 256, 0, stream>>>(Bf, rconv2_w + i * 9216,
        rconv2_b + i * 32, rbn2_g + i * 32, rbn2_b + i * 32,
        rbn2_m + i * 32, rbn2_v + i * 32, Af);
  }
  // (16,32,64,1024) -> s0 (1024 x 32768) into B
  transpose_k<<<dim3(32, 1024), dim3(32, 8), 0, stream>>>(Af, Bf);

  // ---- SRU layer 0 (k=4, F=2048) ----
  __hip_bfloat16* xn0  = Ah;                     // 16384x2048 bf16 (64 MB)
  __hip_bfloat16* Wp0t = Ah + 33554432;          // 256x2048 bf16 (1 MB)
  __hip_bfloat16* tmp0 = Bh;                     // 16384x256 bf16 (8 MB)
  __hip_bfloat16* W0t  = Bh + 8388608;           // 4096x256 bf16 (2 MB)
  __hip_bfloat16* U    = Ah;                     // 16384x4096 bf16 (128 MB)
  float* s2 = Bf;                                // 16384x1024 fp32 (64 MB)

  ln_rows_h<2><<<16384, 256, 0, stream>>>(Bf, ln0_g, ln0_b, xn0);
  wt_bf16<<<dim3(8, 64), dim3(32, 8), 0, stream>>>(wproj0, Wp0t, 2048, 256);
  gemm_bf16<<<dim3(2, 128), 256, 0, stream>>>(xn0, Wp0t, tmp0, 16384, 256, 2048);
  wt_bf16<<<dim3(128, 8), dim3(32, 8), 0, stream>>>(w0, W0t, 256, 4096);
  gemm_bf16<<<dim3(32, 128), 256, 0, stream>>>(tmp0, W0t, U, 16384, 4096, 256);
  sru_scan<<<256, 64, 0, stream>>>(U, nullptr, vc0, bias0, s2, 4);

  // ---- SRU layers 1..3 (k=3, F=1024) ----
  __hip_bfloat16* xn3  = Bh + 33554432;          // 16384x1024 bf16 (32 MB @ B+64MB)
  __hip_bfloat16* tmp3 = Ah + 52428800;          // 16384x256 bf16 (8 MB @ A+100MB)
  __hip_bfloat16* Wt3  = Ah + 57671680;          // 3072x256 bf16 (1.5 MB @ A+110MB)
  __hip_bfloat16* Wpt3 = Ah + 62914560;          // 256x1024 bf16 (0.5 MB @ A+120MB)
  for (int i = 0; i < 3; ++i) {
    ln_rows_h<1><<<16384, 256, 0, stream>>>(s2, ln_g + i * 1024, ln_b + i * 1024, xn3);
    wt_bf16<<<dim3(8, 32), dim3(32, 8), 0, stream>>>(wproj + i * 262144, Wpt3,
                                                     1024, 256);
    gemm_bf16<<<dim3(2, 128), 256, 0, stream>>>(xn3, Wpt3, tmp3, 16384, 256, 1024);
    wt_bf16<<<dim3(96, 8), dim3(32, 8), 0, stream>>>(w + i * 786432, Wt3, 256, 3072);
    gemm_bf16<<<dim3(24, 128), 256, 0, stream>>>(tmp3, Wt3, U, 16384, 3072, 256);
    sru_scan<<<256, 64, 0, stream>>>(U, xn3, vc + i * 2048, bias + i * 2048, s2, 3);
  }

  // final LN + classifier
  ln_cls<<<16384, 256, 0, stream>>>(s2, cln_g, cln_b, cls_w, out);
}

// Round 5
// 1815.524 us; speedup vs baseline: 10.1086x; 2.4119x over previous
//
#include <hip/hip_runtime.h>
#include <hip/hip_bf16.h>
#include <math.h>

#define DEV __device__ __forceinline__

typedef __attribute__((ext_vector_type(8))) short short8;
typedef __attribute__((ext_vector_type(4))) float floatx4;

DEV float sigmoidf_(float x) { return 1.f / (1.f + __expf(-x)); }

union U8 { uint4 u; __hip_bfloat16 h[8]; };

// ------- conv stem: (16,1,128,2048) -> NHWC bf16 h[n][f][t][oc], s2 p1 -------
__global__ __launch_bounds__(256) void conv_stem_nhwc(const float* __restrict__ x,
    const float* __restrict__ w, const float* __restrict__ bias,
    __hip_bfloat16* __restrict__ out) {
  int idx = blockIdx.x * 256 + threadIdx.x;   // (n, f, t, ocq)
  int ocq = idx & 3;
  int t  = (idx >> 2) & 1023;
  int f  = (idx >> 12) & 63;
  int n  = idx >> 18;
  const float* xb = x + (size_t)n * 262144;
  float xv[9];
#pragma unroll
  for (int df = 0; df < 3; ++df) {
    int fi = 2 * f + df - 1;
#pragma unroll
    for (int dc = 0; dc < 3; ++dc) {
      int ti = 2 * t + dc - 1;
      xv[df * 3 + dc] = (fi >= 0 && fi < 128 && ti >= 0 && ti < 2048)
                          ? xb[fi * 2048 + ti] : 0.f;
    }
  }
  U8 o;
#pragma unroll
  for (int oo = 0; oo < 8; ++oo) {
    int oc = ocq * 8 + oo;
    float acc = bias[oc];
#pragma unroll
    for (int q = 0; q < 9; ++q) acc += w[oc * 9 + q] * xv[q];
    o.h[oo] = __float2bfloat16(acc);
  }
  *(uint4*)&out[(((size_t)n * 64 + f) * 1024 + t) * 32 + ocq * 8] = o.u;
}

// ----- weight swizzle: (32oc,32ic,3,3) fp32 -> [tap][oc][ic] bf16 (9216) -----
__global__ __launch_bounds__(256) void wtap_conv(const float* __restrict__ in,
    __hip_bfloat16* __restrict__ out) {
  int i = blockIdx.x * 256 + threadIdx.x;
  if (i < 9216) {
    int tap = i >> 10;
    int oc = (i >> 5) & 31;
    int ic = i & 31;
    out[i] = __float2bfloat16(in[(oc * 32 + ic) * 9 + tap]);
  }
}

// ------ residual conv 3x3 via MFMA implicit GEMM (NHWC bf16) + BN/res/ReLU ---
// block = (tb:8, f:64, n:16); t-tile 128. Wave w: 32 t x 32 oc, 36 MFMAs.
template <int ADD>
__global__ __launch_bounds__(256) void conv_mfma(const __hip_bfloat16* __restrict__ Hin,
    const __hip_bfloat16* __restrict__ wt,      // [9][32][32] bf16
    const float* __restrict__ cb, const float* __restrict__ bg,
    const float* __restrict__ bb, const float* __restrict__ bm,
    const float* __restrict__ bv, __hip_bfloat16* Hres) {
  __shared__ __hip_bfloat16 sIn[3 * 130 * 40];  // [df][p][ic pad40] 31.2 KB
  __hip_bfloat16* sOut = sIn;                   // reuse after barrier [128][40]
  const int tid = threadIdx.x;
  const int tb = blockIdx.x, f = blockIdx.y, n = blockIdx.z;
  const int t0 = tb * 128;
  const __hip_bfloat16* Hb = Hin + (size_t)n * 64 * 1024 * 32;

  // stage input halo: 3 df x 130 p x 32 ic (uint4 chunks of 8 ic)
  for (int c = tid; c < 1560; c += 256) {
    int df = c / 520;
    int r = c - df * 520;
    int p = r >> 2, icq = r & 3;
    int fi = f + df - 1;
    int tg = t0 + p - 1;
    uint4 v = {0, 0, 0, 0};
    if (fi >= 0 && fi < 64 && tg >= 0 && tg < 1024)
      v = *(const uint4*)&Hb[((size_t)fi * 1024 + tg) * 32 + icq * 8];
    *(uint4*)&sIn[(df * 130 + p) * 40 + icq * 8] = v;
  }

  const int lane = tid & 63, wave = tid >> 6;
  const int fr = lane & 15, fq = lane >> 4;
  // B-fragments: 9 taps x 2 oc-halves, in registers
  short8 bfrag[9][2];
#pragma unroll
  for (int tap = 0; tap < 9; ++tap)
#pragma unroll
    for (int j = 0; j < 2; ++j)
      bfrag[tap][j] = *(const short8*)&wt[(tap * 32 + j * 16 + fr) * 32 + fq * 8];

  __syncthreads();

  const int t0w = wave * 32;
  floatx4 acc[2][2];
#pragma unroll
  for (int mi = 0; mi < 2; ++mi)
#pragma unroll
    for (int j = 0; j < 2; ++j) acc[mi][j] = (floatx4){0.f, 0.f, 0.f, 0.f};

#pragma unroll
  for (int mi = 0; mi < 2; ++mi) {
    int tbase = t0w + mi * 16;
#pragma unroll
    for (int df = 0; df < 3; ++df)
#pragma unroll
      for (int dc = 0; dc < 3; ++dc) {
        int p = tbase + fr + dc;
        short8 af = *(const short8*)&sIn[(df * 130 + p) * 40 + fq * 8];
        acc[mi][0] = __builtin_amdgcn_mfma_f32_16x16x32_bf16(
            af, bfrag[df * 3 + dc][0], acc[mi][0], 0, 0, 0);
        acc[mi][1] = __builtin_amdgcn_mfma_f32_16x16x32_bf16(
            af, bfrag[df * 3 + dc][1], acc[mi][1], 0, 0, 0);
      }
  }

  // BN fold (fp32): y = conv*scale + shift
  float sc0 = bg[fr] * rsqrtf(bv[fr] + 1e-5f);
  float sh0 = (cb[fr] - bm[fr]) * sc0 + bb[fr];
  float sc1 = bg[fr + 16] * rsqrtf(bv[fr + 16] + 1e-5f);
  float sh1 = (cb[fr + 16] - bm[fr + 16]) * sc1 + bb[fr + 16];

  __syncthreads();                              // all A-frag reads done
#pragma unroll
  for (int mi = 0; mi < 2; ++mi)
#pragma unroll
    for (int j = 0; j < 2; ++j) {
      float sc = j ? sc1 : sc0, sh = j ? sh1 : sh0;
#pragma unroll
      for (int reg = 0; reg < 4; ++reg) {
        int t_l = t0w + mi * 16 + fq * 4 + reg;
        sOut[t_l * 40 + j * 16 + fr] = __float2bfloat16(acc[mi][j][reg] * sc + sh);
      }
    }
  __syncthreads();

  // coalesced writeout (+res+relu): 512 uint4 chunks
  for (int c = tid; c < 512; c += 256) {
    int t_l = c >> 2, icq = c & 3;
    U8 y;
    y.u = *(uint4*)&sOut[t_l * 40 + icq * 8];
    size_t addr = (((size_t)n * 64 + f) * 1024 + t0 + t_l) * 32 + icq * 8;
    U8 o;
    if (ADD) {
      U8 r;
      r.u = *(const uint4*)&Hres[addr];
#pragma unroll
      for (int i = 0; i < 8; ++i)
        o.h[i] = __float2bfloat16(
            fmaxf(__bfloat162float(y.h[i]) + __bfloat162float(r.h[i]), 0.f));
    } else {
#pragma unroll
      for (int i = 0; i < 8; ++i)
        o.h[i] = __float2bfloat16(fmaxf(__bfloat162float(y.h[i]), 0.f));
    }
    *(uint4*)&Hres[addr] = o.u;
  }
}

// ------ LN over NHWC row (t,n): F=2048, k-order k' = f*32+ic, bf16 out -------
__global__ __launch_bounds__(256) void ln_nhwc(const __hip_bfloat16* __restrict__ H,
    const float* __restrict__ g, const float* __restrict__ b,
    __hip_bfloat16* __restrict__ xn) {
  int r = blockIdx.x;          // r = t*16 + n
  int t = r >> 4, n = r & 15;
  int tid = threadIdx.x;
  int f = tid >> 2, icq = tid & 3;
  U8 v;
  v.u = *(const uint4*)&H[(((size_t)n * 64 + f) * 1024 + t) * 32 + icq * 8];
  float xv[8];
  float sum = 0.f, ss = 0.f;
#pragma unroll
  for (int i = 0; i < 8; ++i) {
    xv[i] = __bfloat162float(v.h[i]);
    sum += xv[i];
    ss += xv[i] * xv[i];
  }
#pragma unroll
  for (int off = 32; off > 0; off >>= 1) {
    sum += __shfl_down(sum, off);
    ss  += __shfl_down(ss, off);
  }
  __shared__ float red[8];
  int lane = tid & 63, wave = tid >> 6;
  if (lane == 0) { red[wave] = sum; red[4 + wave] = ss; }
  __syncthreads();
  sum = red[0] + red[1] + red[2] + red[3];
  ss  = red[4] + red[5] + red[6] + red[7];
  float mean = sum * (1.f / 2048.f);
  float var = ss * (1.f / 2048.f) - mean * mean;
  float inv = rsqrtf(var + 1e-5f);
  U8 o;
#pragma unroll
  for (int i = 0; i < 8; ++i) {
    int cf = (icq * 8 + i) * 64 + f;
    o.h[i] = __float2bfloat16((xv[i] - mean) * inv * g[cf] + b[cf]);
  }
  *(uint4*)&xn[(size_t)r * 2048 + tid * 8] = o.u;
}

// -- wproj0 permuted transpose: Wp0t[p][k'=f*32+ic] = wproj0[ic*64+f][p] bf16 --
__global__ __launch_bounds__(256) void wt_perm0(const float* __restrict__ in,
    __hip_bfloat16* __restrict__ out) {
  int i = blockIdx.x * 256 + threadIdx.x;      // 524288
  int p = i >> 11, kp = i & 2047;
  int ic = kp & 31, f = kp >> 5;
  out[i] = __float2bfloat16(in[(ic * 64 + f) * 256 + p]);
}

// -------- LayerNorm fp32 rows F=1024 -> bf16 out -----------------------------
__global__ __launch_bounds__(256) void ln_rows_h(const float* __restrict__ in,
    const float* __restrict__ g, const float* __restrict__ b,
    __hip_bfloat16* __restrict__ out) {
  int r = blockIdx.x;
  int tid = threadIdx.x;
  const float* row = in + (size_t)r * 1024;
  float4 v = *(const float4*)&row[tid * 4];
  float sum = v.x + v.y + v.z + v.w;
  float ss = v.x * v.x + v.y * v.y + v.z * v.z + v.w * v.w;
#pragma unroll
  for (int off = 32; off > 0; off >>= 1) {
    sum += __shfl_down(sum, off);
    ss  += __shfl_down(ss, off);
  }
  __shared__ float red[8];
  int lane = tid & 63, wave = tid >> 6;
  if (lane == 0) { red[wave] = sum; red[4 + wave] = ss; }
  __syncthreads();
  sum = red[0] + red[1] + red[2] + red[3];
  ss  = red[4] + red[5] + red[6] + red[7];
  float mean = sum * (1.f / 1024.f);
  float var = ss * (1.f / 1024.f) - mean * mean;
  float inv = rsqrtf(var + 1e-5f);
  float4 gv = *(const float4*)&g[tid * 4];
  float4 bv = *(const float4*)&b[tid * 4];
  union { ushort4 u; __hip_bfloat16 h[4]; } o;
  o.h[0] = __float2bfloat16((v.x - mean) * inv * gv.x + bv.x);
  o.h[1] = __float2bfloat16((v.y - mean) * inv * gv.y + bv.y);
  o.h[2] = __float2bfloat16((v.z - mean) * inv * gv.z + bv.z);
  o.h[3] = __float2bfloat16((v.w - mean) * inv * gv.w + bv.w);
  *(ushort4*)&out[(size_t)r * 1024 + tid * 4] = o.u;
}

// ------- weight convert+transpose: in (K x N) fp32 -> out (N x K) bf16 -------
__global__ __launch_bounds__(256) void wt_bf16(const float* __restrict__ in,
    __hip_bfloat16* __restrict__ out, int K, int N) {
  __shared__ float tile[32][33];
  int x = threadIdx.x, y0 = threadIdx.y;
  int bn = blockIdx.x * 32;
  int bk = blockIdx.y * 32;
#pragma unroll
  for (int i = 0; i < 4; ++i) {
    int yy = y0 + i * 8;
    tile[yy][x] = in[(size_t)(bk + yy) * N + bn + x];
  }
  __syncthreads();
#pragma unroll
  for (int i = 0; i < 4; ++i) {
    int yy = y0 + i * 8;
    out[(size_t)(bn + yy) * K + bk + x] = __float2bfloat16(tile[x][yy]);
  }
}

// -------- bf16 MFMA GEMM: C(MxN) = A(MxK) @ Bt(NxK)^T, bf16 out --------------
__global__ __launch_bounds__(256) void gemm_bf16(const __hip_bfloat16* __restrict__ A,
    const __hip_bfloat16* __restrict__ Bt, __hip_bfloat16* __restrict__ C,
    int M, int N, int K) {
  __shared__ __hip_bfloat16 As[128 * 40];
  __shared__ __hip_bfloat16 Bs[128 * 40];
  const int tid = threadIdx.x;
  const int m0 = blockIdx.y * 128, n0 = blockIdx.x * 128;
  const int lane = tid & 63, wave = tid >> 6;
  const int wm = wave & 1, wn = wave >> 1;
  const int fr = lane & 15;
  const int fq = lane >> 4;
  floatx4 acc[4][4];
#pragma unroll
  for (int i = 0; i < 4; ++i)
#pragma unroll
    for (int j = 0; j < 4; ++j)
      acc[i][j] = (floatx4){0.f, 0.f, 0.f, 0.f};

  for (int k0 = 0; k0 < K; k0 += 32) {
    __syncthreads();
#pragma unroll
    for (int p = 0; p < 4; ++p) {
      int i = tid + p * 256;
      int half = i >> 9;
      int j = i & 511;
      int row = j >> 2, ch = j & 3;
      const __hip_bfloat16* src = half
          ? &Bt[(size_t)(n0 + row) * K + k0 + ch * 8]
          : &A[(size_t)(m0 + row) * K + k0 + ch * 8];
      __hip_bfloat16* dst = (half ? Bs : As) + row * 40 + ch * 8;
      *(uint4*)dst = *(const uint4*)src;
    }
    __syncthreads();

    short8 af[4], bf_[4];
#pragma unroll
    for (int i = 0; i < 4; ++i) {
      af[i]  = *(const short8*)&As[(wm * 64 + i * 16 + fr) * 40 + fq * 8];
      bf_[i] = *(const short8*)&Bs[(wn * 64 + i * 16 + fr) * 40 + fq * 8];
    }
#pragma unroll
    for (int i = 0; i < 4; ++i)
#pragma unroll
      for (int j = 0; j < 4; ++j)
        acc[i][j] = __builtin_amdgcn_mfma_f32_16x16x32_bf16(af[i], bf_[j],
                                                            acc[i][j], 0, 0, 0);
  }

#pragma unroll
  for (int i = 0; i < 4; ++i)
#pragma unroll
    for (int j = 0; j < 4; ++j)
#pragma unroll
      for (int reg = 0; reg < 4; ++reg) {
        int row = m0 + wm * 64 + i * 16 + fq * 4 + reg;
        int col = n0 + wn * 64 + j * 16 + fr;
        C[(size_t)row * N + col] = __float2bfloat16(acc[i][j][reg]);
      }
}

// ---------------- SRU bidirectional scan (U bf16, res bf16) ------------------
__global__ __launch_bounds__(64) void sru_scan(const __hip_bfloat16* __restrict__ U,
    const __hip_bfloat16* __restrict__ resx, const float* __restrict__ vc,
    const float* __restrict__ bias, float* __restrict__ out, int k) {
  int gid = blockIdx.x * 64 + threadIdx.x;
  int j = gid & 511;
  int n = (gid >> 9) & 15;
  int d = gid >> 13;
  float vf = vc[(d * 2 + 0) * 512 + j];
  float vr = vc[(d * 2 + 1) * 512 + j];
  float bf = bias[(d * 2 + 0) * 512 + j];
  float br = bias[(d * 2 + 1) * 512 + j];
  const bool k4 = (k == 4);
  const size_t tstride = (size_t)k * 16384;
  const __hip_bfloat16* Ub = U + (size_t)(n * 2 + d) * k * 512 + j;
  const __hip_bfloat16* Rb = k4 ? nullptr : (resx + (size_t)n * 1024 + d * 512 + j);
  float* ob = out + (size_t)n * 1024 + d * 512 + j;
  const int PF = 8;
  float Aa0[PF], Aa1[PF], Aa2[PF], Arx[PF];
  float Ba0[PF], Ba1[PF], Ba2[PF], Brx[PF];
  float c = 0.f;

#define LOAD_CHUNK(CB, A0, A1, A2, RX)                                    \
  {                                                                       \
    _Pragma("unroll") for (int ss = 0; ss < PF; ++ss) {                   \
      int tt = (CB) * PF + ss;                                            \
      int t = d ? (1023 - tt) : tt;                                       \
      size_t off = (size_t)t * tstride;                                   \
      A0[ss] = __bfloat162float(Ub[off]);                                 \
      A1[ss] = __bfloat162float(Ub[off + 512]);                           \
      A2[ss] = __bfloat162float(Ub[off + 1024]);                          \
      RX[ss] = k4 ? __bfloat162float(Ub[off + 1536])                      \
                  : __bfloat162float(Rb[(size_t)t * 16384]);              \
    }                                                                     \
  }

#define COMP_CHUNK(CB, A0, A1, A2, RX)                                    \
  {                                                                       \
    _Pragma("unroll") for (int ss = 0; ss < PF; ++ss) {                   \
      int tt = (CB) * PF + ss;                                            \
      int t = d ? (1023 - tt) : tt;                                       \
      float f = sigmoidf_(A1[ss] + vf * c + bf);                          \
      float c2 = f * c + (1.f - f) * A0[ss];                              \
      float r = sigmoidf_(A2[ss] + vr * c2 + br);                        \
      ob[(size_t)t * 16384] = r * c2 + (1.f - r) * RX[ss];                \
      c = c2;                                                             \
    }                                                                     \
  }

  LOAD_CHUNK(0, Aa0, Aa1, Aa2, Arx);
  for (int cb = 0; cb < 128; cb += 2) {
    LOAD_CHUNK(cb + 1, Ba0, Ba1, Ba2, Brx);
    COMP_CHUNK(cb, Aa0, Aa1, Aa2, Arx);
    if (cb + 2 < 128) LOAD_CHUNK(cb + 2, Aa0, Aa1, Aa2, Arx);
    COMP_CHUNK(cb + 1, Ba0, Ba1, Ba2, Brx);
  }
#undef LOAD_CHUNK
#undef COMP_CHUNK
}

// ------------- final LN (1024) + classifier (1024x30), out (16,1024,30) ------
__global__ __launch_bounds__(256) void ln_cls(const float* __restrict__ s2,
    const float* __restrict__ g, const float* __restrict__ b,
    const float* __restrict__ W, float* __restrict__ out) {
  int r = blockIdx.x;
  int t = r >> 4, n = r & 15;
  int tid = threadIdx.x;
  const float* row = s2 + (size_t)r * 1024;
  float4 v = *(const float4*)&row[tid * 4];
  float sum = v.x + v.y + v.z + v.w;
  float ss = v.x * v.x + v.y * v.y + v.z * v.z + v.w * v.w;
#pragma unroll
  for (int off = 32; off > 0; off >>= 1) {
    sum += __shfl_down(sum, off);
    ss  += __shfl_down(ss, off);
  }
  __shared__ float red[128];
  int lane = tid & 63, wave = tid >> 6;
  if (lane == 0) { red[wave] = sum; red[4 + wave] = ss; }
  __syncthreads();
  sum = red[0] + red[1] + red[2] + red[3];
  ss  = red[4] + red[5] + red[6] + red[7];
  float mean = sum * (1.f / 1024.f);
  float var = ss * (1.f / 1024.f) - mean * mean;
  float inv = rsqrtf(var + 1e-5f);
  float4 gv = *(const float4*)&g[tid * 4];
  float4 bv = *(const float4*)&b[tid * 4];
  float y0 = (v.x - mean) * inv * gv.x + bv.x;
  float y1 = (v.y - mean) * inv * gv.y + bv.y;
  float y2 = (v.z - mean) * inv * gv.z + bv.z;
  float y3 = (v.w - mean) * inv * gv.w + bv.w;
  const float* wp = W + (size_t)tid * 120;
  float acc[30];
#pragma unroll
  for (int jj = 0; jj < 30; ++jj)
    acc[jj] = y0 * wp[jj] + y1 * wp[30 + jj] + y2 * wp[60 + jj] + y3 * wp[90 + jj];
  __syncthreads();
#pragma unroll
  for (int jj = 0; jj < 30; ++jj) {
    float vs = acc[jj];
    vs += __shfl_down(vs, 32);
    vs += __shfl_down(vs, 16);
    vs += __shfl_down(vs, 8);
    vs += __shfl_down(vs, 4);
    vs += __shfl_down(vs, 2);
    vs += __shfl_down(vs, 1);
    if (lane == 0) red[wave * 30 + jj] = vs;
  }
  __syncthreads();
  if (tid < 30) {
    float tot = red[tid] + red[30 + tid] + red[60 + tid] + red[90 + tid];
    out[(size_t)n * 30720 + t * 30 + tid] = tot;
  }
}

extern "C" void kernel_launch(void* const* d_in, const int* in_sizes, int n_in,
                              void* d_out, int out_size, void* d_ws, size_t ws_size,
                              hipStream_t stream) {
  const float* x        = (const float*)d_in[0];
  const float* conv0_w  = (const float*)d_in[1];
  const float* conv0_b  = (const float*)d_in[2];
  const float* rconv1_w = (const float*)d_in[3];
  const float* rconv1_b = (const float*)d_in[4];
  const float* rbn1_g   = (const float*)d_in[5];
  const float* rbn1_b   = (const float*)d_in[6];
  const float* rbn1_m   = (const float*)d_in[7];
  const float* rbn1_v   = (const float*)d_in[8];
  const float* rconv2_w = (const float*)d_in[9];
  const float* rconv2_b = (const float*)d_in[10];
  const float* rbn2_g   = (const float*)d_in[11];
  const float* rbn2_b   = (const float*)d_in[12];
  const float* rbn2_m   = (const float*)d_in[13];
  const float* rbn2_v   = (const float*)d_in[14];
  const float* ln0_g    = (const float*)d_in[15];
  const float* ln0_b    = (const float*)d_in[16];
  const float* wproj0   = (const float*)d_in[17];
  const float* w0       = (const float*)d_in[18];
  const float* vc0      = (const float*)d_in[19];
  const float* bias0    = (const float*)d_in[20];
  const float* ln_g     = (const float*)d_in[21];
  const float* ln_b     = (const float*)d_in[22];
  const float* wproj    = (const float*)d_in[23];
  const float* w        = (const float*)d_in[24];
  const float* vc       = (const float*)d_in[25];
  const float* bias     = (const float*)d_in[26];
  const float* cln_g    = (const float*)d_in[27];
  const float* cln_b    = (const float*)d_in[28];
  const float* cls_w    = (const float*)d_in[29];
  float* out = (float*)d_out;

  // Two 128 MiB arenas.
  float* Af = (float*)d_ws;
  float* Bf = Af + 33554432;
  __hip_bfloat16* Ah = (__hip_bfloat16*)Af;
  __hip_bfloat16* Bh = (__hip_bfloat16*)Bf;

  __hip_bfloat16* hA   = Ah;                   // NHWC h, 67.1 MB
  __hip_bfloat16* hB   = Bh;                   // NHWC temp, 67.1 MB
  __hip_bfloat16* wt1h = Ah + 62914560;        // 18 KB @ A+120MB
  __hip_bfloat16* wt2h = Ah + 62931944 + 8;    // next 18 KB (aligned region)

  conv_stem_nhwc<<<16384, 256, 0, stream>>>(x, conv0_w, conv0_b, hA);
  for (int i = 0; i < 3; ++i) {
    wtap_conv<<<36, 256, 0, stream>>>(rconv1_w + i * 9216, wt1h);
    conv_mfma<0><<<dim3(8, 64, 16), 256, 0, stream>>>(hA, wt1h,
        rconv1_b + i * 32, rbn1_g + i * 32, rbn1_b + i * 32,
        rbn1_m + i * 32, rbn1_v + i * 32, hB);
    wtap_conv<<<36, 256, 0, stream>>>(rconv2_w + i * 9216, wt2h);
    conv_mfma<1><<<dim3(8, 64, 16), 256, 0, stream>>>(hB, wt2h,
        rconv2_b + i * 32, rbn2_g + i * 32, rbn2_b + i * 32,
        rbn2_m + i * 32, rbn2_v + i * 32, hA);
  }

  // ---- SRU layer 0 (k=4, F=2048) ----
  __hip_bfloat16* xn0  = Bh;                   // 64 MB (hB dead)
  __hip_bfloat16* Wp0t = Ah + 52428800;        // 1 MB @ A+100MB (past hA? hA=67MB; ok)
  __hip_bfloat16* tmp0 = Bh + 50331648;        // 8 MB @ B+96MB
  __hip_bfloat16* W0t  = Bh + 57671680;        // 2 MB @ B+110MB
  __hip_bfloat16* U    = Ah;                   // 128 MB (hA, Wp0t dead by then)
  float* s2 = Bf;                              // 64 MB fp32 @ B (xn0 dead)

  ln_nhwc<<<16384, 256, 0, stream>>>(hA, ln0_g, ln0_b, xn0);
  wt_perm0<<<2048, 256, 0, stream>>>(wproj0, Wp0t);
  gemm_bf16<<<dim3(2, 128), 256, 0, stream>>>(xn0, Wp0t, tmp0, 16384, 256, 2048);
  wt_bf16<<<dim3(128, 8), dim3(32, 8), 0, stream>>>(w0, W0t, 256, 4096);
  gemm_bf16<<<dim3(32, 128), 256, 0, stream>>>(tmp0, W0t, U, 16384, 4096, 256);
  sru_scan<<<256, 64, 0, stream>>>(U, nullptr, vc0, bias0, s2, 4);

  // ---- SRU layers 1..3 (k=3, F=1024) ----
  __hip_bfloat16* xn3  = Bh + 33554432;        // 32 MB @ B+64MB
  __hip_bfloat16* tmp3 = Bh + 50331648;        // 8 MB @ B+96MB
  __hip_bfloat16* Wt3  = Bh + 54525952;        // 1.5 MB @ B+104MB
  __hip_bfloat16* Wpt3 = Bh + 55574528;        // 0.5 MB @ B+106MB
  for (int i = 0; i < 3; ++i) {
    ln_rows_h<<<16384, 256, 0, stream>>>(s2, ln_g + i * 1024, ln_b + i * 1024, xn3);
    wt_bf16<<<dim3(8, 32), dim3(32, 8), 0, stream>>>(wproj + i * 262144, Wpt3,
                                                     1024, 256);
    gemm_bf16<<<dim3(2, 128), 256, 0, stream>>>(xn3, Wpt3, tmp3, 16384, 256, 1024);
    wt_bf16<<<dim3(96, 8), dim3(32, 8), 0, stream>>>(w + i * 786432, Wt3, 256, 3072);
    gemm_bf16<<<dim3(24, 128), 256, 0, stream>>>(tmp3, Wt3, U, 16384, 3072, 256);
    sru_scan<<<256, 64, 0, stream>>>(U, xn3, vc + i * 2048, bias + i * 2048, s2, 3);
  }

  ln_cls<<<16384, 256, 0, stream>>>(s2, cln_g, cln_b, cls_w, out);
}

// Round 6
// 1639.038 us; speedup vs baseline: 11.1970x; 1.1077x over previous
//
#include <hip/hip_runtime.h>
#include <hip/hip_bf16.h>
#include <math.h>

#define DEV __device__ __forceinline__

typedef __attribute__((ext_vector_type(8))) short short8;
typedef __attribute__((ext_vector_type(4))) float floatx4;

DEV float sigmoidf_(float x) { return 1.f / (1.f + __expf(-x)); }

union U8 { uint4 u; __hip_bfloat16 h[8]; };

// ------- conv stem: (16,1,128,2048) -> NHWC bf16 h[n][f][t][oc], s2 p1 -------
__global__ __launch_bounds__(256) void conv_stem_nhwc(const float* __restrict__ x,
    const float* __restrict__ w, const float* __restrict__ bias,
    __hip_bfloat16* __restrict__ out) {
  int idx = blockIdx.x * 256 + threadIdx.x;   // (n, f, t, ocq)
  int ocq = idx & 3;
  int t  = (idx >> 2) & 1023;
  int f  = (idx >> 12) & 63;
  int n  = idx >> 18;
  const float* xb = x + (size_t)n * 262144;
  float xv[9];
#pragma unroll
  for (int df = 0; df < 3; ++df) {
    int fi = 2 * f + df - 1;
#pragma unroll
    for (int dc = 0; dc < 3; ++dc) {
      int ti = 2 * t + dc - 1;
      xv[df * 3 + dc] = (fi >= 0 && fi < 128 && ti >= 0 && ti < 2048)
                          ? xb[fi * 2048 + ti] : 0.f;
    }
  }
  U8 o;
#pragma unroll
  for (int oo = 0; oo < 8; ++oo) {
    int oc = ocq * 8 + oo;
    float acc = bias[oc];
#pragma unroll
    for (int q = 0; q < 9; ++q) acc += w[oc * 9 + q] * xv[q];
    o.h[oo] = __float2bfloat16(acc);
  }
  *(uint4*)&out[(((size_t)n * 64 + f) * 1024 + t) * 32 + ocq * 8] = o.u;
}

// ----- weight swizzle: (32oc,32ic,3,3) fp32 -> [tap][oc][ic] bf16 (9216) -----
__global__ __launch_bounds__(256) void wtap_conv(const float* __restrict__ in,
    __hip_bfloat16* __restrict__ out) {
  int i = blockIdx.x * 256 + threadIdx.x;
  if (i < 9216) {
    int tap = i >> 10;
    int oc = (i >> 5) & 31;
    int ic = i & 31;
    out[i] = __float2bfloat16(in[(oc * 32 + ic) * 9 + tap]);
  }
}

// ------ residual conv 3x3 via MFMA implicit GEMM (NHWC bf16) + BN/res/ReLU ---
template <int ADD>
__global__ __launch_bounds__(256) void conv_mfma(const __hip_bfloat16* __restrict__ Hin,
    const __hip_bfloat16* __restrict__ wt,      // [9][32][32] bf16
    const float* __restrict__ cb, const float* __restrict__ bg,
    const float* __restrict__ bb, const float* __restrict__ bm,
    const float* __restrict__ bv, __hip_bfloat16* Hres) {
  __shared__ __hip_bfloat16 sIn[3 * 130 * 40];
  __hip_bfloat16* sOut = sIn;
  const int tid = threadIdx.x;
  const int tb = blockIdx.x, f = blockIdx.y, n = blockIdx.z;
  const int t0 = tb * 128;
  const __hip_bfloat16* Hb = Hin + (size_t)n * 64 * 1024 * 32;

  for (int c = tid; c < 1560; c += 256) {
    int df = c / 520;
    int r = c - df * 520;
    int p = r >> 2, icq = r & 3;
    int fi = f + df - 1;
    int tg = t0 + p - 1;
    uint4 v = {0, 0, 0, 0};
    if (fi >= 0 && fi < 64 && tg >= 0 && tg < 1024)
      v = *(const uint4*)&Hb[((size_t)fi * 1024 + tg) * 32 + icq * 8];
    *(uint4*)&sIn[(df * 130 + p) * 40 + icq * 8] = v;
  }

  const int lane = tid & 63, wave = tid >> 6;
  const int fr = lane & 15, fq = lane >> 4;
  short8 bfrag[9][2];
#pragma unroll
  for (int tap = 0; tap < 9; ++tap)
#pragma unroll
    for (int j = 0; j < 2; ++j)
      bfrag[tap][j] = *(const short8*)&wt[(tap * 32 + j * 16 + fr) * 32 + fq * 8];

  __syncthreads();

  const int t0w = wave * 32;
  floatx4 acc[2][2];
#pragma unroll
  for (int mi = 0; mi < 2; ++mi)
#pragma unroll
    for (int j = 0; j < 2; ++j) acc[mi][j] = (floatx4){0.f, 0.f, 0.f, 0.f};

#pragma unroll
  for (int mi = 0; mi < 2; ++mi) {
    int tbase = t0w + mi * 16;
#pragma unroll
    for (int df = 0; df < 3; ++df)
#pragma unroll
      for (int dc = 0; dc < 3; ++dc) {
        int p = tbase + fr + dc;
        short8 af = *(const short8*)&sIn[(df * 130 + p) * 40 + fq * 8];
        acc[mi][0] = __builtin_amdgcn_mfma_f32_16x16x32_bf16(
            af, bfrag[df * 3 + dc][0], acc[mi][0], 0, 0, 0);
        acc[mi][1] = __builtin_amdgcn_mfma_f32_16x16x32_bf16(
            af, bfrag[df * 3 + dc][1], acc[mi][1], 0, 0, 0);
      }
  }

  float sc0 = bg[fr] * rsqrtf(bv[fr] + 1e-5f);
  float sh0 = (cb[fr] - bm[fr]) * sc0 + bb[fr];
  float sc1 = bg[fr + 16] * rsqrtf(bv[fr + 16] + 1e-5f);
  float sh1 = (cb[fr + 16] - bm[fr + 16]) * sc1 + bb[fr + 16];

  __syncthreads();
#pragma unroll
  for (int mi = 0; mi < 2; ++mi)
#pragma unroll
    for (int j = 0; j < 2; ++j) {
      float sc = j ? sc1 : sc0, sh = j ? sh1 : sh0;
#pragma unroll
      for (int reg = 0; reg < 4; ++reg) {
        int t_l = t0w + mi * 16 + fq * 4 + reg;
        sOut[t_l * 40 + j * 16 + fr] = __float2bfloat16(acc[mi][j][reg] * sc + sh);
      }
    }
  __syncthreads();

  for (int c = tid; c < 512; c += 256) {
    int t_l = c >> 2, icq = c & 3;
    U8 y;
    y.u = *(uint4*)&sOut[t_l * 40 + icq * 8];
    size_t addr = (((size_t)n * 64 + f) * 1024 + t0 + t_l) * 32 + icq * 8;
    U8 o;
    if (ADD) {
      U8 r;
      r.u = *(const uint4*)&Hres[addr];
#pragma unroll
      for (int i = 0; i < 8; ++i)
        o.h[i] = __float2bfloat16(
            fmaxf(__bfloat162float(y.h[i]) + __bfloat162float(r.h[i]), 0.f));
    } else {
#pragma unroll
      for (int i = 0; i < 8; ++i)
        o.h[i] = __float2bfloat16(fmaxf(__bfloat162float(y.h[i]), 0.f));
    }
    *(uint4*)&Hres[addr] = o.u;
  }
}

// ------ LN over NHWC row (t,n): F=2048, k-order k' = f*32+ic, bf16 out -------
__global__ __launch_bounds__(256) void ln_nhwc(const __hip_bfloat16* __restrict__ H,
    const float* __restrict__ g, const float* __restrict__ b,
    __hip_bfloat16* __restrict__ xn) {
  int r = blockIdx.x;          // r = t*16 + n
  int t = r >> 4, n = r & 15;
  int tid = threadIdx.x;
  int f = tid >> 2, icq = tid & 3;
  U8 v;
  v.u = *(const uint4*)&H[(((size_t)n * 64 + f) * 1024 + t) * 32 + icq * 8];
  float xv[8];
  float sum = 0.f, ss = 0.f;
#pragma unroll
  for (int i = 0; i < 8; ++i) {
    xv[i] = __bfloat162float(v.h[i]);
    sum += xv[i];
    ss += xv[i] * xv[i];
  }
#pragma unroll
  for (int off = 32; off > 0; off >>= 1) {
    sum += __shfl_down(sum, off);
    ss  += __shfl_down(ss, off);
  }
  __shared__ float red[8];
  int lane = tid & 63, wave = tid >> 6;
  if (lane == 0) { red[wave] = sum; red[4 + wave] = ss; }
  __syncthreads();
  sum = red[0] + red[1] + red[2] + red[3];
  ss  = red[4] + red[5] + red[6] + red[7];
  float mean = sum * (1.f / 2048.f);
  float var = ss * (1.f / 2048.f) - mean * mean;
  float inv = rsqrtf(var + 1e-5f);
  U8 o;
#pragma unroll
  for (int i = 0; i < 8; ++i) {
    int cf = (icq * 8 + i) * 64 + f;
    o.h[i] = __float2bfloat16((xv[i] - mean) * inv * g[cf] + b[cf]);
  }
  *(uint4*)&xn[(size_t)r * 2048 + tid * 8] = o.u;
}

// -- wproj0 permuted transpose: Wp0t[p][k'=f*32+ic] = wproj0[ic*64+f][p] bf16 --
__global__ __launch_bounds__(256) void wt_perm0(const float* __restrict__ in,
    __hip_bfloat16* __restrict__ out) {
  int i = blockIdx.x * 256 + threadIdx.x;
  int p = i >> 11, kp = i & 2047;
  int ic = kp & 31, f = kp >> 5;
  out[i] = __float2bfloat16(in[(ic * 64 + f) * 256 + p]);
}

// -------- LayerNorm bf16 rows F=1024 -> bf16 out -----------------------------
__global__ __launch_bounds__(256) void ln_rows_h(const __hip_bfloat16* __restrict__ in,
    const float* __restrict__ g, const float* __restrict__ b,
    __hip_bfloat16* __restrict__ out) {
  int r = blockIdx.x;
  int tid = threadIdx.x;
  union { ushort4 u; __hip_bfloat16 h[4]; } iv;
  iv.u = *(const ushort4*)&in[(size_t)r * 1024 + tid * 4];
  float x0 = __bfloat162float(iv.h[0]);
  float x1 = __bfloat162float(iv.h[1]);
  float x2 = __bfloat162float(iv.h[2]);
  float x3 = __bfloat162float(iv.h[3]);
  float sum = x0 + x1 + x2 + x3;
  float ss = x0 * x0 + x1 * x1 + x2 * x2 + x3 * x3;
#pragma unroll
  for (int off = 32; off > 0; off >>= 1) {
    sum += __shfl_down(sum, off);
    ss  += __shfl_down(ss, off);
  }
  __shared__ float red[8];
  int lane = tid & 63, wave = tid >> 6;
  if (lane == 0) { red[wave] = sum; red[4 + wave] = ss; }
  __syncthreads();
  sum = red[0] + red[1] + red[2] + red[3];
  ss  = red[4] + red[5] + red[6] + red[7];
  float mean = sum * (1.f / 1024.f);
  float var = ss * (1.f / 1024.f) - mean * mean;
  float inv = rsqrtf(var + 1e-5f);
  float4 gv = *(const float4*)&g[tid * 4];
  float4 bv = *(const float4*)&b[tid * 4];
  union { ushort4 u; __hip_bfloat16 h[4]; } o;
  o.h[0] = __float2bfloat16((x0 - mean) * inv * gv.x + bv.x);
  o.h[1] = __float2bfloat16((x1 - mean) * inv * gv.y + bv.y);
  o.h[2] = __float2bfloat16((x2 - mean) * inv * gv.z + bv.z);
  o.h[3] = __float2bfloat16((x3 - mean) * inv * gv.w + bv.w);
  *(ushort4*)&out[(size_t)r * 1024 + tid * 4] = o.u;
}

// ------- weight convert+transpose: in (K x N) fp32 -> out (N x K) bf16 -------
__global__ __launch_bounds__(256) void wt_bf16(const float* __restrict__ in,
    __hip_bfloat16* __restrict__ out, int K, int N) {
  __shared__ float tile[32][33];
  int x = threadIdx.x, y0 = threadIdx.y;
  int bn = blockIdx.x * 32;
  int bk = blockIdx.y * 32;
#pragma unroll
  for (int i = 0; i < 4; ++i) {
    int yy = y0 + i * 8;
    tile[yy][x] = in[(size_t)(bk + yy) * N + bn + x];
  }
  __syncthreads();
#pragma unroll
  for (int i = 0; i < 4; ++i) {
    int yy = y0 + i * 8;
    out[(size_t)(bn + yy) * K + bk + x] = __float2bfloat16(tile[x][yy]);
  }
}

// ---- cls_w (1024x30) fp32 -> Wct (32x1024) bf16, rows >=30 zero -------------
__global__ __launch_bounds__(256) void wct_prep(const float* __restrict__ in,
    __hip_bfloat16* __restrict__ out) {
  int i = blockIdx.x * 256 + threadIdx.x;      // 32768
  int nn = i >> 10, kk = i & 1023;
  out[i] = __float2bfloat16(nn < 30 ? in[kk * 30 + nn] : 0.f);
}

// -------- bf16 MFMA GEMM: C(MxN) = A(MxK) @ Bt(NxK)^T, bf16 out --------------
__global__ __launch_bounds__(256) void gemm_bf16(const __hip_bfloat16* __restrict__ A,
    const __hip_bfloat16* __restrict__ Bt, __hip_bfloat16* __restrict__ C,
    int M, int N, int K) {
  __shared__ __hip_bfloat16 As[128 * 40];
  __shared__ __hip_bfloat16 Bs[128 * 40];
  const int tid = threadIdx.x;
  const int m0 = blockIdx.y * 128, n0 = blockIdx.x * 128;
  const int lane = tid & 63, wave = tid >> 6;
  const int wm = wave & 1, wn = wave >> 1;
  const int fr = lane & 15;
  const int fq = lane >> 4;
  floatx4 acc[4][4];
#pragma unroll
  for (int i = 0; i < 4; ++i)
#pragma unroll
    for (int j = 0; j < 4; ++j)
      acc[i][j] = (floatx4){0.f, 0.f, 0.f, 0.f};

  for (int k0 = 0; k0 < K; k0 += 32) {
    __syncthreads();
#pragma unroll
    for (int p = 0; p < 4; ++p) {
      int i = tid + p * 256;
      int half = i >> 9;
      int j = i & 511;
      int row = j >> 2, ch = j & 3;
      const __hip_bfloat16* src = half
          ? &Bt[(size_t)(n0 + row) * K + k0 + ch * 8]
          : &A[(size_t)(m0 + row) * K + k0 + ch * 8];
      __hip_bfloat16* dst = (half ? Bs : As) + row * 40 + ch * 8;
      *(uint4*)dst = *(const uint4*)src;
    }
    __syncthreads();

    short8 af[4], bf_[4];
#pragma unroll
    for (int i = 0; i < 4; ++i) {
      af[i]  = *(const short8*)&As[(wm * 64 + i * 16 + fr) * 40 + fq * 8];
      bf_[i] = *(const short8*)&Bs[(wn * 64 + i * 16 + fr) * 40 + fq * 8];
    }
#pragma unroll
    for (int i = 0; i < 4; ++i)
#pragma unroll
      for (int j = 0; j < 4; ++j)
        acc[i][j] = __builtin_amdgcn_mfma_f32_16x16x32_bf16(af[i], bf_[j],
                                                            acc[i][j], 0, 0, 0);
  }

#pragma unroll
  for (int i = 0; i < 4; ++i)
#pragma unroll
    for (int j = 0; j < 4; ++j)
#pragma unroll
      for (int reg = 0; reg < 4; ++reg) {
        int row = m0 + wm * 64 + i * 16 + fq * 4 + reg;
        int col = n0 + wn * 64 + j * 16 + fr;
        C[(size_t)row * N + col] = __float2bfloat16(acc[i][j][reg]);
      }
}

// ------- skinny classifier GEMM: out[n][t][30] = xnc(16384x1024) @ Wct^T -----
// one wave per 16-row m-tile; B = Wct (32x1024 bf16, L1-resident)
__global__ __launch_bounds__(256) void cls_gemm(const __hip_bfloat16* __restrict__ A,
    const __hip_bfloat16* __restrict__ Wct, float* __restrict__ out) {
  const int tid = threadIdx.x;
  const int lane = tid & 63, wave = tid >> 6;
  const int fr = lane & 15, fq = lane >> 4;
  const int m0 = (blockIdx.x * 4 + wave) * 16;
  floatx4 acc[2];
  acc[0] = (floatx4){0.f, 0.f, 0.f, 0.f};
  acc[1] = (floatx4){0.f, 0.f, 0.f, 0.f};
#pragma unroll 4
  for (int k0 = 0; k0 < 1024; k0 += 32) {
    short8 af = *(const short8*)&A[(size_t)(m0 + fr) * 1024 + k0 + fq * 8];
    short8 b0 = *(const short8*)&Wct[(size_t)fr * 1024 + k0 + fq * 8];
    short8 b1 = *(const short8*)&Wct[(size_t)(16 + fr) * 1024 + k0 + fq * 8];
    acc[0] = __builtin_amdgcn_mfma_f32_16x16x32_bf16(af, b0, acc[0], 0, 0, 0);
    acc[1] = __builtin_amdgcn_mfma_f32_16x16x32_bf16(af, b1, acc[1], 0, 0, 0);
  }
#pragma unroll
  for (int j = 0; j < 2; ++j) {
    int col = j * 16 + fr;
    if (col < 30) {
#pragma unroll
      for (int reg = 0; reg < 4; ++reg) {
        int row = m0 + fq * 4 + reg;     // row = t*16 + n
        int t = row >> 4, n = row & 15;
        out[(size_t)n * 30720 + t * 30 + col] = acc[j][reg];
      }
    }
  }
}

// ---------------- SRU bidirectional scan (U bf16, res bf16, out bf16) --------
__global__ __launch_bounds__(64) void sru_scan(const __hip_bfloat16* __restrict__ U,
    const __hip_bfloat16* __restrict__ resx, const float* __restrict__ vc,
    const float* __restrict__ bias, __hip_bfloat16* __restrict__ out, int k) {
  int gid = blockIdx.x * 64 + threadIdx.x;
  int j = gid & 511;
  int n = (gid >> 9) & 15;
  int d = gid >> 13;
  float vf = vc[(d * 2 + 0) * 512 + j];
  float vr = vc[(d * 2 + 1) * 512 + j];
  float bf = bias[(d * 2 + 0) * 512 + j];
  float br = bias[(d * 2 + 1) * 512 + j];
  const bool k4 = (k == 4);
  const size_t tstride = (size_t)k * 16384;
  const __hip_bfloat16* Ub = U + (size_t)(n * 2 + d) * k * 512 + j;
  const __hip_bfloat16* Rb = k4 ? nullptr : (resx + (size_t)n * 1024 + d * 512 + j);
  __hip_bfloat16* ob = out + (size_t)n * 1024 + d * 512 + j;
  const int PF = 8;
  float Aa0[PF], Aa1[PF], Aa2[PF], Arx[PF];
  float Ba0[PF], Ba1[PF], Ba2[PF], Brx[PF];
  float c = 0.f;

#define LOAD_CHUNK(CB, A0, A1, A2, RX)                                    \
  {                                                                       \
    _Pragma("unroll") for (int ss = 0; ss < PF; ++ss) {                   \
      int tt = (CB) * PF + ss;                                            \
      int t = d ? (1023 - tt) : tt;                                       \
      size_t off = (size_t)t * tstride;                                   \
      A0[ss] = __bfloat162float(Ub[off]);                                 \
      A1[ss] = __bfloat162float(Ub[off + 512]);                           \
      A2[ss] = __bfloat162float(Ub[off + 1024]);                          \
      RX[ss] = k4 ? __bfloat162float(Ub[off + 1536])                      \
                  : __bfloat162float(Rb[(size_t)t * 16384]);              \
    }                                                                     \
  }

#define COMP_CHUNK(CB, A0, A1, A2, RX)                                    \
  {                                                                       \
    _Pragma("unroll") for (int ss = 0; ss < PF; ++ss) {                   \
      int tt = (CB) * PF + ss;                                            \
      int t = d ? (1023 - tt) : tt;                                       \
      float f = sigmoidf_(A1[ss] + vf * c + bf);                          \
      float c2 = f * c + (1.f - f) * A0[ss];                              \
      float r = sigmoidf_(A2[ss] + vr * c2 + br);                        \
      ob[(size_t)t * 16384] = __float2bfloat16(r * c2 + (1.f - r) * RX[ss]); \
      c = c2;                                                             \
    }                                                                     \
  }

  LOAD_CHUNK(0, Aa0, Aa1, Aa2, Arx);
  for (int cb = 0; cb < 128; cb += 2) {
    LOAD_CHUNK(cb + 1, Ba0, Ba1, Ba2, Brx);
    COMP_CHUNK(cb, Aa0, Aa1, Aa2, Arx);
    if (cb + 2 < 128) LOAD_CHUNK(cb + 2, Aa0, Aa1, Aa2, Arx);
    COMP_CHUNK(cb + 1, Ba0, Ba1, Ba2, Brx);
  }
#undef LOAD_CHUNK
#undef COMP_CHUNK
}

extern "C" void kernel_launch(void* const* d_in, const int* in_sizes, int n_in,
                              void* d_out, int out_size, void* d_ws, size_t ws_size,
                              hipStream_t stream) {
  const float* x        = (const float*)d_in[0];
  const float* conv0_w  = (const float*)d_in[1];
  const float* conv0_b  = (const float*)d_in[2];
  const float* rconv1_w = (const float*)d_in[3];
  const float* rconv1_b = (const float*)d_in[4];
  const float* rbn1_g   = (const float*)d_in[5];
  const float* rbn1_b   = (const float*)d_in[6];
  const float* rbn1_m   = (const float*)d_in[7];
  const float* rbn1_v   = (const float*)d_in[8];
  const float* rconv2_w = (const float*)d_in[9];
  const float* rconv2_b = (const float*)d_in[10];
  const float* rbn2_g   = (const float*)d_in[11];
  const float* rbn2_b   = (const float*)d_in[12];
  const float* rbn2_m   = (const float*)d_in[13];
  const float* rbn2_v   = (const float*)d_in[14];
  const float* ln0_g    = (const float*)d_in[15];
  const float* ln0_b    = (const float*)d_in[16];
  const float* wproj0   = (const float*)d_in[17];
  const float* w0       = (const float*)d_in[18];
  const float* vc0      = (const float*)d_in[19];
  const float* bias0    = (const float*)d_in[20];
  const float* ln_g     = (const float*)d_in[21];
  const float* ln_b     = (const float*)d_in[22];
  const float* wproj    = (const float*)d_in[23];
  const float* w        = (const float*)d_in[24];
  const float* vc       = (const float*)d_in[25];
  const float* bias     = (const float*)d_in[26];
  const float* cln_g    = (const float*)d_in[27];
  const float* cln_b    = (const float*)d_in[28];
  const float* cls_w    = (const float*)d_in[29];
  float* out = (float*)d_out;

  // Two 128 MiB arenas.
  float* Af = (float*)d_ws;
  float* Bf = Af + 33554432;
  __hip_bfloat16* Ah = (__hip_bfloat16*)Af;
  __hip_bfloat16* Bh = (__hip_bfloat16*)Bf;

  __hip_bfloat16* hA   = Ah;                   // NHWC h (67 MB)
  __hip_bfloat16* hB   = Bh;                   // NHWC temp
  __hip_bfloat16* wt1h = Ah + 62914560;        // 18 KB @ A+120MB
  __hip_bfloat16* wt2h = Ah + 62931952;        // next 18 KB

  conv_stem_nhwc<<<16384, 256, 0, stream>>>(x, conv0_w, conv0_b, hA);
  for (int i = 0; i < 3; ++i) {
    wtap_conv<<<36, 256, 0, stream>>>(rconv1_w + i * 9216, wt1h);
    conv_mfma<0><<<dim3(8, 64, 16), 256, 0, stream>>>(hA, wt1h,
        rconv1_b + i * 32, rbn1_g + i * 32, rbn1_b + i * 32,
        rbn1_m + i * 32, rbn1_v + i * 32, hB);
    wtap_conv<<<36, 256, 0, stream>>>(rconv2_w + i * 9216, wt2h);
    conv_mfma<1><<<dim3(8, 64, 16), 256, 0, stream>>>(hB, wt2h,
        rconv2_b + i * 32, rbn2_g + i * 32, rbn2_b + i * 32,
        rbn2_m + i * 32, rbn2_v + i * 32, hA);
  }

  // ---- SRU layer 0 (k=4, F=2048) ----
  __hip_bfloat16* xn0  = Bh;                   // 64 MB (hB dead)
  __hip_bfloat16* Wp0t = Ah + 52428800;        // 1 MB @ A+100MB
  __hip_bfloat16* tmp0 = Bh + 50331648;        // 8 MB @ B+96MB
  __hip_bfloat16* W0t  = Bh + 57671680;        // 2 MB @ B+110MB
  __hip_bfloat16* U    = Ah;                   // 128 MB
  __hip_bfloat16* s2h  = Bh;                   // 32 MB bf16 (xn0 dead)

  ln_nhwc<<<16384, 256, 0, stream>>>(hA, ln0_g, ln0_b, xn0);
  wt_perm0<<<2048, 256, 0, stream>>>(wproj0, Wp0t);
  gemm_bf16<<<dim3(2, 128), 256, 0, stream>>>(xn0, Wp0t, tmp0, 16384, 256, 2048);
  wt_bf16<<<dim3(128, 8), dim3(32, 8), 0, stream>>>(w0, W0t, 256, 4096);
  gemm_bf16<<<dim3(32, 128), 256, 0, stream>>>(tmp0, W0t, U, 16384, 4096, 256);
  sru_scan<<<256, 64, 0, stream>>>(U, nullptr, vc0, bias0, s2h, 4);

  // ---- SRU layers 1..3 (k=3, F=1024) ----
  __hip_bfloat16* xn3  = Bh + 33554432;        // 32 MB @ B+64MB
  __hip_bfloat16* tmp3 = Bh + 50331648;        // 8 MB @ B+96MB
  __hip_bfloat16* Wt3  = Bh + 54525952;        // 1.5 MB @ B+104MB
  __hip_bfloat16* Wpt3 = Bh + 55574528;        // 0.5 MB @ B+106MB
  for (int i = 0; i < 3; ++i) {
    ln_rows_h<<<16384, 256, 0, stream>>>(s2h, ln_g + i * 1024, ln_b + i * 1024, xn3);
    wt_bf16<<<dim3(8, 32), dim3(32, 8), 0, stream>>>(wproj + i * 262144, Wpt3,
                                                     1024, 256);
    gemm_bf16<<<dim3(2, 128), 256, 0, stream>>>(xn3, Wpt3, tmp3, 16384, 256, 1024);
    wt_bf16<<<dim3(96, 8), dim3(32, 8), 0, stream>>>(w + i * 786432, Wt3, 256, 3072);
    gemm_bf16<<<dim3(24, 128), 256, 0, stream>>>(tmp3, Wt3, U, 16384, 3072, 256);
    sru_scan<<<256, 64, 0, stream>>>(U, xn3, vc + i * 2048, bias + i * 2048, s2h, 3);
  }

  // ---- final LN + classifier (skinny MFMA GEMM) ----
  __hip_bfloat16* xnc = Bh + 16777216;         // 32 MB @ B+32MB
  __hip_bfloat16* Wct = Ah;                    // 64 KB (U dead)
  ln_rows_h<<<16384, 256, 0, stream>>>(s2h, cln_g, cln_b, xnc);
  wct_prep<<<128, 256, 0, stream>>>(cls_w, Wct);
  cls_gemm<<<256, 256, 0, stream>>>(xnc, Wct, out);
}

// Round 7
// 1579.295 us; speedup vs baseline: 11.6206x; 1.0378x over previous
//
#include <hip/hip_runtime.h>
#include <hip/hip_bf16.h>
#include <math.h>

#define DEV __device__ __forceinline__

typedef __attribute__((ext_vector_type(8))) short short8;
typedef __attribute__((ext_vector_type(4))) float floatx4;

DEV float sigmoidf_(float x) { return 1.f / (1.f + __expf(-x)); }
DEV float b2f_lo(unsigned u) { return __uint_as_float(u << 16); }
DEV float b2f_hi(unsigned u) { return __uint_as_float(u & 0xffff0000u); }

union U8 { uint4 u; __hip_bfloat16 h[8]; };

// ------- conv stem: (16,1,128,2048) -> NHWC bf16 h[n][f][t][oc], s2 p1 -------
__global__ __launch_bounds__(256) void conv_stem_nhwc(const float* __restrict__ x,
    const float* __restrict__ w, const float* __restrict__ bias,
    __hip_bfloat16* __restrict__ out) {
  int idx = blockIdx.x * 256 + threadIdx.x;   // (n, f, t, ocq)
  int ocq = idx & 3;
  int t  = (idx >> 2) & 1023;
  int f  = (idx >> 12) & 63;
  int n  = idx >> 18;
  const float* xb = x + (size_t)n * 262144;
  float xv[9];
#pragma unroll
  for (int df = 0; df < 3; ++df) {
    int fi = 2 * f + df - 1;
#pragma unroll
    for (int dc = 0; dc < 3; ++dc) {
      int ti = 2 * t + dc - 1;
      xv[df * 3 + dc] = (fi >= 0 && fi < 128 && ti >= 0 && ti < 2048)
                          ? xb[fi * 2048 + ti] : 0.f;
    }
  }
  U8 o;
#pragma unroll
  for (int oo = 0; oo < 8; ++oo) {
    int oc = ocq * 8 + oo;
    float acc = bias[oc];
#pragma unroll
    for (int q = 0; q < 9; ++q) acc += w[oc * 9 + q] * xv[q];
    o.h[oo] = __float2bfloat16(acc);
  }
  *(uint4*)&out[(((size_t)n * 64 + f) * 1024 + t) * 32 + ocq * 8] = o.u;
}

// ----- weight swizzle: (32oc,32ic,3,3) fp32 -> [tap][oc][ic] bf16 (9216) -----
__global__ __launch_bounds__(256) void wtap_conv(const float* __restrict__ in,
    __hip_bfloat16* __restrict__ out) {
  int i = blockIdx.x * 256 + threadIdx.x;
  if (i < 9216) {
    int tap = i >> 10;
    int oc = (i >> 5) & 31;
    int ic = i & 31;
    out[i] = __float2bfloat16(in[(oc * 32 + ic) * 9 + tap]);
  }
}

// ------ residual conv 3x3 via MFMA implicit GEMM (NHWC bf16) + BN/res/ReLU ---
template <int ADD>
__global__ __launch_bounds__(256) void conv_mfma(const __hip_bfloat16* __restrict__ Hin,
    const __hip_bfloat16* __restrict__ wt,      // [9][32][32] bf16
    const float* __restrict__ cb, const float* __restrict__ bg,
    const float* __restrict__ bb, const float* __restrict__ bm,
    const float* __restrict__ bv, __hip_bfloat16* Hres) {
  __shared__ __hip_bfloat16 sIn[3 * 130 * 40];
  __hip_bfloat16* sOut = sIn;
  const int tid = threadIdx.x;
  const int tb = blockIdx.x, f = blockIdx.y, n = blockIdx.z;
  const int t0 = tb * 128;
  const __hip_bfloat16* Hb = Hin + (size_t)n * 64 * 1024 * 32;

  for (int c = tid; c < 1560; c += 256) {
    int df = c / 520;
    int r = c - df * 520;
    int p = r >> 2, icq = r & 3;
    int fi = f + df - 1;
    int tg = t0 + p - 1;
    uint4 v = {0, 0, 0, 0};
    if (fi >= 0 && fi < 64 && tg >= 0 && tg < 1024)
      v = *(const uint4*)&Hb[((size_t)fi * 1024 + tg) * 32 + icq * 8];
    *(uint4*)&sIn[(df * 130 + p) * 40 + icq * 8] = v;
  }

  const int lane = tid & 63, wave = tid >> 6;
  const int fr = lane & 15, fq = lane >> 4;
  short8 bfrag[9][2];
#pragma unroll
  for (int tap = 0; tap < 9; ++tap)
#pragma unroll
    for (int j = 0; j < 2; ++j)
      bfrag[tap][j] = *(const short8*)&wt[(tap * 32 + j * 16 + fr) * 32 + fq * 8];

  __syncthreads();

  const int t0w = wave * 32;
  floatx4 acc[2][2];
#pragma unroll
  for (int mi = 0; mi < 2; ++mi)
#pragma unroll
    for (int j = 0; j < 2; ++j) acc[mi][j] = (floatx4){0.f, 0.f, 0.f, 0.f};

#pragma unroll
  for (int mi = 0; mi < 2; ++mi) {
    int tbase = t0w + mi * 16;
#pragma unroll
    for (int df = 0; df < 3; ++df)
#pragma unroll
      for (int dc = 0; dc < 3; ++dc) {
        int p = tbase + fr + dc;
        short8 af = *(const short8*)&sIn[(df * 130 + p) * 40 + fq * 8];
        acc[mi][0] = __builtin_amdgcn_mfma_f32_16x16x32_bf16(
            af, bfrag[df * 3 + dc][0], acc[mi][0], 0, 0, 0);
        acc[mi][1] = __builtin_amdgcn_mfma_f32_16x16x32_bf16(
            af, bfrag[df * 3 + dc][1], acc[mi][1], 0, 0, 0);
      }
  }

  float sc0 = bg[fr] * rsqrtf(bv[fr] + 1e-5f);
  float sh0 = (cb[fr] - bm[fr]) * sc0 + bb[fr];
  float sc1 = bg[fr + 16] * rsqrtf(bv[fr + 16] + 1e-5f);
  float sh1 = (cb[fr + 16] - bm[fr + 16]) * sc1 + bb[fr + 16];

  __syncthreads();
#pragma unroll
  for (int mi = 0; mi < 2; ++mi)
#pragma unroll
    for (int j = 0; j < 2; ++j) {
      float sc = j ? sc1 : sc0, sh = j ? sh1 : sh0;
#pragma unroll
      for (int reg = 0; reg < 4; ++reg) {
        int t_l = t0w + mi * 16 + fq * 4 + reg;
        sOut[t_l * 40 + j * 16 + fr] = __float2bfloat16(acc[mi][j][reg] * sc + sh);
      }
    }
  __syncthreads();

  for (int c = tid; c < 512; c += 256) {
    int t_l = c >> 2, icq = c & 3;
    U8 y;
    y.u = *(uint4*)&sOut[t_l * 40 + icq * 8];
    size_t addr = (((size_t)n * 64 + f) * 1024 + t0 + t_l) * 32 + icq * 8;
    U8 o;
    if (ADD) {
      U8 r;
      r.u = *(const uint4*)&Hres[addr];
#pragma unroll
      for (int i = 0; i < 8; ++i)
        o.h[i] = __float2bfloat16(
            fmaxf(__bfloat162float(y.h[i]) + __bfloat162float(r.h[i]), 0.f));
    } else {
#pragma unroll
      for (int i = 0; i < 8; ++i)
        o.h[i] = __float2bfloat16(fmaxf(__bfloat162float(y.h[i]), 0.f));
    }
    *(uint4*)&Hres[addr] = o.u;
  }
}

// ------ LN over NHWC row (t,n): F=2048, k-order k' = f*32+ic, bf16 out -------
__global__ __launch_bounds__(256) void ln_nhwc(const __hip_bfloat16* __restrict__ H,
    const float* __restrict__ g, const float* __restrict__ b,
    __hip_bfloat16* __restrict__ xn) {
  int r = blockIdx.x;          // r = t*16 + n
  int t = r >> 4, n = r & 15;
  int tid = threadIdx.x;
  int f = tid >> 2, icq = tid & 3;
  U8 v;
  v.u = *(const uint4*)&H[(((size_t)n * 64 + f) * 1024 + t) * 32 + icq * 8];
  float xv[8];
  float sum = 0.f, ss = 0.f;
#pragma unroll
  for (int i = 0; i < 8; ++i) {
    xv[i] = __bfloat162float(v.h[i]);
    sum += xv[i];
    ss += xv[i] * xv[i];
  }
#pragma unroll
  for (int off = 32; off > 0; off >>= 1) {
    sum += __shfl_down(sum, off);
    ss  += __shfl_down(ss, off);
  }
  __shared__ float red[8];
  int lane = tid & 63, wave = tid >> 6;
  if (lane == 0) { red[wave] = sum; red[4 + wave] = ss; }
  __syncthreads();
  sum = red[0] + red[1] + red[2] + red[3];
  ss  = red[4] + red[5] + red[6] + red[7];
  float mean = sum * (1.f / 2048.f);
  float var = ss * (1.f / 2048.f) - mean * mean;
  float inv = rsqrtf(var + 1e-5f);
  U8 o;
#pragma unroll
  for (int i = 0; i < 8; ++i) {
    int cf = (icq * 8 + i) * 64 + f;
    o.h[i] = __float2bfloat16((xv[i] - mean) * inv * g[cf] + b[cf]);
  }
  *(uint4*)&xn[(size_t)r * 2048 + tid * 8] = o.u;
}

// -- wproj0 permuted transpose: Wp0t[p][k'=f*32+ic] = wproj0[ic*64+f][p] bf16 --
__global__ __launch_bounds__(256) void wt_perm0(const float* __restrict__ in,
    __hip_bfloat16* __restrict__ out) {
  int i = blockIdx.x * 256 + threadIdx.x;
  int p = i >> 11, kp = i & 2047;
  int ic = kp & 31, f = kp >> 5;
  out[i] = __float2bfloat16(in[(ic * 64 + f) * 256 + p]);
}

// -------- LayerNorm bf16 rows F=1024 -> bf16 out -----------------------------
__global__ __launch_bounds__(256) void ln_rows_h(const __hip_bfloat16* __restrict__ in,
    const float* __restrict__ g, const float* __restrict__ b,
    __hip_bfloat16* __restrict__ out) {
  int r = blockIdx.x;
  int tid = threadIdx.x;
  union { ushort4 u; __hip_bfloat16 h[4]; } iv;
  iv.u = *(const ushort4*)&in[(size_t)r * 1024 + tid * 4];
  float x0 = __bfloat162float(iv.h[0]);
  float x1 = __bfloat162float(iv.h[1]);
  float x2 = __bfloat162float(iv.h[2]);
  float x3 = __bfloat162float(iv.h[3]);
  float sum = x0 + x1 + x2 + x3;
  float ss = x0 * x0 + x1 * x1 + x2 * x2 + x3 * x3;
#pragma unroll
  for (int off = 32; off > 0; off >>= 1) {
    sum += __shfl_down(sum, off);
    ss  += __shfl_down(ss, off);
  }
  __shared__ float red[8];
  int lane = tid & 63, wave = tid >> 6;
  if (lane == 0) { red[wave] = sum; red[4 + wave] = ss; }
  __syncthreads();
  sum = red[0] + red[1] + red[2] + red[3];
  ss  = red[4] + red[5] + red[6] + red[7];
  float mean = sum * (1.f / 1024.f);
  float var = ss * (1.f / 1024.f) - mean * mean;
  float inv = rsqrtf(var + 1e-5f);
  float4 gv = *(const float4*)&g[tid * 4];
  float4 bv = *(const float4*)&b[tid * 4];
  union { ushort4 u; __hip_bfloat16 h[4]; } o;
  o.h[0] = __float2bfloat16((x0 - mean) * inv * gv.x + bv.x);
  o.h[1] = __float2bfloat16((x1 - mean) * inv * gv.y + bv.y);
  o.h[2] = __float2bfloat16((x2 - mean) * inv * gv.z + bv.z);
  o.h[3] = __float2bfloat16((x3 - mean) * inv * gv.w + bv.w);
  *(ushort4*)&out[(size_t)r * 1024 + tid * 4] = o.u;
}

// ------- weight convert+transpose: in (K x N) fp32 -> out (N x K) bf16 -------
__global__ __launch_bounds__(256) void wt_bf16(const float* __restrict__ in,
    __hip_bfloat16* __restrict__ out, int K, int N) {
  __shared__ float tile[32][33];
  int x = threadIdx.x, y0 = threadIdx.y;
  int bn = blockIdx.x * 32;
  int bk = blockIdx.y * 32;
#pragma unroll
  for (int i = 0; i < 4; ++i) {
    int yy = y0 + i * 8;
    tile[yy][x] = in[(size_t)(bk + yy) * N + bn + x];
  }
  __syncthreads();
#pragma unroll
  for (int i = 0; i < 4; ++i) {
    int yy = y0 + i * 8;
    out[(size_t)(bn + yy) * K + bk + x] = __float2bfloat16(tile[x][yy]);
  }
}

// ---- expansion weight prep: w (256 x korig*1024) fp32 ->
// ---- Bt[(d*512+j)*4+k][ck] bf16 (4096 x 256), k>=korig rows zeroed ----------
__global__ void wexp_prep(const float* __restrict__ in,
    __hip_bfloat16* __restrict__ out, int korig) {
  __shared__ float tile[32][33];
  int jt = blockIdx.x;         // 0..15 (j tile)
  int ckt = blockIdx.y;        // 0..7  (ck tile)
  int dk = blockIdx.z;         // 0..7  (d*4+k)
  int d = dk >> 2, k = dk & 3;
  int x = threadIdx.x, y0 = threadIdx.y;
  bool valid = (k < korig);
#pragma unroll
  for (int i = 0; i < 4; ++i) {
    int yy = y0 + i * 8;       // ck'
    tile[yy][x] = valid
        ? in[(size_t)(ckt * 32 + yy) * (korig * 1024) + (d * korig + k) * 512 +
             jt * 32 + x]
        : 0.f;
  }
  __syncthreads();
#pragma unroll
  for (int i = 0; i < 4; ++i) {
    int yy = y0 + i * 8;       // j'
    out[(size_t)((d * 512 + jt * 32 + yy) * 4 + k) * 256 + ckt * 32 + x] =
        __float2bfloat16(tile[x][yy]);
  }
}

// ---- cls_w (1024x30) fp32 -> Wct (32x1024) bf16, rows >=30 zero -------------
__global__ __launch_bounds__(256) void wct_prep(const float* __restrict__ in,
    __hip_bfloat16* __restrict__ out) {
  int i = blockIdx.x * 256 + threadIdx.x;
  int nn = i >> 10, kk = i & 1023;
  out[i] = __float2bfloat16(nn < 30 ? in[kk * 30 + nn] : 0.f);
}

// -------- bf16 MFMA GEMM: C(MxN) = A(MxK) @ Bt(NxK)^T, bf16 out --------------
__global__ __launch_bounds__(256) void gemm_bf16(const __hip_bfloat16* __restrict__ A,
    const __hip_bfloat16* __restrict__ Bt, __hip_bfloat16* __restrict__ C,
    int M, int N, int K) {
  __shared__ __hip_bfloat16 As[128 * 40];
  __shared__ __hip_bfloat16 Bs[128 * 40];
  const int tid = threadIdx.x;
  const int m0 = blockIdx.y * 128, n0 = blockIdx.x * 128;
  const int lane = tid & 63, wave = tid >> 6;
  const int wm = wave & 1, wn = wave >> 1;
  const int fr = lane & 15;
  const int fq = lane >> 4;
  floatx4 acc[4][4];
#pragma unroll
  for (int i = 0; i < 4; ++i)
#pragma unroll
    for (int j = 0; j < 4; ++j)
      acc[i][j] = (floatx4){0.f, 0.f, 0.f, 0.f};

  for (int k0 = 0; k0 < K; k0 += 32) {
    __syncthreads();
#pragma unroll
    for (int p = 0; p < 4; ++p) {
      int i = tid + p * 256;
      int half = i >> 9;
      int j = i & 511;
      int row = j >> 2, ch = j & 3;
      const __hip_bfloat16* src = half
          ? &Bt[(size_t)(n0 + row) * K + k0 + ch * 8]
          : &A[(size_t)(m0 + row) * K + k0 + ch * 8];
      __hip_bfloat16* dst = (half ? Bs : As) + row * 40 + ch * 8;
      *(uint4*)dst = *(const uint4*)src;
    }
    __syncthreads();

    short8 af[4], bf_[4];
#pragma unroll
    for (int i = 0; i < 4; ++i) {
      af[i]  = *(const short8*)&As[(wm * 64 + i * 16 + fr) * 40 + fq * 8];
      bf_[i] = *(const short8*)&Bs[(wn * 64 + i * 16 + fr) * 40 + fq * 8];
    }
#pragma unroll
    for (int i = 0; i < 4; ++i)
#pragma unroll
      for (int j = 0; j < 4; ++j)
        acc[i][j] = __builtin_amdgcn_mfma_f32_16x16x32_bf16(af[i], bf_[j],
                                                            acc[i][j], 0, 0, 0);
  }

#pragma unroll
  for (int i = 0; i < 4; ++i)
#pragma unroll
    for (int j = 0; j < 4; ++j)
#pragma unroll
      for (int reg = 0; reg < 4; ++reg) {
        int row = m0 + wm * 64 + i * 16 + fq * 4 + reg;
        int col = n0 + wn * 64 + j * 16 + fr;
        C[(size_t)row * N + col] = __float2bfloat16(acc[i][j][reg]);
      }
}

// ------- skinny classifier GEMM: out[n][t][30] = xnc(16384x1024) @ Wct^T -----
__global__ __launch_bounds__(256) void cls_gemm(const __hip_bfloat16* __restrict__ A,
    const __hip_bfloat16* __restrict__ Wct, float* __restrict__ out) {
  const int tid = threadIdx.x;
  const int lane = tid & 63, wave = tid >> 6;
  const int fr = lane & 15, fq = lane >> 4;
  const int m0 = (blockIdx.x * 4 + wave) * 16;
  floatx4 acc[2];
  acc[0] = (floatx4){0.f, 0.f, 0.f, 0.f};
  acc[1] = (floatx4){0.f, 0.f, 0.f, 0.f};
#pragma unroll 4
  for (int k0 = 0; k0 < 1024; k0 += 32) {
    short8 af = *(const short8*)&A[(size_t)(m0 + fr) * 1024 + k0 + fq * 8];
    short8 b0 = *(const short8*)&Wct[(size_t)fr * 1024 + k0 + fq * 8];
    short8 b1 = *(const short8*)&Wct[(size_t)(16 + fr) * 1024 + k0 + fq * 8];
    acc[0] = __builtin_amdgcn_mfma_f32_16x16x32_bf16(af, b0, acc[0], 0, 0, 0);
    acc[1] = __builtin_amdgcn_mfma_f32_16x16x32_bf16(af, b1, acc[1], 0, 0, 0);
  }
#pragma unroll
  for (int j = 0; j < 2; ++j) {
    int col = j * 16 + fr;
    if (col < 30) {
#pragma unroll
      for (int reg = 0; reg < 4; ++reg) {
        int row = m0 + fq * 4 + reg;     // row = t*16 + n
        int t = row >> 4, n = row & 15;
        out[(size_t)n * 30720 + t * 30 + col] = acc[j][reg];
      }
    }
  }
}

// ---------------- SRU bidirectional scan -------------------------------------
// U rows 4096 = [d][j][k4]; lane loads one uint2 (u0,u1,u2,res/pad) per t.
// 4-buffer pipeline, prefetch depth 3 (24/48 outstanding loads <= vmcnt 63).
template <int K4>
__global__ __launch_bounds__(64) void sru_scan(const __hip_bfloat16* __restrict__ U,
    const __hip_bfloat16* __restrict__ resx, const float* __restrict__ vc,
    const float* __restrict__ bias, __hip_bfloat16* __restrict__ out) {
  int gid = blockIdx.x * 64 + threadIdx.x;
  int j = gid & 511;
  int n = (gid >> 9) & 15;
  int d = gid >> 13;                         // wave-uniform
  float vf = vc[(d * 2 + 0) * 512 + j];
  float vr = vc[(d * 2 + 1) * 512 + j];
  float bf = bias[(d * 2 + 0) * 512 + j];
  float br = bias[(d * 2 + 1) * 512 + j];
  const uint2* Ub = (const uint2*)(U + (size_t)n * 4096 + d * 2048 + (size_t)j * 4);
  const __hip_bfloat16* Rb = K4 ? nullptr : (resx + (size_t)n * 1024 + d * 512 + j);
  __hip_bfloat16* ob = out + (size_t)n * 1024 + d * 512 + j;

  uint2 B0[8], B1[8], B2[8], B3[8];
  __hip_bfloat16 R0[8], R1[8], R2[8], R3[8];
  float c = 0.f;

#define LOADC(CB, UB, RB)                                                 \
  {                                                                       \
    _Pragma("unroll") for (int ss = 0; ss < 8; ++ss) {                    \
      int tt = (CB) * 8 + ss;                                             \
      int t = d ? (1023 - tt) : tt;                                       \
      UB[ss] = Ub[(size_t)t * 16384];                                     \
      if (!K4) RB[ss] = Rb[(size_t)t * 16384];                            \
    }                                                                     \
  }

#define COMPC(CB, UB, RB)                                                 \
  {                                                                       \
    _Pragma("unroll") for (int ss = 0; ss < 8; ++ss) {                    \
      int tt = (CB) * 8 + ss;                                             \
      int t = d ? (1023 - tt) : tt;                                       \
      uint2 uv = UB[ss];                                                  \
      float a0 = b2f_lo(uv.x), a1 = b2f_hi(uv.x), a2 = b2f_lo(uv.y);      \
      float rx = K4 ? b2f_hi(uv.y) : __bfloat162float(RB[ss]);            \
      float f = sigmoidf_(a1 + vf * c + bf);                              \
      float c2 = f * c + (1.f - f) * a0;                                  \
      float r = sigmoidf_(a2 + vr * c2 + br);                             \
      ob[(size_t)t * 16384] = __float2bfloat16(r * c2 + (1.f - r) * rx);  \
      c = c2;                                                             \
    }                                                                     \
  }

  LOADC(0, B0, R0);
  LOADC(1, B1, R1);
  LOADC(2, B2, R2);
  for (int cb = 0; cb < 128; cb += 4) {
    LOADC(cb + 3, B3, R3);
    COMPC(cb, B0, R0);
    if (cb + 4 < 128) LOADC(cb + 4, B0, R0);
    COMPC(cb + 1, B1, R1);
    if (cb + 5 < 128) LOADC(cb + 5, B1, R1);
    COMPC(cb + 2, B2, R2);
    if (cb + 6 < 128) LOADC(cb + 6, B2, R2);
    COMPC(cb + 3, B3, R3);
  }
#undef LOADC
#undef COMPC
}

extern "C" void kernel_launch(void* const* d_in, const int* in_sizes, int n_in,
                              void* d_out, int out_size, void* d_ws, size_t ws_size,
                              hipStream_t stream) {
  const float* x        = (const float*)d_in[0];
  const float* conv0_w  = (const float*)d_in[1];
  const float* conv0_b  = (const float*)d_in[2];
  const float* rconv1_w = (const float*)d_in[3];
  const float* rconv1_b = (const float*)d_in[4];
  const float* rbn1_g   = (const float*)d_in[5];
  const float* rbn1_b   = (const float*)d_in[6];
  const float* rbn1_m   = (const float*)d_in[7];
  const float* rbn1_v   = (const float*)d_in[8];
  const float* rconv2_w = (const float*)d_in[9];
  const float* rconv2_b = (const float*)d_in[10];
  const float* rbn2_g   = (const float*)d_in[11];
  const float* rbn2_b   = (const float*)d_in[12];
  const float* rbn2_m   = (const float*)d_in[13];
  const float* rbn2_v   = (const float*)d_in[14];
  const float* ln0_g    = (const float*)d_in[15];
  const float* ln0_b    = (const float*)d_in[16];
  const float* wproj0   = (const float*)d_in[17];
  const float* w0       = (const float*)d_in[18];
  const float* vc0      = (const float*)d_in[19];
  const float* bias0    = (const float*)d_in[20];
  const float* ln_g     = (const float*)d_in[21];
  const float* ln_b     = (const float*)d_in[22];
  const float* wproj    = (const float*)d_in[23];
  const float* w        = (const float*)d_in[24];
  const float* vc       = (const float*)d_in[25];
  const float* bias     = (const float*)d_in[26];
  const float* cln_g    = (const float*)d_in[27];
  const float* cln_b    = (const float*)d_in[28];
  const float* cls_w    = (const float*)d_in[29];
  float* out = (float*)d_out;

  // Two 128 MiB arenas.
  float* Af = (float*)d_ws;
  float* Bf = Af + 33554432;
  __hip_bfloat16* Ah = (__hip_bfloat16*)Af;
  __hip_bfloat16* Bh = (__hip_bfloat16*)Bf;

  __hip_bfloat16* hA   = Ah;                   // NHWC h (67 MB)
  __hip_bfloat16* hB   = Bh;                   // NHWC temp
  __hip_bfloat16* wt1h = Ah + 62914560;        // 18 KB @ A+120MB
  __hip_bfloat16* wt2h = Ah + 62931952;        // next 18 KB

  conv_stem_nhwc<<<16384, 256, 0, stream>>>(x, conv0_w, conv0_b, hA);
  for (int i = 0; i < 3; ++i) {
    wtap_conv<<<36, 256, 0, stream>>>(rconv1_w + i * 9216, wt1h);
    conv_mfma<0><<<dim3(8, 64, 16), 256, 0, stream>>>(hA, wt1h,
        rconv1_b + i * 32, rbn1_g + i * 32, rbn1_b + i * 32,
        rbn1_m + i * 32, rbn1_v + i * 32, hB);
    wtap_conv<<<36, 256, 0, stream>>>(rconv2_w + i * 9216, wt2h);
    conv_mfma<1><<<dim3(8, 64, 16), 256, 0, stream>>>(hB, wt2h,
        rconv2_b + i * 32, rbn2_g + i * 32, rbn2_b + i * 32,
        rbn2_m + i * 32, rbn2_v + i * 32, hA);
  }

  // ---- SRU layer 0 (k=4, F=2048) ----
  __hip_bfloat16* xn0  = Bh;                   // 64 MB (hB dead)
  __hip_bfloat16* Wp0t = Ah + 52428800;        // 1 MB @ A+100MB
  __hip_bfloat16* tmp0 = Bh + 50331648;        // 8 MB @ B+96MB
  __hip_bfloat16* W0p  = Bh + 57671680;        // 2 MB @ B+110MB
  __hip_bfloat16* U    = Ah;                   // 128 MB (rows = 4096)
  __hip_bfloat16* s2h  = Bh;                   // 32 MB bf16 (xn0 dead)

  ln_nhwc<<<16384, 256, 0, stream>>>(hA, ln0_g, ln0_b, xn0);
  wt_perm0<<<2048, 256, 0, stream>>>(wproj0, Wp0t);
  gemm_bf16<<<dim3(2, 128), 256, 0, stream>>>(xn0, Wp0t, tmp0, 16384, 256, 2048);
  wexp_prep<<<dim3(16, 8, 8), dim3(32, 8), 0, stream>>>(w0, W0p, 4);
  gemm_bf16<<<dim3(32, 128), 256, 0, stream>>>(tmp0, W0p, U, 16384, 4096, 256);
  sru_scan<1><<<256, 64, 0, stream>>>(U, nullptr, vc0, bias0, s2h);

  // ---- SRU layers 1..3 (k=3 padded to 4, F=1024) ----
  __hip_bfloat16* xn3  = Bh + 33554432;        // 32 MB @ B+64MB
  __hip_bfloat16* tmp3 = Bh + 50331648;        // 8 MB @ B+96MB
  __hip_bfloat16* W3p  = Bh + 54525952;        // 2 MB @ B+104MB
  __hip_bfloat16* Wpt3 = Bh + 55574528;        // 0.5 MB @ B+106MB
  for (int i = 0; i < 3; ++i) {
    ln_rows_h<<<16384, 256, 0, stream>>>(s2h, ln_g + i * 1024, ln_b + i * 1024, xn3);
    wt_bf16<<<dim3(8, 32), dim3(32, 8), 0, stream>>>(wproj + i * 262144, Wpt3,
                                                     1024, 256);
    gemm_bf16<<<dim3(2, 128), 256, 0, stream>>>(xn3, Wpt3, tmp3, 16384, 256, 1024);
    wexp_prep<<<dim3(16, 8, 8), dim3(32, 8), 0, stream>>>(w + i * 786432, W3p, 3);
    gemm_bf16<<<dim3(32, 128), 256, 0, stream>>>(tmp3, W3p, U, 16384, 4096, 256);
    sru_scan<0><<<256, 64, 0, stream>>>(U, xn3, vc + i * 2048, bias + i * 2048, s2h);
  }

  // ---- final LN + classifier (skinny MFMA GEMM) ----
  __hip_bfloat16* xnc = Bh + 16777216;         // 32 MB @ B+32MB
  __hip_bfloat16* Wct = Ah;                    // 64 KB (U dead)
  ln_rows_h<<<16384, 256, 0, stream>>>(s2h, cln_g, cln_b, xnc);
  wct_prep<<<128, 256, 0, stream>>>(cls_w, Wct);
  cls_gemm<<<256, 256, 0, stream>>>(xnc, Wct, out);
}

// Round 8
// 1398.222 us; speedup vs baseline: 13.1255x; 1.1295x over previous
//
#include <hip/hip_runtime.h>
#include <hip/hip_bf16.h>
#include <math.h>

#define DEV __device__ __forceinline__

typedef __attribute__((ext_vector_type(8))) short short8;
typedef __attribute__((ext_vector_type(4))) float floatx4;

DEV float sigmoidf_(float x) { return 1.f / (1.f + __expf(-x)); }
DEV float b2f_lo(unsigned u) { return __uint_as_float(u << 16); }
DEV float b2f_hi(unsigned u) { return __uint_as_float(u & 0xffff0000u); }

#if __has_builtin(__builtin_amdgcn_exp2f)
DEV float fexp2_(float x) { return __builtin_amdgcn_exp2f(x); }
#else
DEV float fexp2_(float x) { return exp2f(x); }
#endif
#if __has_builtin(__builtin_amdgcn_rcpf)
DEV float frcp_(float x) { return __builtin_amdgcn_rcpf(x); }
#else
DEV float frcp_(float x) { return 1.f / x; }
#endif

union U8 { uint4 u; __hip_bfloat16 h[8]; };

// ------- conv stem: (16,1,128,2048) -> NHWC bf16 h[n][f][t][oc], s2 p1 -------
__global__ __launch_bounds__(256) void conv_stem_nhwc(const float* __restrict__ x,
    const float* __restrict__ w, const float* __restrict__ bias,
    __hip_bfloat16* __restrict__ out) {
  int idx = blockIdx.x * 256 + threadIdx.x;   // (n, f, t, ocq)
  int ocq = idx & 3;
  int t  = (idx >> 2) & 1023;
  int f  = (idx >> 12) & 63;
  int n  = idx >> 18;
  const float* xb = x + (size_t)n * 262144;
  float xv[9];
#pragma unroll
  for (int df = 0; df < 3; ++df) {
    int fi = 2 * f + df - 1;
#pragma unroll
    for (int dc = 0; dc < 3; ++dc) {
      int ti = 2 * t + dc - 1;
      xv[df * 3 + dc] = (fi >= 0 && fi < 128 && ti >= 0 && ti < 2048)
                          ? xb[fi * 2048 + ti] : 0.f;
    }
  }
  U8 o;
#pragma unroll
  for (int oo = 0; oo < 8; ++oo) {
    int oc = ocq * 8 + oo;
    float acc = bias[oc];
#pragma unroll
    for (int q = 0; q < 9; ++q) acc += w[oc * 9 + q] * xv[q];
    o.h[oo] = __float2bfloat16(acc);
  }
  *(uint4*)&out[(((size_t)n * 64 + f) * 1024 + t) * 32 + ocq * 8] = o.u;
}

// ----- weight swizzle: (32oc,32ic,3,3) fp32 -> [tap][oc][ic] bf16 (9216) -----
__global__ __launch_bounds__(256) void wtap_conv(const float* __restrict__ in,
    __hip_bfloat16* __restrict__ out) {
  int i = blockIdx.x * 256 + threadIdx.x;
  if (i < 9216) {
    int tap = i >> 10;
    int oc = (i >> 5) & 31;
    int ic = i & 31;
    out[i] = __float2bfloat16(in[(oc * 32 + ic) * 9 + tap]);
  }
}

// ------ residual conv 3x3 via MFMA implicit GEMM (NHWC bf16) + BN/res/ReLU ---
template <int ADD>
__global__ __launch_bounds__(256) void conv_mfma(const __hip_bfloat16* __restrict__ Hin,
    const __hip_bfloat16* __restrict__ wt,      // [9][32][32] bf16
    const float* __restrict__ cb, const float* __restrict__ bg,
    const float* __restrict__ bb, const float* __restrict__ bm,
    const float* __restrict__ bv, __hip_bfloat16* Hres) {
  __shared__ __hip_bfloat16 sIn[3 * 130 * 40];
  __hip_bfloat16* sOut = sIn;
  const int tid = threadIdx.x;
  const int tb = blockIdx.x, f = blockIdx.y, n = blockIdx.z;
  const int t0 = tb * 128;
  const __hip_bfloat16* Hb = Hin + (size_t)n * 64 * 1024 * 32;

  for (int c = tid; c < 1560; c += 256) {
    int df = c / 520;
    int r = c - df * 520;
    int p = r >> 2, icq = r & 3;
    int fi = f + df - 1;
    int tg = t0 + p - 1;
    uint4 v = {0, 0, 0, 0};
    if (fi >= 0 && fi < 64 && tg >= 0 && tg < 1024)
      v = *(const uint4*)&Hb[((size_t)fi * 1024 + tg) * 32 + icq * 8];
    *(uint4*)&sIn[(df * 130 + p) * 40 + icq * 8] = v;
  }

  const int lane = tid & 63, wave = tid >> 6;
  const int fr = lane & 15, fq = lane >> 4;
  short8 bfrag[9][2];
#pragma unroll
  for (int tap = 0; tap < 9; ++tap)
#pragma unroll
    for (int j = 0; j < 2; ++j)
      bfrag[tap][j] = *(const short8*)&wt[(tap * 32 + j * 16 + fr) * 32 + fq * 8];

  __syncthreads();

  const int t0w = wave * 32;
  floatx4 acc[2][2];
#pragma unroll
  for (int mi = 0; mi < 2; ++mi)
#pragma unroll
    for (int j = 0; j < 2; ++j) acc[mi][j] = (floatx4){0.f, 0.f, 0.f, 0.f};

#pragma unroll
  for (int mi = 0; mi < 2; ++mi) {
    int tbase = t0w + mi * 16;
#pragma unroll
    for (int df = 0; df < 3; ++df)
#pragma unroll
      for (int dc = 0; dc < 3; ++dc) {
        int p = tbase + fr + dc;
        short8 af = *(const short8*)&sIn[(df * 130 + p) * 40 + fq * 8];
        acc[mi][0] = __builtin_amdgcn_mfma_f32_16x16x32_bf16(
            af, bfrag[df * 3 + dc][0], acc[mi][0], 0, 0, 0);
        acc[mi][1] = __builtin_amdgcn_mfma_f32_16x16x32_bf16(
            af, bfrag[df * 3 + dc][1], acc[mi][1], 0, 0, 0);
      }
  }

  float sc0 = bg[fr] * rsqrtf(bv[fr] + 1e-5f);
  float sh0 = (cb[fr] - bm[fr]) * sc0 + bb[fr];
  float sc1 = bg[fr + 16] * rsqrtf(bv[fr + 16] + 1e-5f);
  float sh1 = (cb[fr + 16] - bm[fr + 16]) * sc1 + bb[fr + 16];

  __syncthreads();
#pragma unroll
  for (int mi = 0; mi < 2; ++mi)
#pragma unroll
    for (int j = 0; j < 2; ++j) {
      float sc = j ? sc1 : sc0, sh = j ? sh1 : sh0;
#pragma unroll
      for (int reg = 0; reg < 4; ++reg) {
        int t_l = t0w + mi * 16 + fq * 4 + reg;
        sOut[t_l * 40 + j * 16 + fr] = __float2bfloat16(acc[mi][j][reg] * sc + sh);
      }
    }
  __syncthreads();

  for (int c = tid; c < 512; c += 256) {
    int t_l = c >> 2, icq = c & 3;
    U8 y;
    y.u = *(uint4*)&sOut[t_l * 40 + icq * 8];
    size_t addr = (((size_t)n * 64 + f) * 1024 + t0 + t_l) * 32 + icq * 8;
    U8 o;
    if (ADD) {
      U8 r;
      r.u = *(const uint4*)&Hres[addr];
#pragma unroll
      for (int i = 0; i < 8; ++i)
        o.h[i] = __float2bfloat16(
            fmaxf(__bfloat162float(y.h[i]) + __bfloat162float(r.h[i]), 0.f));
    } else {
#pragma unroll
      for (int i = 0; i < 8; ++i)
        o.h[i] = __float2bfloat16(fmaxf(__bfloat162float(y.h[i]), 0.f));
    }
    *(uint4*)&Hres[addr] = o.u;
  }
}

// ------ LN over NHWC row (t,n): F=2048, k-order k' = f*32+ic, bf16 out -------
__global__ __launch_bounds__(256) void ln_nhwc(const __hip_bfloat16* __restrict__ H,
    const float* __restrict__ g, const float* __restrict__ b,
    __hip_bfloat16* __restrict__ xn) {
  int r = blockIdx.x;          // r = t*16 + n
  int t = r >> 4, n = r & 15;
  int tid = threadIdx.x;
  int f = tid >> 2, icq = tid & 3;
  U8 v;
  v.u = *(const uint4*)&H[(((size_t)n * 64 + f) * 1024 + t) * 32 + icq * 8];
  float xv[8];
  float sum = 0.f, ss = 0.f;
#pragma unroll
  for (int i = 0; i < 8; ++i) {
    xv[i] = __bfloat162float(v.h[i]);
    sum += xv[i];
    ss += xv[i] * xv[i];
  }
#pragma unroll
  for (int off = 32; off > 0; off >>= 1) {
    sum += __shfl_down(sum, off);
    ss  += __shfl_down(ss, off);
  }
  __shared__ float red[8];
  int lane = tid & 63, wave = tid >> 6;
  if (lane == 0) { red[wave] = sum; red[4 + wave] = ss; }
  __syncthreads();
  sum = red[0] + red[1] + red[2] + red[3];
  ss  = red[4] + red[5] + red[6] + red[7];
  float mean = sum * (1.f / 2048.f);
  float var = ss * (1.f / 2048.f) - mean * mean;
  float inv = rsqrtf(var + 1e-5f);
  U8 o;
#pragma unroll
  for (int i = 0; i < 8; ++i) {
    int cf = (icq * 8 + i) * 64 + f;
    o.h[i] = __float2bfloat16((xv[i] - mean) * inv * g[cf] + b[cf]);
  }
  *(uint4*)&xn[(size_t)r * 2048 + tid * 8] = o.u;
}

// -- wproj0 permuted transpose: Wp0t[p][k'=f*32+ic] = wproj0[ic*64+f][p] bf16 --
__global__ __launch_bounds__(256) void wt_perm0(const float* __restrict__ in,
    __hip_bfloat16* __restrict__ out) {
  int i = blockIdx.x * 256 + threadIdx.x;
  int p = i >> 11, kp = i & 2047;
  int ic = kp & 31, f = kp >> 5;
  out[i] = __float2bfloat16(in[(ic * 64 + f) * 256 + p]);
}

// -------- LayerNorm bf16 rows F=1024 -> bf16 out -----------------------------
__global__ __launch_bounds__(256) void ln_rows_h(const __hip_bfloat16* __restrict__ in,
    const float* __restrict__ g, const float* __restrict__ b,
    __hip_bfloat16* __restrict__ out) {
  int r = blockIdx.x;
  int tid = threadIdx.x;
  union { ushort4 u; __hip_bfloat16 h[4]; } iv;
  iv.u = *(const ushort4*)&in[(size_t)r * 1024 + tid * 4];
  float x0 = __bfloat162float(iv.h[0]);
  float x1 = __bfloat162float(iv.h[1]);
  float x2 = __bfloat162float(iv.h[2]);
  float x3 = __bfloat162float(iv.h[3]);
  float sum = x0 + x1 + x2 + x3;
  float ss = x0 * x0 + x1 * x1 + x2 * x2 + x3 * x3;
#pragma unroll
  for (int off = 32; off > 0; off >>= 1) {
    sum += __shfl_down(sum, off);
    ss  += __shfl_down(ss, off);
  }
  __shared__ float red[8];
  int lane = tid & 63, wave = tid >> 6;
  if (lane == 0) { red[wave] = sum; red[4 + wave] = ss; }
  __syncthreads();
  sum = red[0] + red[1] + red[2] + red[3];
  ss  = red[4] + red[5] + red[6] + red[7];
  float mean = sum * (1.f / 1024.f);
  float var = ss * (1.f / 1024.f) - mean * mean;
  float inv = rsqrtf(var + 1e-5f);
  float4 gv = *(const float4*)&g[tid * 4];
  float4 bv = *(const float4*)&b[tid * 4];
  union { ushort4 u; __hip_bfloat16 h[4]; } o;
  o.h[0] = __float2bfloat16((x0 - mean) * inv * gv.x + bv.x);
  o.h[1] = __float2bfloat16((x1 - mean) * inv * gv.y + bv.y);
  o.h[2] = __float2bfloat16((x2 - mean) * inv * gv.z + bv.z);
  o.h[3] = __float2bfloat16((x3 - mean) * inv * gv.w + bv.w);
  *(ushort4*)&out[(size_t)r * 1024 + tid * 4] = o.u;
}

// ------- weight convert+transpose: in (K x N) fp32 -> out (N x K) bf16 -------
__global__ __launch_bounds__(256) void wt_bf16(const float* __restrict__ in,
    __hip_bfloat16* __restrict__ out, int K, int N) {
  __shared__ float tile[32][33];
  int x = threadIdx.x, y0 = threadIdx.y;
  int bn = blockIdx.x * 32;
  int bk = blockIdx.y * 32;
#pragma unroll
  for (int i = 0; i < 4; ++i) {
    int yy = y0 + i * 8;
    tile[yy][x] = in[(size_t)(bk + yy) * N + bn + x];
  }
  __syncthreads();
#pragma unroll
  for (int i = 0; i < 4; ++i) {
    int yy = y0 + i * 8;
    out[(size_t)(bn + yy) * K + bk + x] = __float2bfloat16(tile[x][yy]);
  }
}

// ---- expansion weight prep: w (256 x korig*1024) fp32 ->
// ---- Bt[(d*512+j)*4+k][ck] bf16 (4096 x 256), k>=korig rows zeroed ----------
__global__ void wexp_prep(const float* __restrict__ in,
    __hip_bfloat16* __restrict__ out, int korig) {
  __shared__ float tile[32][33];
  int jt = blockIdx.x;
  int ckt = blockIdx.y;
  int dk = blockIdx.z;
  int d = dk >> 2, k = dk & 3;
  int x = threadIdx.x, y0 = threadIdx.y;
  bool valid = (k < korig);
#pragma unroll
  for (int i = 0; i < 4; ++i) {
    int yy = y0 + i * 8;
    tile[yy][x] = valid
        ? in[(size_t)(ckt * 32 + yy) * (korig * 1024) + (d * korig + k) * 512 +
             jt * 32 + x]
        : 0.f;
  }
  __syncthreads();
#pragma unroll
  for (int i = 0; i < 4; ++i) {
    int yy = y0 + i * 8;
    out[(size_t)((d * 512 + jt * 32 + yy) * 4 + k) * 256 + ckt * 32 + x] =
        __float2bfloat16(tile[x][yy]);
  }
}

// ---- cls_w (1024x30) fp32 -> Wct (32x1024) bf16, rows >=30 zero -------------
__global__ __launch_bounds__(256) void wct_prep(const float* __restrict__ in,
    __hip_bfloat16* __restrict__ out) {
  int i = blockIdx.x * 256 + threadIdx.x;
  int nn = i >> 10, kk = i & 1023;
  out[i] = __float2bfloat16(nn < 30 ? in[kk * 30 + nn] : 0.f);
}

// -------- bf16 MFMA GEMM: C(MxN) = A(MxK) @ Bt(NxK)^T, bf16 out --------------
__global__ __launch_bounds__(256) void gemm_bf16(const __hip_bfloat16* __restrict__ A,
    const __hip_bfloat16* __restrict__ Bt, __hip_bfloat16* __restrict__ C,
    int M, int N, int K) {
  __shared__ __hip_bfloat16 As[128 * 40];
  __shared__ __hip_bfloat16 Bs[128 * 40];
  const int tid = threadIdx.x;
  const int m0 = blockIdx.y * 128, n0 = blockIdx.x * 128;
  const int lane = tid & 63, wave = tid >> 6;
  const int wm = wave & 1, wn = wave >> 1;
  const int fr = lane & 15;
  const int fq = lane >> 4;
  floatx4 acc[4][4];
#pragma unroll
  for (int i = 0; i < 4; ++i)
#pragma unroll
    for (int j = 0; j < 4; ++j)
      acc[i][j] = (floatx4){0.f, 0.f, 0.f, 0.f};

  for (int k0 = 0; k0 < K; k0 += 32) {
    __syncthreads();
#pragma unroll
    for (int p = 0; p < 4; ++p) {
      int i = tid + p * 256;
      int half = i >> 9;
      int j = i & 511;
      int row = j >> 2, ch = j & 3;
      const __hip_bfloat16* src = half
          ? &Bt[(size_t)(n0 + row) * K + k0 + ch * 8]
          : &A[(size_t)(m0 + row) * K + k0 + ch * 8];
      __hip_bfloat16* dst = (half ? Bs : As) + row * 40 + ch * 8;
      *(uint4*)dst = *(const uint4*)src;
    }
    __syncthreads();

    short8 af[4], bf_[4];
#pragma unroll
    for (int i = 0; i < 4; ++i) {
      af[i]  = *(const short8*)&As[(wm * 64 + i * 16 + fr) * 40 + fq * 8];
      bf_[i] = *(const short8*)&Bs[(wn * 64 + i * 16 + fr) * 40 + fq * 8];
    }
#pragma unroll
    for (int i = 0; i < 4; ++i)
#pragma unroll
      for (int j = 0; j < 4; ++j)
        acc[i][j] = __builtin_amdgcn_mfma_f32_16x16x32_bf16(af[i], bf_[j],
                                                            acc[i][j], 0, 0, 0);
  }

#pragma unroll
  for (int i = 0; i < 4; ++i)
#pragma unroll
    for (int j = 0; j < 4; ++j)
#pragma unroll
      for (int reg = 0; reg < 4; ++reg) {
        int row = m0 + wm * 64 + i * 16 + fq * 4 + reg;
        int col = n0 + wn * 64 + j * 16 + fr;
        C[(size_t)row * N + col] = __float2bfloat16(acc[i][j][reg]);
      }
}

// ------- skinny classifier GEMM: out[n][t][30] = xnc(16384x1024) @ Wct^T -----
__global__ __launch_bounds__(256) void cls_gemm(const __hip_bfloat16* __restrict__ A,
    const __hip_bfloat16* __restrict__ Wct, float* __restrict__ out) {
  const int tid = threadIdx.x;
  const int lane = tid & 63, wave = tid >> 6;
  const int fr = lane & 15, fq = lane >> 4;
  const int m0 = (blockIdx.x * 4 + wave) * 16;
  floatx4 acc[2];
  acc[0] = (floatx4){0.f, 0.f, 0.f, 0.f};
  acc[1] = (floatx4){0.f, 0.f, 0.f, 0.f};
#pragma unroll 4
  for (int k0 = 0; k0 < 1024; k0 += 32) {
    short8 af = *(const short8*)&A[(size_t)(m0 + fr) * 1024 + k0 + fq * 8];
    short8 b0 = *(const short8*)&Wct[(size_t)fr * 1024 + k0 + fq * 8];
    short8 b1 = *(const short8*)&Wct[(size_t)(16 + fr) * 1024 + k0 + fq * 8];
    acc[0] = __builtin_amdgcn_mfma_f32_16x16x32_bf16(af, b0, acc[0], 0, 0, 0);
    acc[1] = __builtin_amdgcn_mfma_f32_16x16x32_bf16(af, b1, acc[1], 0, 0, 0);
  }
#pragma unroll
  for (int j = 0; j < 2; ++j) {
    int col = j * 16 + fr;
    if (col < 30) {
#pragma unroll
      for (int reg = 0; reg < 4; ++reg) {
        int row = m0 + fq * 4 + reg;     // row = t*16 + n
        int t = row >> 4, n = row & 15;
        out[(size_t)n * 30720 + t * 30 + col] = acc[j][reg];
      }
    }
  }
}

// ---------------- SRU bidirectional scan -------------------------------------
// U rows 4096 = [d][j][k4]; lane loads one uint2 per t. Pointer-walk addressing
// (wave-uniform direction), exp2/rcp sigmoid, 4-buffer depth-3 prefetch.
template <int K4>
__global__ __launch_bounds__(64) void sru_scan(const __hip_bfloat16* __restrict__ U,
    const __hip_bfloat16* __restrict__ resx, const float* __restrict__ vc,
    const float* __restrict__ bias, __hip_bfloat16* __restrict__ out) {
  int gid = blockIdx.x * 64 + threadIdx.x;
  int j = gid & 511;
  int n = (gid >> 9) & 15;
  int d = gid >> 13;                         // wave-uniform
  const float NL2E = -1.44269504f;
  float vf2 = NL2E * vc[(d * 2 + 0) * 512 + j];
  float vr2 = NL2E * vc[(d * 2 + 1) * 512 + j];
  float bf2 = NL2E * bias[(d * 2 + 0) * 512 + j];
  float br2 = NL2E * bias[(d * 2 + 1) * 512 + j];

  const char* Ub = (const char*)(U + (size_t)n * 4096 + d * 2048) + (size_t)j * 8;
  const char* Rb = K4 ? nullptr
      : (const char*)(resx + (size_t)n * 1024 + d * 512) + (size_t)j * 2;
  char* Ob = (char*)(out + (size_t)n * 1024 + d * 512) + (size_t)j * 2;
  const int US = d ? -131072 : 131072;       // uint2 row stride (16384*8 B)
  const int RS = d ? -32768 : 32768;         // bf16 row stride (16384*2 B)
  int uoff = d ? 1023 * 131072 : 0;
  int roff = d ? 1023 * 32768 : 0;
  int ooff = roff;

  uint2 B0[8], B1[8], B2[8], B3[8];
  unsigned short R0[8], R1[8], R2[8], R3[8];
  float c = 0.f;

#define LOADC(UB, RB)                                                     \
  {                                                                       \
    _Pragma("unroll") for (int ss = 0; ss < 8; ++ss) {                    \
      UB[ss] = *(const uint2*)(Ub + uoff);                                \
      if (!K4) RB[ss] = *(const unsigned short*)(Rb + roff);              \
      uoff += US;                                                         \
      if (!K4) roff += RS;                                                \
    }                                                                     \
  }

#define COMPC(UB, RB)                                                     \
  {                                                                       \
    _Pragma("unroll") for (int ss = 0; ss < 8; ++ss) {                    \
      uint2 uv = UB[ss];                                                  \
      float a0 = b2f_lo(uv.x), a1 = b2f_hi(uv.x), a2 = b2f_lo(uv.y);      \
      float rx = K4 ? b2f_hi(uv.y)                                        \
                    : __uint_as_float((unsigned)RB[ss] << 16);            \
      float A1 = fmaf(a1, NL2E, bf2);                                     \
      float f = frcp_(1.f + fexp2_(fmaf(vf2, c, A1)));                    \
      float c2 = fmaf(f, c - a0, a0);                                     \
      float A2 = fmaf(a2, NL2E, br2);                                     \
      float r = frcp_(1.f + fexp2_(fmaf(vr2, c2, A2)));                   \
      float y = fmaf(r, c2 - rx, rx);                                     \
      *(__hip_bfloat16*)(Ob + ooff) = __float2bfloat16(y);                \
      ooff += RS;                                                         \
      c = c2;                                                             \
    }                                                                     \
  }

  LOADC(B0, R0);
  LOADC(B1, R1);
  LOADC(B2, R2);
  for (int cb = 0; cb < 128; cb += 4) {
    LOADC(B3, R3);
    COMPC(B0, R0);
    if (cb + 4 < 128) LOADC(B0, R0);
    COMPC(B1, R1);
    if (cb + 5 < 128) LOADC(B1, R1);
    COMPC(B2, R2);
    if (cb + 6 < 128) LOADC(B2, R2);
    COMPC(B3, R3);
  }
#undef LOADC
#undef COMPC
}

extern "C" void kernel_launch(void* const* d_in, const int* in_sizes, int n_in,
                              void* d_out, int out_size, void* d_ws, size_t ws_size,
                              hipStream_t stream) {
  const float* x        = (const float*)d_in[0];
  const float* conv0_w  = (const float*)d_in[1];
  const float* conv0_b  = (const float*)d_in[2];
  const float* rconv1_w = (const float*)d_in[3];
  const float* rconv1_b = (const float*)d_in[4];
  const float* rbn1_g   = (const float*)d_in[5];
  const float* rbn1_b   = (const float*)d_in[6];
  const float* rbn1_m   = (const float*)d_in[7];
  const float* rbn1_v   = (const float*)d_in[8];
  const float* rconv2_w = (const float*)d_in[9];
  const float* rconv2_b = (const float*)d_in[10];
  const float* rbn2_g   = (const float*)d_in[11];
  const float* rbn2_b   = (const float*)d_in[12];
  const float* rbn2_m   = (const float*)d_in[13];
  const float* rbn2_v   = (const float*)d_in[14];
  const float* ln0_g    = (const float*)d_in[15];
  const float* ln0_b    = (const float*)d_in[16];
  const float* wproj0   = (const float*)d_in[17];
  const float* w0       = (const float*)d_in[18];
  const float* vc0      = (const float*)d_in[19];
  const float* bias0    = (const float*)d_in[20];
  const float* ln_g     = (const float*)d_in[21];
  const float* ln_b     = (const float*)d_in[22];
  const float* wproj    = (const float*)d_in[23];
  const float* w        = (const float*)d_in[24];
  const float* vc       = (const float*)d_in[25];
  const float* bias     = (const float*)d_in[26];
  const float* cln_g    = (const float*)d_in[27];
  const float* cln_b    = (const float*)d_in[28];
  const float* cls_w    = (const float*)d_in[29];
  float* out = (float*)d_out;

  // Two 128 MiB arenas.
  float* Af = (float*)d_ws;
  float* Bf = Af + 33554432;
  __hip_bfloat16* Ah = (__hip_bfloat16*)Af;
  __hip_bfloat16* Bh = (__hip_bfloat16*)Bf;

  __hip_bfloat16* hA   = Ah;                   // NHWC h (67 MB)
  __hip_bfloat16* hB   = Bh;                   // NHWC temp
  __hip_bfloat16* wt1h = Ah + 62914560;        // 18 KB @ A+120MB
  __hip_bfloat16* wt2h = Ah + 62931952;        // next 18 KB

  conv_stem_nhwc<<<16384, 256, 0, stream>>>(x, conv0_w, conv0_b, hA);
  for (int i = 0; i < 3; ++i) {
    wtap_conv<<<36, 256, 0, stream>>>(rconv1_w + i * 9216, wt1h);
    conv_mfma<0><<<dim3(8, 64, 16), 256, 0, stream>>>(hA, wt1h,
        rconv1_b + i * 32, rbn1_g + i * 32, rbn1_b + i * 32,
        rbn1_m + i * 32, rbn1_v + i * 32, hB);
    wtap_conv<<<36, 256, 0, stream>>>(rconv2_w + i * 9216, wt2h);
    conv_mfma<1><<<dim3(8, 64, 16), 256, 0, stream>>>(hB, wt2h,
        rconv2_b + i * 32, rbn2_g + i * 32, rbn2_b + i * 32,
        rbn2_m + i * 32, rbn2_v + i * 32, hA);
  }

  // ---- SRU layer 0 (k=4, F=2048) ----
  __hip_bfloat16* xn0  = Bh;                   // 64 MB (hB dead)
  __hip_bfloat16* Wp0t = Ah + 52428800;        // 1 MB @ A+100MB
  __hip_bfloat16* tmp0 = Bh + 50331648;        // 8 MB @ B+96MB
  __hip_bfloat16* W0p  = Bh + 57671680;        // 2 MB @ B+110MB
  __hip_bfloat16* U    = Ah;                   // 128 MB (rows = 4096)
  __hip_bfloat16* s2h  = Bh;                   // 32 MB bf16 (xn0 dead)

  ln_nhwc<<<16384, 256, 0, stream>>>(hA, ln0_g, ln0_b, xn0);
  wt_perm0<<<2048, 256, 0, stream>>>(wproj0, Wp0t);
  gemm_bf16<<<dim3(2, 128), 256, 0, stream>>>(xn0, Wp0t, tmp0, 16384, 256, 2048);
  wexp_prep<<<dim3(16, 8, 8), dim3(32, 8), 0, stream>>>(w0, W0p, 4);
  gemm_bf16<<<dim3(32, 128), 256, 0, stream>>>(tmp0, W0p, U, 16384, 4096, 256);
  sru_scan<1><<<256, 64, 0, stream>>>(U, nullptr, vc0, bias0, s2h);

  // ---- SRU layers 1..3 (k=3 padded to 4, F=1024) ----
  __hip_bfloat16* xn3  = Bh + 33554432;        // 32 MB @ B+64MB
  __hip_bfloat16* tmp3 = Bh + 50331648;        // 8 MB @ B+96MB
  __hip_bfloat16* W3p  = Bh + 54525952;        // 2 MB @ B+104MB
  __hip_bfloat16* Wpt3 = Bh + 55574528;        // 0.5 MB @ B+106MB
  for (int i = 0; i < 3; ++i) {
    ln_rows_h<<<16384, 256, 0, stream>>>(s2h, ln_g + i * 1024, ln_b + i * 1024, xn3);
    wt_bf16<<<dim3(8, 32), dim3(32, 8), 0, stream>>>(wproj + i * 262144, Wpt3,
                                                     1024, 256);
    gemm_bf16<<<dim3(2, 128), 256, 0, stream>>>(xn3, Wpt3, tmp3, 16384, 256, 1024);
    wexp_prep<<<dim3(16, 8, 8), dim3(32, 8), 0, stream>>>(w + i * 786432, W3p, 3);
    gemm_bf16<<<dim3(32, 128), 256, 0, stream>>>(tmp3, W3p, U, 16384, 4096, 256);
    sru_scan<0><<<256, 64, 0, stream>>>(U, xn3, vc + i * 2048, bias + i * 2048, s2h);
  }

  // ---- final LN + classifier (skinny MFMA GEMM) ----
  __hip_bfloat16* xnc = Bh + 16777216;         // 32 MB @ B+32MB
  __hip_bfloat16* Wct = Ah;                    // 64 KB (U dead)
  ln_rows_h<<<16384, 256, 0, stream>>>(s2h, cln_g, cln_b, xnc);
  wct_prep<<<128, 256, 0, stream>>>(cls_w, Wct);
  cls_gemm<<<256, 256, 0, stream>>>(xnc, Wct, out);
}

// Round 9
// 1324.900 us; speedup vs baseline: 13.8519x; 1.0553x over previous
//
#include <hip/hip_runtime.h>
#include <hip/hip_bf16.h>
#include <math.h>

#define DEV __device__ __forceinline__

typedef __attribute__((ext_vector_type(8))) short short8;
typedef __attribute__((ext_vector_type(4))) float floatx4;

DEV float b2f_lo(unsigned u) { return __uint_as_float(u << 16); }
DEV float b2f_hi(unsigned u) { return __uint_as_float(u & 0xffff0000u); }

#if __has_builtin(__builtin_amdgcn_exp2f)
DEV float fexp2_(float x) { return __builtin_amdgcn_exp2f(x); }
#else
DEV float fexp2_(float x) { return exp2f(x); }
#endif
#if __has_builtin(__builtin_amdgcn_rcpf)
DEV float frcp_(float x) { return __builtin_amdgcn_rcpf(x); }
#else
DEV float frcp_(float x) { return 1.f / x; }
#endif

// async global->LDS, 16B per lane; LDS dest = uniform base + lane*16
DEV void gl2lds16(const void* g, void* l) {
  __builtin_amdgcn_global_load_lds(
      (const __attribute__((address_space(1))) unsigned int*)g,
      (__attribute__((address_space(3))) unsigned int*)l, 16, 0, 0);
}

union U8 { uint4 u; __hip_bfloat16 h[8]; };

// ------- conv stem: (16,1,128,2048) -> NHWC bf16 h[n][f][t][oc], s2 p1 -------
__global__ __launch_bounds__(256) void conv_stem_nhwc(const float* __restrict__ x,
    const float* __restrict__ w, const float* __restrict__ bias,
    __hip_bfloat16* __restrict__ out) {
  int idx = blockIdx.x * 256 + threadIdx.x;
  int ocq = idx & 3;
  int t  = (idx >> 2) & 1023;
  int f  = (idx >> 12) & 63;
  int n  = idx >> 18;
  const float* xb = x + (size_t)n * 262144;
  float xv[9];
#pragma unroll
  for (int df = 0; df < 3; ++df) {
    int fi = 2 * f + df - 1;
#pragma unroll
    for (int dc = 0; dc < 3; ++dc) {
      int ti = 2 * t + dc - 1;
      xv[df * 3 + dc] = (fi >= 0 && fi < 128 && ti >= 0 && ti < 2048)
                          ? xb[fi * 2048 + ti] : 0.f;
    }
  }
  U8 o;
#pragma unroll
  for (int oo = 0; oo < 8; ++oo) {
    int oc = ocq * 8 + oo;
    float acc = bias[oc];
#pragma unroll
    for (int q = 0; q < 9; ++q) acc += w[oc * 9 + q] * xv[q];
    o.h[oo] = __float2bfloat16(acc);
  }
  *(uint4*)&out[(((size_t)n * 64 + f) * 1024 + t) * 32 + ocq * 8] = o.u;
}

// ----- weight swizzle: (32oc,32ic,3,3) fp32 -> [tap][oc][ic] bf16 (9216) -----
__global__ __launch_bounds__(256) void wtap_conv(const float* __restrict__ in,
    __hip_bfloat16* __restrict__ out) {
  int i = blockIdx.x * 256 + threadIdx.x;
  if (i < 9216) {
    int tap = i >> 10;
    int oc = (i >> 5) & 31;
    int ic = i & 31;
    out[i] = __float2bfloat16(in[(oc * 32 + ic) * 9 + tap]);
  }
}

// ------ residual conv 3x3 via MFMA implicit GEMM (NHWC bf16) + BN/res/ReLU ---
template <int ADD>
__global__ __launch_bounds__(256) void conv_mfma(const __hip_bfloat16* __restrict__ Hin,
    const __hip_bfloat16* __restrict__ wt,
    const float* __restrict__ cb, const float* __restrict__ bg,
    const float* __restrict__ bb, const float* __restrict__ bm,
    const float* __restrict__ bv, __hip_bfloat16* Hres) {
  __shared__ __hip_bfloat16 sIn[3 * 130 * 40];
  __hip_bfloat16* sOut = sIn;
  const int tid = threadIdx.x;
  const int tb = blockIdx.x, f = blockIdx.y, n = blockIdx.z;
  const int t0 = tb * 128;
  const __hip_bfloat16* Hb = Hin + (size_t)n * 64 * 1024 * 32;

  for (int c = tid; c < 1560; c += 256) {
    int df = c / 520;
    int r = c - df * 520;
    int p = r >> 2, icq = r & 3;
    int fi = f + df - 1;
    int tg = t0 + p - 1;
    uint4 v = {0, 0, 0, 0};
    if (fi >= 0 && fi < 64 && tg >= 0 && tg < 1024)
      v = *(const uint4*)&Hb[((size_t)fi * 1024 + tg) * 32 + icq * 8];
    *(uint4*)&sIn[(df * 130 + p) * 40 + icq * 8] = v;
  }

  const int lane = tid & 63, wave = tid >> 6;
  const int fr = lane & 15, fq = lane >> 4;
  short8 bfrag[9][2];
#pragma unroll
  for (int tap = 0; tap < 9; ++tap)
#pragma unroll
    for (int j = 0; j < 2; ++j)
      bfrag[tap][j] = *(const short8*)&wt[(tap * 32 + j * 16 + fr) * 32 + fq * 8];

  __syncthreads();

  const int t0w = wave * 32;
  floatx4 acc[2][2];
#pragma unroll
  for (int mi = 0; mi < 2; ++mi)
#pragma unroll
    for (int j = 0; j < 2; ++j) acc[mi][j] = (floatx4){0.f, 0.f, 0.f, 0.f};

#pragma unroll
  for (int mi = 0; mi < 2; ++mi) {
    int tbase = t0w + mi * 16;
#pragma unroll
    for (int df = 0; df < 3; ++df)
#pragma unroll
      for (int dc = 0; dc < 3; ++dc) {
        int p = tbase + fr + dc;
        short8 af = *(const short8*)&sIn[(df * 130 + p) * 40 + fq * 8];
        acc[mi][0] = __builtin_amdgcn_mfma_f32_16x16x32_bf16(
            af, bfrag[df * 3 + dc][0], acc[mi][0], 0, 0, 0);
        acc[mi][1] = __builtin_amdgcn_mfma_f32_16x16x32_bf16(
            af, bfrag[df * 3 + dc][1], acc[mi][1], 0, 0, 0);
      }
  }

  float sc0 = bg[fr] * rsqrtf(bv[fr] + 1e-5f);
  float sh0 = (cb[fr] - bm[fr]) * sc0 + bb[fr];
  float sc1 = bg[fr + 16] * rsqrtf(bv[fr + 16] + 1e-5f);
  float sh1 = (cb[fr + 16] - bm[fr + 16]) * sc1 + bb[fr + 16];

  __syncthreads();
#pragma unroll
  for (int mi = 0; mi < 2; ++mi)
#pragma unroll
    for (int j = 0; j < 2; ++j) {
      float sc = j ? sc1 : sc0, sh = j ? sh1 : sh0;
#pragma unroll
      for (int reg = 0; reg < 4; ++reg) {
        int t_l = t0w + mi * 16 + fq * 4 + reg;
        sOut[t_l * 40 + j * 16 + fr] = __float2bfloat16(acc[mi][j][reg] * sc + sh);
      }
    }
  __syncthreads();

  for (int c = tid; c < 512; c += 256) {
    int t_l = c >> 2, icq = c & 3;
    U8 y;
    y.u = *(uint4*)&sOut[t_l * 40 + icq * 8];
    size_t addr = (((size_t)n * 64 + f) * 1024 + t0 + t_l) * 32 + icq * 8;
    U8 o;
    if (ADD) {
      U8 r;
      r.u = *(const uint4*)&Hres[addr];
#pragma unroll
      for (int i = 0; i < 8; ++i)
        o.h[i] = __float2bfloat16(
            fmaxf(__bfloat162float(y.h[i]) + __bfloat162float(r.h[i]), 0.f));
    } else {
#pragma unroll
      for (int i = 0; i < 8; ++i)
        o.h[i] = __float2bfloat16(fmaxf(__bfloat162float(y.h[i]), 0.f));
    }
    *(uint4*)&Hres[addr] = o.u;
  }
}

// ------ LN over NHWC row (t,n): F=2048, k-order k' = f*32+ic, bf16 out -------
__global__ __launch_bounds__(256) void ln_nhwc(const __hip_bfloat16* __restrict__ H,
    const float* __restrict__ g, const float* __restrict__ b,
    __hip_bfloat16* __restrict__ xn) {
  int r = blockIdx.x;
  int t = r >> 4, n = r & 15;
  int tid = threadIdx.x;
  int f = tid >> 2, icq = tid & 3;
  U8 v;
  v.u = *(const uint4*)&H[(((size_t)n * 64 + f) * 1024 + t) * 32 + icq * 8];
  float xv[8];
  float sum = 0.f, ss = 0.f;
#pragma unroll
  for (int i = 0; i < 8; ++i) {
    xv[i] = __bfloat162float(v.h[i]);
    sum += xv[i];
    ss += xv[i] * xv[i];
  }
#pragma unroll
  for (int off = 32; off > 0; off >>= 1) {
    sum += __shfl_down(sum, off);
    ss  += __shfl_down(ss, off);
  }
  __shared__ float red[8];
  int lane = tid & 63, wave = tid >> 6;
  if (lane == 0) { red[wave] = sum; red[4 + wave] = ss; }
  __syncthreads();
  sum = red[0] + red[1] + red[2] + red[3];
  ss  = red[4] + red[5] + red[6] + red[7];
  float mean = sum * (1.f / 2048.f);
  float var = ss * (1.f / 2048.f) - mean * mean;
  float inv = rsqrtf(var + 1e-5f);
  U8 o;
#pragma unroll
  for (int i = 0; i < 8; ++i) {
    int cf = (icq * 8 + i) * 64 + f;
    o.h[i] = __float2bfloat16((xv[i] - mean) * inv * g[cf] + b[cf]);
  }
  *(uint4*)&xn[(size_t)r * 2048 + tid * 8] = o.u;
}

// -- wproj0 permuted transpose: Wp0t[p][k'=f*32+ic] = wproj0[ic*64+f][p] bf16 --
__global__ __launch_bounds__(256) void wt_perm0(const float* __restrict__ in,
    __hip_bfloat16* __restrict__ out) {
  int i = blockIdx.x * 256 + threadIdx.x;
  int p = i >> 11, kp = i & 2047;
  int ic = kp & 31, f = kp >> 5;
  out[i] = __float2bfloat16(in[(ic * 64 + f) * 256 + p]);
}

// -------- LayerNorm bf16 rows F=1024 -> bf16 out -----------------------------
__global__ __launch_bounds__(256) void ln_rows_h(const __hip_bfloat16* __restrict__ in,
    const float* __restrict__ g, const float* __restrict__ b,
    __hip_bfloat16* __restrict__ out) {
  int r = blockIdx.x;
  int tid = threadIdx.x;
  union { ushort4 u; __hip_bfloat16 h[4]; } iv;
  iv.u = *(const ushort4*)&in[(size_t)r * 1024 + tid * 4];
  float x0 = __bfloat162float(iv.h[0]);
  float x1 = __bfloat162float(iv.h[1]);
  float x2 = __bfloat162float(iv.h[2]);
  float x3 = __bfloat162float(iv.h[3]);
  float sum = x0 + x1 + x2 + x3;
  float ss = x0 * x0 + x1 * x1 + x2 * x2 + x3 * x3;
#pragma unroll
  for (int off = 32; off > 0; off >>= 1) {
    sum += __shfl_down(sum, off);
    ss  += __shfl_down(ss, off);
  }
  __shared__ float red[8];
  int lane = tid & 63, wave = tid >> 6;
  if (lane == 0) { red[wave] = sum; red[4 + wave] = ss; }
  __syncthreads();
  sum = red[0] + red[1] + red[2] + red[3];
  ss  = red[4] + red[5] + red[6] + red[7];
  float mean = sum * (1.f / 1024.f);
  float var = ss * (1.f / 1024.f) - mean * mean;
  float inv = rsqrtf(var + 1e-5f);
  float4 gv = *(const float4*)&g[tid * 4];
  float4 bv = *(const float4*)&b[tid * 4];
  union { ushort4 u; __hip_bfloat16 h[4]; } o;
  o.h[0] = __float2bfloat16((x0 - mean) * inv * gv.x + bv.x);
  o.h[1] = __float2bfloat16((x1 - mean) * inv * gv.y + bv.y);
  o.h[2] = __float2bfloat16((x2 - mean) * inv * gv.z + bv.z);
  o.h[3] = __float2bfloat16((x3 - mean) * inv * gv.w + bv.w);
  *(ushort4*)&out[(size_t)r * 1024 + tid * 4] = o.u;
}

// ---- res transpose: xn[r=t*16+n][c] -> resT[c][n][t] (all bf16) -------------
__global__ __launch_bounds__(256) void resT_pack(const __hip_bfloat16* __restrict__ xn,
    __hip_bfloat16* __restrict__ rT) {
  __shared__ __hip_bfloat16 tile[32][33];
  int t0 = blockIdx.x * 32, k0 = blockIdx.y * 32, n = blockIdx.z;
  int tx = threadIdx.x, ty = threadIdx.y;
#pragma unroll
  for (int i = 0; i < 4; ++i) {
    int yy = ty + i * 8;
    tile[yy][tx] = xn[(size_t)((t0 + yy) * 16 + n) * 1024 + k0 + tx];
  }
  __syncthreads();
#pragma unroll
  for (int i = 0; i < 4; ++i) {
    int yy = ty + i * 8;
    rT[(size_t)(k0 + yy) * 16384 + n * 1024 + t0 + tx] = tile[tx][yy];
  }
}

// ------- weight convert+transpose: in (K x N) fp32 -> out (N x K) bf16 -------
__global__ __launch_bounds__(256) void wt_bf16(const float* __restrict__ in,
    __hip_bfloat16* __restrict__ out, int K, int N) {
  __shared__ float tile[32][33];
  int x = threadIdx.x, y0 = threadIdx.y;
  int bn = blockIdx.x * 32;
  int bk = blockIdx.y * 32;
#pragma unroll
  for (int i = 0; i < 4; ++i) {
    int yy = y0 + i * 8;
    tile[yy][x] = in[(size_t)(bk + yy) * N + bn + x];
  }
  __syncthreads();
#pragma unroll
  for (int i = 0; i < 4; ++i) {
    int yy = y0 + i * 8;
    out[(size_t)(bn + yy) * K + bk + x] = __float2bfloat16(tile[x][yy]);
  }
}

// ---- expansion weight prep: w (256 x korig*1024) fp32 ->
// ---- Bt[(d*512+j)*4+k][ck] bf16 (4096 x 256), k>=korig rows zeroed ----------
__global__ void wexp_prep(const float* __restrict__ in,
    __hip_bfloat16* __restrict__ out, int korig) {
  __shared__ float tile[32][33];
  int jt = blockIdx.x;
  int ckt = blockIdx.y;
  int dk = blockIdx.z;
  int d = dk >> 2, k = dk & 3;
  int x = threadIdx.x, y0 = threadIdx.y;
  bool valid = (k < korig);
#pragma unroll
  for (int i = 0; i < 4; ++i) {
    int yy = y0 + i * 8;
    tile[yy][x] = valid
        ? in[(size_t)(ckt * 32 + yy) * (korig * 1024) + (d * korig + k) * 512 +
             jt * 32 + x]
        : 0.f;
  }
  __syncthreads();
#pragma unroll
  for (int i = 0; i < 4; ++i) {
    int yy = y0 + i * 8;
    out[(size_t)((d * 512 + jt * 32 + yy) * 4 + k) * 256 + ckt * 32 + x] =
        __float2bfloat16(tile[x][yy]);
  }
}

// ---- cls_w (1024x30) fp32 -> Wct (32x1024) bf16, rows >=30 zero -------------
__global__ __launch_bounds__(256) void wct_prep(const float* __restrict__ in,
    __hip_bfloat16* __restrict__ out) {
  int i = blockIdx.x * 256 + threadIdx.x;
  int nn = i >> 10, kk = i & 1023;
  out[i] = __float2bfloat16(nn < 30 ? in[kk * 30 + nn] : 0.f);
}

// -------- bf16 MFMA GEMM (m97 structure): C = A(MxK) @ Bt(NxK)^T -------------
// 128x128 tile, BK=32, global_load_lds 16B staging into unpadded LDS.
__global__ __launch_bounds__(256) void gemm_bf16(const __hip_bfloat16* __restrict__ A,
    const __hip_bfloat16* __restrict__ Bt, __hip_bfloat16* __restrict__ C,
    int M, int N, int K) {
  __shared__ __hip_bfloat16 As[128 * 32];   // 8 KB, rows stride 32
  __shared__ __hip_bfloat16 Bs[128 * 32];
  const int tid = threadIdx.x;
  const int m0 = blockIdx.y * 128, n0 = blockIdx.x * 128;
  const int lane = tid & 63, wave = tid >> 6;
  const int wm = wave & 1, wn = wave >> 1;
  const int fr = lane & 15, fq = lane >> 4;
  const int srow = lane >> 2, sch = lane & 3;   // staging: 16 rows per inst

  const __hip_bfloat16* ga0 = &A[(size_t)(m0 + wave * 32 + srow) * K + sch * 8];
  const __hip_bfloat16* ga1 = ga0 + (size_t)16 * K;
  const __hip_bfloat16* gb0 = &Bt[(size_t)(n0 + wave * 32 + srow) * K + sch * 8];
  const __hip_bfloat16* gb1 = gb0 + (size_t)16 * K;
  __hip_bfloat16* la0 = &As[(wave * 32) * 32];
  __hip_bfloat16* la1 = &As[(wave * 32 + 16) * 32];
  __hip_bfloat16* lb0 = &Bs[(wave * 32) * 32];
  __hip_bfloat16* lb1 = &Bs[(wave * 32 + 16) * 32];

  floatx4 acc[4][4];
#pragma unroll
  for (int i = 0; i < 4; ++i)
#pragma unroll
    for (int j = 0; j < 4; ++j)
      acc[i][j] = (floatx4){0.f, 0.f, 0.f, 0.f};

  for (int k0 = 0; k0 < K; k0 += 32) {
    __syncthreads();
    gl2lds16(ga0 + k0, la0);
    gl2lds16(ga1 + k0, la1);
    gl2lds16(gb0 + k0, lb0);
    gl2lds16(gb1 + k0, lb1);
    __syncthreads();

    short8 af[4], bf_[4];
#pragma unroll
    for (int i = 0; i < 4; ++i) {
      af[i]  = *(const short8*)&As[(wm * 64 + i * 16 + fr) * 32 + fq * 8];
      bf_[i] = *(const short8*)&Bs[(wn * 64 + i * 16 + fr) * 32 + fq * 8];
    }
#pragma unroll
    for (int i = 0; i < 4; ++i)
#pragma unroll
      for (int j = 0; j < 4; ++j)
        acc[i][j] = __builtin_amdgcn_mfma_f32_16x16x32_bf16(af[i], bf_[j],
                                                            acc[i][j], 0, 0, 0);
  }

#pragma unroll
  for (int i = 0; i < 4; ++i)
#pragma unroll
    for (int j = 0; j < 4; ++j)
#pragma unroll
      for (int reg = 0; reg < 4; ++reg) {
        int row = m0 + wm * 64 + i * 16 + fq * 4 + reg;
        int col = n0 + wn * 64 + j * 16 + fr;
        C[(size_t)row * N + col] = __float2bfloat16(acc[i][j][reg]);
      }
}

// ------- skinny classifier GEMM: out[n][t][30] = xnc(16384x1024) @ Wct^T -----
__global__ __launch_bounds__(256) void cls_gemm(const __hip_bfloat16* __restrict__ A,
    const __hip_bfloat16* __restrict__ Wct, float* __restrict__ out) {
  const int tid = threadIdx.x;
  const int lane = tid & 63, wave = tid >> 6;
  const int fr = lane & 15, fq = lane >> 4;
  const int m0 = (blockIdx.x * 4 + wave) * 16;
  floatx4 acc[2];
  acc[0] = (floatx4){0.f, 0.f, 0.f, 0.f};
  acc[1] = (floatx4){0.f, 0.f, 0.f, 0.f};
#pragma unroll 4
  for (int k0 = 0; k0 < 1024; k0 += 32) {
    short8 af = *(const short8*)&A[(size_t)(m0 + fr) * 1024 + k0 + fq * 8];
    short8 b0 = *(const short8*)&Wct[(size_t)fr * 1024 + k0 + fq * 8];
    short8 b1 = *(const short8*)&Wct[(size_t)(16 + fr) * 1024 + k0 + fq * 8];
    acc[0] = __builtin_amdgcn_mfma_f32_16x16x32_bf16(af, b0, acc[0], 0, 0, 0);
    acc[1] = __builtin_amdgcn_mfma_f32_16x16x32_bf16(af, b1, acc[1], 0, 0, 0);
  }
#pragma unroll
  for (int j = 0; j < 2; ++j) {
    int col = j * 16 + fr;
    if (col < 30) {
#pragma unroll
      for (int reg = 0; reg < 4; ++reg) {
        int row = m0 + fq * 4 + reg;
        int t = row >> 4, n = row & 15;
        out[(size_t)n * 30720 + t * 30 + col] = acc[j][reg];
      }
    }
  }
}

// ---------------- SRU bidirectional scan -------------------------------------
// U rows 4096 = [d][j][k4]; res in resT[c][n][t] (contiguous in t).
// chunk = 16 steps, 4 buffers, prefetch depth 3 (<=54 outstanding loads).
template <int K4>
__global__ __launch_bounds__(64) void sru_scan(const __hip_bfloat16* __restrict__ U,
    const __hip_bfloat16* __restrict__ resT, const float* __restrict__ vc,
    const float* __restrict__ bias, __hip_bfloat16* __restrict__ out) {
  int gid = blockIdx.x * 64 + threadIdx.x;
  int j = gid & 511;
  int n = (gid >> 9) & 15;
  int d = gid >> 13;                         // wave-uniform
  const float NL2E = -1.44269504f;
  float vf2 = NL2E * vc[(d * 2 + 0) * 512 + j];
  float vr2 = NL2E * vc[(d * 2 + 1) * 512 + j];
  float bf2 = NL2E * bias[(d * 2 + 0) * 512 + j];
  float br2 = NL2E * bias[(d * 2 + 1) * 512 + j];

  const char* Ub = (const char*)(U + (size_t)n * 4096 + d * 2048) + (size_t)j * 8;
  const char* Rb = K4 ? nullptr
      : (const char*)(resT + (size_t)(d * 512 + j) * 16384 + n * 1024);
  char* Ob = (char*)(out + (size_t)n * 1024 + d * 512) + (size_t)j * 2;
  const int US = d ? -131072 : 131072;       // U byte stride per t
  const int OS = d ? -32768 : 32768;         // out byte stride per t
  int uoff = d ? 1023 * 131072 : 0;
  int ooff = d ? 1023 * 32768 : 0;
  int roff = d ? 2016 : 0;                   // res chunk base byte offset
  const int RS = d ? -32 : 32;               // res byte step per chunk

  uint2 B0[16], B1[16], B2[16], B3[16];
  U8 R0[2], R1[2], R2[2], R3[2];
  float c = 0.f;

#define LOADC(UB, RB)                                                     \
  {                                                                       \
    _Pragma("unroll") for (int ss = 0; ss < 16; ++ss) {                   \
      UB[ss] = *(const uint2*)(Ub + uoff);                                \
      uoff += US;                                                         \
    }                                                                     \
    if (!K4) {                                                            \
      RB[0].u = *(const uint4*)(Rb + roff);                               \
      RB[1].u = *(const uint4*)(Rb + roff + 16);                          \
      roff += RS;                                                         \
    }                                                                     \
  }

#define COMPC(UB, RB)                                                     \
  {                                                                       \
    _Pragma("unroll") for (int ss = 0; ss < 16; ++ss) {                   \
      uint2 uv = UB[ss];                                                  \
      float a0 = b2f_lo(uv.x), a1 = b2f_hi(uv.x), a2 = b2f_lo(uv.y);      \
      float rx;                                                           \
      if (K4) {                                                           \
        rx = b2f_hi(uv.y);                                                \
      } else {                                                            \
        __hip_bfloat16 rf = RB[ss >> 3].h[ss & 7];                        \
        __hip_bfloat16 rr = RB[(15 - ss) >> 3].h[(15 - ss) & 7];          \
        rx = __bfloat162float(d ? rr : rf);                               \
      }                                                                   \
      float A1 = fmaf(a1, NL2E, bf2);                                     \
      float f = frcp_(1.f + fexp2_(fmaf(vf2, c, A1)));                    \
      float c2 = fmaf(f, c - a0, a0);                                     \
      float A2 = fmaf(a2, NL2E, br2);                                     \
      float r = frcp_(1.f + fexp2_(fmaf(vr2, c2, A2)));                   \
      float y = fmaf(r, c2 - rx, rx);                                     \
      *(__hip_bfloat16*)(Ob + ooff) = __float2bfloat16(y);                \
      ooff += OS;                                                         \
      c = c2;                                                             \
    }                                                                     \
  }

  LOADC(B0, R0);
  LOADC(B1, R1);
  LOADC(B2, R2);
  for (int cb = 0; cb < 64; cb += 4) {
    LOADC(B3, R3);
    COMPC(B0, R0);
    if (cb + 4 < 64) LOADC(B0, R0);
    COMPC(B1, R1);
    if (cb + 5 < 64) LOADC(B1, R1);
    COMPC(B2, R2);
    if (cb + 6 < 64) LOADC(B2, R2);
    COMPC(B3, R3);
  }
#undef LOADC
#undef COMPC
}

extern "C" void kernel_launch(void* const* d_in, const int* in_sizes, int n_in,
                              void* d_out, int out_size, void* d_ws, size_t ws_size,
                              hipStream_t stream) {
  const float* x        = (const float*)d_in[0];
  const float* conv0_w  = (const float*)d_in[1];
  const float* conv0_b  = (const float*)d_in[2];
  const float* rconv1_w = (const float*)d_in[3];
  const float* rconv1_b = (const float*)d_in[4];
  const float* rbn1_g   = (const float*)d_in[5];
  const float* rbn1_b   = (const float*)d_in[6];
  const float* rbn1_m   = (const float*)d_in[7];
  const float* rbn1_v   = (const float*)d_in[8];
  const float* rconv2_w = (const float*)d_in[9];
  const float* rconv2_b = (const float*)d_in[10];
  const float* rbn2_g   = (const float*)d_in[11];
  const float* rbn2_b   = (const float*)d_in[12];
  const float* rbn2_m   = (const float*)d_in[13];
  const float* rbn2_v   = (const float*)d_in[14];
  const float* ln0_g    = (const float*)d_in[15];
  const float* ln0_b    = (const float*)d_in[16];
  const float* wproj0   = (const float*)d_in[17];
  const float* w0       = (const float*)d_in[18];
  const float* vc0      = (const float*)d_in[19];
  const float* bias0    = (const float*)d_in[20];
  const float* ln_g     = (const float*)d_in[21];
  const float* ln_b     = (const float*)d_in[22];
  const float* wproj    = (const float*)d_in[23];
  const float* w        = (const float*)d_in[24];
  const float* vc       = (const float*)d_in[25];
  const float* bias     = (const float*)d_in[26];
  const float* cln_g    = (const float*)d_in[27];
  const float* cln_b    = (const float*)d_in[28];
  const float* cls_w    = (const float*)d_in[29];
  float* out = (float*)d_out;

  // Two 128 MiB arenas.
  float* Af = (float*)d_ws;
  float* Bf = Af + 33554432;
  __hip_bfloat16* Ah = (__hip_bfloat16*)Af;
  __hip_bfloat16* Bh = (__hip_bfloat16*)Bf;

  __hip_bfloat16* hA   = Ah;                   // NHWC h (67 MB)
  __hip_bfloat16* hB   = Bh;                   // NHWC temp
  __hip_bfloat16* wt1h = Ah + 62914560;        // 18 KB @ A+120MB
  __hip_bfloat16* wt2h = Ah + 62931952;        // next 18 KB

  conv_stem_nhwc<<<16384, 256, 0, stream>>>(x, conv0_w, conv0_b, hA);
  for (int i = 0; i < 3; ++i) {
    wtap_conv<<<36, 256, 0, stream>>>(rconv1_w + i * 9216, wt1h);
    conv_mfma<0><<<dim3(8, 64, 16), 256, 0, stream>>>(hA, wt1h,
        rconv1_b + i * 32, rbn1_g + i * 32, rbn1_b + i * 32,
        rbn1_m + i * 32, rbn1_v + i * 32, hB);
    wtap_conv<<<36, 256, 0, stream>>>(rconv2_w + i * 9216, wt2h);
    conv_mfma<1><<<dim3(8, 64, 16), 256, 0, stream>>>(hB, wt2h,
        rconv2_b + i * 32, rbn2_g + i * 32, rbn2_b + i * 32,
        rbn2_m + i * 32, rbn2_v + i * 32, hA);
  }

  // ---- SRU layer 0 (k=4, F=2048) ----
  __hip_bfloat16* xn0  = Bh;                   // 64 MB (hB dead)
  __hip_bfloat16* Wp0t = Ah + 52428800;        // 1 MB @ A+100MB
  __hip_bfloat16* tmp0 = Bh + 50331648;        // 8 MB @ B+96MB
  __hip_bfloat16* W0p  = Bh + 57671680;        // 2 MB @ B+110MB
  __hip_bfloat16* U    = Ah;                   // 128 MB (rows = 4096)
  __hip_bfloat16* s2h  = Bh;                   // 32 MB bf16

  ln_nhwc<<<16384, 256, 0, stream>>>(hA, ln0_g, ln0_b, xn0);
  wt_perm0<<<2048, 256, 0, stream>>>(wproj0, Wp0t);
  gemm_bf16<<<dim3(2, 128), 256, 0, stream>>>(xn0, Wp0t, tmp0, 16384, 256, 2048);
  wexp_prep<<<dim3(16, 8, 8), dim3(32, 8), 0, stream>>>(w0, W0p, 4);
  gemm_bf16<<<dim3(32, 128), 256, 0, stream>>>(tmp0, W0p, U, 16384, 4096, 256);
  sru_scan<1><<<256, 64, 0, stream>>>(U, nullptr, vc0, bias0, s2h);

  // ---- SRU layers 1..3 (k=3 padded to 4, F=1024) ----
  __hip_bfloat16* xn3  = Bh + 33554432;        // 32 MB @ B+64MB
  __hip_bfloat16* resT = Bh + 16777216;        // 32 MB @ B+32MB
  __hip_bfloat16* tmp3 = Bh + 50331648;        // 8 MB @ B+96MB
  __hip_bfloat16* W3p  = Bh + 54525952;        // 2 MB @ B+104MB
  __hip_bfloat16* Wpt3 = Bh + 55574528;        // 0.5 MB @ B+106MB
  for (int i = 0; i < 3; ++i) {
    ln_rows_h<<<16384, 256, 0, stream>>>(s2h, ln_g + i * 1024, ln_b + i * 1024, xn3);
    resT_pack<<<dim3(32, 32, 16), dim3(32, 8), 0, stream>>>(xn3, resT);
    wt_bf16<<<dim3(8, 32), dim3(32, 8), 0, stream>>>(wproj + i * 262144, Wpt3,
                                                     1024, 256);
    gemm_bf16<<<dim3(2, 128), 256, 0, stream>>>(xn3, Wpt3, tmp3, 16384, 256, 1024);
    wexp_prep<<<dim3(16, 8, 8), dim3(32, 8), 0, stream>>>(w + i * 786432, W3p, 3);
    gemm_bf16<<<dim3(32, 128), 256, 0, stream>>>(tmp3, W3p, U, 16384, 4096, 256);
    sru_scan<0><<<256, 64, 0, stream>>>(U, resT, vc + i * 2048, bias + i * 2048, s2h);
  }

  // ---- final LN + classifier (skinny MFMA GEMM) ----
  __hip_bfloat16* xnc = Bh + 16777216;         // 32 MB @ B+32MB (resT dead)
  __hip_bfloat16* Wct = Ah;                    // 64 KB (U dead)
  ln_rows_h<<<16384, 256, 0, stream>>>(s2h, cln_g, cln_b, xnc);
  wct_prep<<<128, 256, 0, stream>>>(cls_w, Wct);
  cls_gemm<<<256, 256, 0, stream>>>(xnc, Wct, out);
}

// Round 10
// 1237.390 us; speedup vs baseline: 14.8315x; 1.0707x over previous
//
#include <hip/hip_runtime.h>
#include <hip/hip_bf16.h>
#include <math.h>

#define DEV __device__ __forceinline__

typedef __attribute__((ext_vector_type(8))) short short8;
typedef __attribute__((ext_vector_type(4))) float floatx4;

DEV float b2f_lo(unsigned u) { return __uint_as_float(u << 16); }
DEV float b2f_hi(unsigned u) { return __uint_as_float(u & 0xffff0000u); }

#if __has_builtin(__builtin_amdgcn_exp2f)
DEV float fexp2_(float x) { return __builtin_amdgcn_exp2f(x); }
#else
DEV float fexp2_(float x) { return exp2f(x); }
#endif
#if __has_builtin(__builtin_amdgcn_rcpf)
DEV float frcp_(float x) { return __builtin_amdgcn_rcpf(x); }
#else
DEV float frcp_(float x) { return 1.f / x; }
#endif

// async global->LDS, 16B per lane; LDS dest = uniform base + lane*16
DEV void gl2lds16(const void* g, void* l) {
  __builtin_amdgcn_global_load_lds(
      (const __attribute__((address_space(1))) unsigned int*)g,
      (__attribute__((address_space(3))) unsigned int*)l, 16, 0, 0);
}

union U8 { uint4 u; __hip_bfloat16 h[8]; };

// ------- conv stem v2: LDS-staged rows; block=(f,n); thread = 4t x 32oc ------
__global__ __launch_bounds__(256) void conv_stem_nhwc(const float* __restrict__ x,
    const float* __restrict__ w, const float* __restrict__ bias,
    __hip_bfloat16* __restrict__ out) {
  __shared__ float sX[3][2052];   // col c+1 = x[c]; col 0 / 2049 are zero pads
  __shared__ float sW[288];
  __shared__ float sB[32];
  const int tid = threadIdx.x;
  const int f = blockIdx.x, n = blockIdx.y;
  const float* xb = x + (size_t)n * 262144;

  for (int i = tid; i < 1536; i += 256) {      // 3 rows x 512 float4
    int r = i >> 9, c4 = i & 511;
    int fi = 2 * f - 1 + r;
    float4 v = {0.f, 0.f, 0.f, 0.f};
    if (fi >= 0 && fi < 128) v = *(const float4*)&xb[fi * 2048 + c4 * 4];
    sX[r][1 + c4 * 4 + 0] = v.x;
    sX[r][1 + c4 * 4 + 1] = v.y;
    sX[r][1 + c4 * 4 + 2] = v.z;
    sX[r][1 + c4 * 4 + 3] = v.w;
  }
  if (tid < 3) { sX[tid][0] = 0.f; sX[tid][2049] = 0.f; }
  for (int i = tid; i < 288; i += 256) sW[i] = w[i];
  if (tid < 32) sB[tid] = bias[tid];
  __syncthreads();

  float xv[4][9];
#pragma unroll
  for (int q = 0; q < 4; ++q) {
    int t = tid + q * 256;
#pragma unroll
    for (int r = 0; r < 3; ++r)
#pragma unroll
      for (int dc = 0; dc < 3; ++dc)
        xv[q][r * 3 + dc] = sX[r][2 * t + dc];
  }
#pragma unroll
  for (int ocq = 0; ocq < 4; ++ocq) {
    float wr[8][9];
#pragma unroll
    for (int oo = 0; oo < 8; ++oo)
#pragma unroll
      for (int qq = 0; qq < 9; ++qq)
        wr[oo][qq] = sW[(ocq * 8 + oo) * 9 + qq];
#pragma unroll
    for (int q = 0; q < 4; ++q) {
      U8 o;
#pragma unroll
      for (int oo = 0; oo < 8; ++oo) {
        float acc = sB[ocq * 8 + oo];
#pragma unroll
        for (int qq = 0; qq < 9; ++qq) acc = fmaf(wr[oo][qq], xv[q][qq], acc);
        o.h[oo] = __float2bfloat16(acc);
      }
      int t = tid + q * 256;
      *(uint4*)&out[(((size_t)n * 64 + f) * 1024 + t) * 32 + ocq * 8] = o.u;
    }
  }
}

// ----- weight swizzle: (32oc,32ic,3,3) fp32 -> [tap][oc][ic] bf16 (9216) -----
__global__ __launch_bounds__(256) void wtap_conv(const float* __restrict__ in,
    __hip_bfloat16* __restrict__ out) {
  int i = blockIdx.x * 256 + threadIdx.x;
  if (i < 9216) {
    int tap = i >> 10;
    int oc = (i >> 5) & 31;
    int ic = i & 31;
    out[i] = __float2bfloat16(in[(oc * 32 + ic) * 9 + tap]);
  }
}

// ------ residual conv 3x3 MFMA v2: 4 output f-rows per block -----------------
// grid (tb:8, fb:16, n:16); stage 6 f-rows halo; wave = 32t x 32oc x 4f.
template <int ADD>
__global__ __launch_bounds__(256) void conv_mfma(const __hip_bfloat16* __restrict__ Hin,
    const __hip_bfloat16* __restrict__ wt,      // [9][32][32] bf16
    const float* __restrict__ cb, const float* __restrict__ bg,
    const float* __restrict__ bb, const float* __restrict__ bm,
    const float* __restrict__ bv, __hip_bfloat16* Hres) {
  __shared__ __hip_bfloat16 sIn[6 * 130 * 40];  // 62.4 KB
  __hip_bfloat16* sOut = sIn;                   // reuse after barrier [4][128][40]
  const int tid = threadIdx.x;
  const int tb = blockIdx.x, fb = blockIdx.y, n = blockIdx.z;
  const int t0 = tb * 128, f0 = fb * 4;
  const __hip_bfloat16* Hb = Hin + (size_t)n * 2097152;

  for (int c = tid; c < 3120; c += 256) {       // 6 rows x 130 p x 4 icq
    int rr = c / 520;
    int r2 = c - rr * 520;
    int p = r2 >> 2, icq = r2 & 3;
    int fi = f0 - 1 + rr;
    int tg = t0 + p - 1;
    uint4 v = {0, 0, 0, 0};
    if (fi >= 0 && fi < 64 && tg >= 0 && tg < 1024)
      v = *(const uint4*)&Hb[((size_t)fi * 1024 + tg) * 32 + icq * 8];
    *(uint4*)&sIn[(rr * 130 + p) * 40 + icq * 8] = v;
  }

  const int lane = tid & 63, wave = tid >> 6;
  const int fr = lane & 15, fq = lane >> 4;
  short8 bfrag[9][2];
#pragma unroll
  for (int tap = 0; tap < 9; ++tap)
#pragma unroll
    for (int j = 0; j < 2; ++j)
      bfrag[tap][j] = *(const short8*)&wt[(tap * 32 + j * 16 + fr) * 32 + fq * 8];

  __syncthreads();

  const int tw = wave * 32;
  floatx4 acc[4][2][2];                         // [f'][t-tile][oc-half]
#pragma unroll
  for (int fp = 0; fp < 4; ++fp)
#pragma unroll
    for (int mi = 0; mi < 2; ++mi)
#pragma unroll
      for (int j = 0; j < 2; ++j) acc[fp][mi][j] = (floatx4){0.f, 0.f, 0.f, 0.f};

#pragma unroll
  for (int fp = 0; fp < 4; ++fp) {
#pragma unroll
    for (int mi = 0; mi < 2; ++mi) {
      int pbase = tw + mi * 16 + fr;
#pragma unroll
      for (int df = 0; df < 3; ++df)
#pragma unroll
        for (int dc = 0; dc < 3; ++dc) {
          short8 af =
              *(const short8*)&sIn[((fp + df) * 130 + pbase + dc) * 40 + fq * 8];
          acc[fp][mi][0] = __builtin_amdgcn_mfma_f32_16x16x32_bf16(
              af, bfrag[df * 3 + dc][0], acc[fp][mi][0], 0, 0, 0);
          acc[fp][mi][1] = __builtin_amdgcn_mfma_f32_16x16x32_bf16(
              af, bfrag[df * 3 + dc][1], acc[fp][mi][1], 0, 0, 0);
        }
    }
  }

  float sc0 = bg[fr] * rsqrtf(bv[fr] + 1e-5f);
  float sh0 = (cb[fr] - bm[fr]) * sc0 + bb[fr];
  float sc1 = bg[fr + 16] * rsqrtf(bv[fr + 16] + 1e-5f);
  float sh1 = (cb[fr + 16] - bm[fr + 16]) * sc1 + bb[fr + 16];

  __syncthreads();
#pragma unroll
  for (int fp = 0; fp < 4; ++fp)
#pragma unroll
    for (int mi = 0; mi < 2; ++mi)
#pragma unroll
      for (int j = 0; j < 2; ++j) {
        float sc = j ? sc1 : sc0, sh = j ? sh1 : sh0;
#pragma unroll
        for (int reg = 0; reg < 4; ++reg) {
          int t_l = tw + mi * 16 + fq * 4 + reg;
          sOut[(fp * 128 + t_l) * 40 + j * 16 + fr] =
              __float2bfloat16(acc[fp][mi][j][reg] * sc + sh);
        }
      }
  __syncthreads();

  for (int c = tid; c < 2048; c += 256) {
    int fp = c >> 9, rem = c & 511;
    int t_l = rem >> 2, icq = rem & 3;
    U8 y;
    y.u = *(uint4*)&sOut[(fp * 128 + t_l) * 40 + icq * 8];
    size_t addr = (((size_t)n * 64 + f0 + fp) * 1024 + t0 + t_l) * 32 + icq * 8;
    U8 o;
    if (ADD) {
      U8 r;
      r.u = *(const uint4*)&Hres[addr];
#pragma unroll
      for (int i = 0; i < 8; ++i)
        o.h[i] = __float2bfloat16(
            fmaxf(__bfloat162float(y.h[i]) + __bfloat162float(r.h[i]), 0.f));
    } else {
#pragma unroll
      for (int i = 0; i < 8; ++i)
        o.h[i] = __float2bfloat16(fmaxf(__bfloat162float(y.h[i]), 0.f));
    }
    *(uint4*)&Hres[addr] = o.u;
  }
}

// ------ LN over NHWC row (t,n): F=2048, k-order k' = f*32+ic, bf16 out -------
__global__ __launch_bounds__(256) void ln_nhwc(const __hip_bfloat16* __restrict__ H,
    const float* __restrict__ g, const float* __restrict__ b,
    __hip_bfloat16* __restrict__ xn) {
  int r = blockIdx.x;
  int t = r >> 4, n = r & 15;
  int tid = threadIdx.x;
  int f = tid >> 2, icq = tid & 3;
  U8 v;
  v.u = *(const uint4*)&H[(((size_t)n * 64 + f) * 1024 + t) * 32 + icq * 8];
  float xv[8];
  float sum = 0.f, ss = 0.f;
#pragma unroll
  for (int i = 0; i < 8; ++i) {
    xv[i] = __bfloat162float(v.h[i]);
    sum += xv[i];
    ss += xv[i] * xv[i];
  }
#pragma unroll
  for (int off = 32; off > 0; off >>= 1) {
    sum += __shfl_down(sum, off);
    ss  += __shfl_down(ss, off);
  }
  __shared__ float red[8];
  int lane = tid & 63, wave = tid >> 6;
  if (lane == 0) { red[wave] = sum; red[4 + wave] = ss; }
  __syncthreads();
  sum = red[0] + red[1] + red[2] + red[3];
  ss  = red[4] + red[5] + red[6] + red[7];
  float mean = sum * (1.f / 2048.f);
  float var = ss * (1.f / 2048.f) - mean * mean;
  float inv = rsqrtf(var + 1e-5f);
  U8 o;
#pragma unroll
  for (int i = 0; i < 8; ++i) {
    int cf = (icq * 8 + i) * 64 + f;
    o.h[i] = __float2bfloat16((xv[i] - mean) * inv * g[cf] + b[cf]);
  }
  *(uint4*)&xn[(size_t)r * 2048 + tid * 8] = o.u;
}

// -- wproj0 permuted transpose: Wp0t[p][k'=f*32+ic] = wproj0[ic*64+f][p] bf16 --
__global__ __launch_bounds__(256) void wt_perm0(const float* __restrict__ in,
    __hip_bfloat16* __restrict__ out) {
  int i = blockIdx.x * 256 + threadIdx.x;
  int p = i >> 11, kp = i & 2047;
  int ic = kp & 31, f = kp >> 5;
  out[i] = __float2bfloat16(in[(ic * 64 + f) * 256 + p]);
}

// -------- LayerNorm bf16 rows F=1024 -> bf16 out -----------------------------
__global__ __launch_bounds__(256) void ln_rows_h(const __hip_bfloat16* __restrict__ in,
    const float* __restrict__ g, const float* __restrict__ b,
    __hip_bfloat16* __restrict__ out) {
  int r = blockIdx.x;
  int tid = threadIdx.x;
  union { ushort4 u; __hip_bfloat16 h[4]; } iv;
  iv.u = *(const ushort4*)&in[(size_t)r * 1024 + tid * 4];
  float x0 = __bfloat162float(iv.h[0]);
  float x1 = __bfloat162float(iv.h[1]);
  float x2 = __bfloat162float(iv.h[2]);
  float x3 = __bfloat162float(iv.h[3]);
  float sum = x0 + x1 + x2 + x3;
  float ss = x0 * x0 + x1 * x1 + x2 * x2 + x3 * x3;
#pragma unroll
  for (int off = 32; off > 0; off >>= 1) {
    sum += __shfl_down(sum, off);
    ss  += __shfl_down(ss, off);
  }
  __shared__ float red[8];
  int lane = tid & 63, wave = tid >> 6;
  if (lane == 0) { red[wave] = sum; red[4 + wave] = ss; }
  __syncthreads();
  sum = red[0] + red[1] + red[2] + red[3];
  ss  = red[4] + red[5] + red[6] + red[7];
  float mean = sum * (1.f / 1024.f);
  float var = ss * (1.f / 1024.f) - mean * mean;
  float inv = rsqrtf(var + 1e-5f);
  float4 gv = *(const float4*)&g[tid * 4];
  float4 bv = *(const float4*)&b[tid * 4];
  union { ushort4 u; __hip_bfloat16 h[4]; } o;
  o.h[0] = __float2bfloat16((x0 - mean) * inv * gv.x + bv.x);
  o.h[1] = __float2bfloat16((x1 - mean) * inv * gv.y + bv.y);
  o.h[2] = __float2bfloat16((x2 - mean) * inv * gv.z + bv.z);
  o.h[3] = __float2bfloat16((x3 - mean) * inv * gv.w + bv.w);
  *(ushort4*)&out[(size_t)r * 1024 + tid * 4] = o.u;
}

// ---- res transpose: xn[r=t*16+n][c] -> resT[c][n][t] (all bf16) -------------
__global__ __launch_bounds__(256) void resT_pack(const __hip_bfloat16* __restrict__ xn,
    __hip_bfloat16* __restrict__ rT) {
  __shared__ __hip_bfloat16 tile[32][33];
  int t0 = blockIdx.x * 32, k0 = blockIdx.y * 32, n = blockIdx.z;
  int tx = threadIdx.x, ty = threadIdx.y;
#pragma unroll
  for (int i = 0; i < 4; ++i) {
    int yy = ty + i * 8;
    tile[yy][tx] = xn[(size_t)((t0 + yy) * 16 + n) * 1024 + k0 + tx];
  }
  __syncthreads();
#pragma unroll
  for (int i = 0; i < 4; ++i) {
    int yy = ty + i * 8;
    rT[(size_t)(k0 + yy) * 16384 + n * 1024 + t0 + tx] = tile[tx][yy];
  }
}

// ------- weight convert+transpose: in (K x N) fp32 -> out (N x K) bf16 -------
__global__ __launch_bounds__(256) void wt_bf16(const float* __restrict__ in,
    __hip_bfloat16* __restrict__ out, int K, int N) {
  __shared__ float tile[32][33];
  int x = threadIdx.x, y0 = threadIdx.y;
  int bn = blockIdx.x * 32;
  int bk = blockIdx.y * 32;
#pragma unroll
  for (int i = 0; i < 4; ++i) {
    int yy = y0 + i * 8;
    tile[yy][x] = in[(size_t)(bk + yy) * N + bn + x];
  }
  __syncthreads();
#pragma unroll
  for (int i = 0; i < 4; ++i) {
    int yy = y0 + i * 8;
    out[(size_t)(bn + yy) * K + bk + x] = __float2bfloat16(tile[x][yy]);
  }
}

// ---- expansion weight prep: w (256 x korig*1024) fp32 ->
// ---- Bt[(d*512+j)*4+k][ck] bf16 (4096 x 256), k>=korig rows zeroed ----------
__global__ void wexp_prep(const float* __restrict__ in,
    __hip_bfloat16* __restrict__ out, int korig) {
  __shared__ float tile[32][33];
  int jt = blockIdx.x;
  int ckt = blockIdx.y;
  int dk = blockIdx.z;
  int d = dk >> 2, k = dk & 3;
  int x = threadIdx.x, y0 = threadIdx.y;
  bool valid = (k < korig);
#pragma unroll
  for (int i = 0; i < 4; ++i) {
    int yy = y0 + i * 8;
    tile[yy][x] = valid
        ? in[(size_t)(ckt * 32 + yy) * (korig * 1024) + (d * korig + k) * 512 +
             jt * 32 + x]
        : 0.f;
  }
  __syncthreads();
#pragma unroll
  for (int i = 0; i < 4; ++i) {
    int yy = y0 + i * 8;
    out[(size_t)((d * 512 + jt * 32 + yy) * 4 + k) * 256 + ckt * 32 + x] =
        __float2bfloat16(tile[x][yy]);
  }
}

// ---- cls_w (1024x30) fp32 -> Wct (32x1024) bf16, rows >=30 zero -------------
__global__ __launch_bounds__(256) void wct_prep(const float* __restrict__ in,
    __hip_bfloat16* __restrict__ out) {
  int i = blockIdx.x * 256 + threadIdx.x;
  int nn = i >> 10, kk = i & 1023;
  out[i] = __float2bfloat16(nn < 30 ? in[kk * 30 + nn] : 0.f);
}

// -------- bf16 MFMA GEMM (m97 structure): C = A(MxK) @ Bt(NxK)^T -------------
__global__ __launch_bounds__(256) void gemm_bf16(const __hip_bfloat16* __restrict__ A,
    const __hip_bfloat16* __restrict__ Bt, __hip_bfloat16* __restrict__ C,
    int M, int N, int K) {
  __shared__ __hip_bfloat16 As[128 * 32];
  __shared__ __hip_bfloat16 Bs[128 * 32];
  const int tid = threadIdx.x;
  const int m0 = blockIdx.y * 128, n0 = blockIdx.x * 128;
  const int lane = tid & 63, wave = tid >> 6;
  const int wm = wave & 1, wn = wave >> 1;
  const int fr = lane & 15, fq = lane >> 4;
  const int srow = lane >> 2, sch = lane & 3;

  const __hip_bfloat16* ga0 = &A[(size_t)(m0 + wave * 32 + srow) * K + sch * 8];
  const __hip_bfloat16* ga1 = ga0 + (size_t)16 * K;
  const __hip_bfloat16* gb0 = &Bt[(size_t)(n0 + wave * 32 + srow) * K + sch * 8];
  const __hip_bfloat16* gb1 = gb0 + (size_t)16 * K;
  __hip_bfloat16* la0 = &As[(wave * 32) * 32];
  __hip_bfloat16* la1 = &As[(wave * 32 + 16) * 32];
  __hip_bfloat16* lb0 = &Bs[(wave * 32) * 32];
  __hip_bfloat16* lb1 = &Bs[(wave * 32 + 16) * 32];

  floatx4 acc[4][4];
#pragma unroll
  for (int i = 0; i < 4; ++i)
#pragma unroll
    for (int j = 0; j < 4; ++j)
      acc[i][j] = (floatx4){0.f, 0.f, 0.f, 0.f};

  for (int k0 = 0; k0 < K; k0 += 32) {
    __syncthreads();
    gl2lds16(ga0 + k0, la0);
    gl2lds16(ga1 + k0, la1);
    gl2lds16(gb0 + k0, lb0);
    gl2lds16(gb1 + k0, lb1);
    __syncthreads();

    short8 af[4], bf_[4];
#pragma unroll
    for (int i = 0; i < 4; ++i) {
      af[i]  = *(const short8*)&As[(wm * 64 + i * 16 + fr) * 32 + fq * 8];
      bf_[i] = *(const short8*)&Bs[(wn * 64 + i * 16 + fr) * 32 + fq * 8];
    }
#pragma unroll
    for (int i = 0; i < 4; ++i)
#pragma unroll
      for (int j = 0; j < 4; ++j)
        acc[i][j] = __builtin_amdgcn_mfma_f32_16x16x32_bf16(af[i], bf_[j],
                                                            acc[i][j], 0, 0, 0);
  }

#pragma unroll
  for (int i = 0; i < 4; ++i)
#pragma unroll
    for (int j = 0; j < 4; ++j)
#pragma unroll
      for (int reg = 0; reg < 4; ++reg) {
        int row = m0 + wm * 64 + i * 16 + fq * 4 + reg;
        int col = n0 + wn * 64 + j * 16 + fr;
        C[(size_t)row * N + col] = __float2bfloat16(acc[i][j][reg]);
      }
}

// ------- skinny classifier GEMM: out[n][t][30] = xnc(16384x1024) @ Wct^T -----
__global__ __launch_bounds__(256) void cls_gemm(const __hip_bfloat16* __restrict__ A,
    const __hip_bfloat16* __restrict__ Wct, float* __restrict__ out) {
  const int tid = threadIdx.x;
  const int lane = tid & 63, wave = tid >> 6;
  const int fr = lane & 15, fq = lane >> 4;
  const int m0 = (blockIdx.x * 4 + wave) * 16;
  floatx4 acc[2];
  acc[0] = (floatx4){0.f, 0.f, 0.f, 0.f};
  acc[1] = (floatx4){0.f, 0.f, 0.f, 0.f};
#pragma unroll 4
  for (int k0 = 0; k0 < 1024; k0 += 32) {
    short8 af = *(const short8*)&A[(size_t)(m0 + fr) * 1024 + k0 + fq * 8];
    short8 b0 = *(const short8*)&Wct[(size_t)fr * 1024 + k0 + fq * 8];
    short8 b1 = *(const short8*)&Wct[(size_t)(16 + fr) * 1024 + k0 + fq * 8];
    acc[0] = __builtin_amdgcn_mfma_f32_16x16x32_bf16(af, b0, acc[0], 0, 0, 0);
    acc[1] = __builtin_amdgcn_mfma_f32_16x16x32_bf16(af, b1, acc[1], 0, 0, 0);
  }
#pragma unroll
  for (int j = 0; j < 2; ++j) {
    int col = j * 16 + fr;
    if (col < 30) {
#pragma unroll
      for (int reg = 0; reg < 4; ++reg) {
        int row = m0 + fq * 4 + reg;
        int t = row >> 4, n = row & 15;
        out[(size_t)n * 30720 + t * 30 + col] = acc[j][reg];
      }
    }
  }
}

// ---------------- SRU bidirectional scan -------------------------------------
template <int K4>
__global__ __launch_bounds__(64) void sru_scan(const __hip_bfloat16* __restrict__ U,
    const __hip_bfloat16* __restrict__ resT, const float* __restrict__ vc,
    const float* __restrict__ bias, __hip_bfloat16* __restrict__ out) {
  int gid = blockIdx.x * 64 + threadIdx.x;
  int j = gid & 511;
  int n = (gid >> 9) & 15;
  int d = gid >> 13;
  const float NL2E = -1.44269504f;
  float vf2 = NL2E * vc[(d * 2 + 0) * 512 + j];
  float vr2 = NL2E * vc[(d * 2 + 1) * 512 + j];
  float bf2 = NL2E * bias[(d * 2 + 0) * 512 + j];
  float br2 = NL2E * bias[(d * 2 + 1) * 512 + j];

  const char* Ub = (const char*)(U + (size_t)n * 4096 + d * 2048) + (size_t)j * 8;
  const char* Rb = K4 ? nullptr
      : (const char*)(resT + (size_t)(d * 512 + j) * 16384 + n * 1024);
  char* Ob = (char*)(out + (size_t)n * 1024 + d * 512) + (size_t)j * 2;
  const int US = d ? -131072 : 131072;
  const int OS = d ? -32768 : 32768;
  int uoff = d ? 1023 * 131072 : 0;
  int ooff = d ? 1023 * 32768 : 0;
  int roff = d ? 2016 : 0;
  const int RS = d ? -32 : 32;

  uint2 B0[16], B1[16], B2[16], B3[16];
  U8 R0[2], R1[2], R2[2], R3[2];
  float c = 0.f;

#define LOADC(UB, RB)                                                     \
  {                                                                       \
    _Pragma("unroll") for (int ss = 0; ss < 16; ++ss) {                   \
      UB[ss] = *(const uint2*)(Ub + uoff);                                \
      uoff += US;                                                         \
    }                                                                     \
    if (!K4) {                                                            \
      RB[0].u = *(const uint4*)(Rb + roff);                               \
      RB[1].u = *(const uint4*)(Rb + roff + 16);                          \
      roff += RS;                                                         \
    }                                                                     \
  }

#define COMPC(UB, RB)                                                     \
  {                                                                       \
    _Pragma("unroll") for (int ss = 0; ss < 16; ++ss) {                   \
      uint2 uv = UB[ss];                                                  \
      float a0 = b2f_lo(uv.x), a1 = b2f_hi(uv.x), a2 = b2f_lo(uv.y);      \
      float rx;                                                           \
      if (K4) {                                                           \
        rx = b2f_hi(uv.y);                                                \
      } else {                                                            \
        __hip_bfloat16 rf = RB[ss >> 3].h[ss & 7];                        \
        __hip_bfloat16 rr = RB[(15 - ss) >> 3].h[(15 - ss) & 7];          \
        rx = __bfloat162float(d ? rr : rf);                               \
      }                                                                   \
      float A1 = fmaf(a1, NL2E, bf2);                                     \
      float f = frcp_(1.f + fexp2_(fmaf(vf2, c, A1)));                    \
      float c2 = fmaf(f, c - a0, a0);                                     \
      float A2 = fmaf(a2, NL2E, br2);                                     \
      float r = frcp_(1.f + fexp2_(fmaf(vr2, c2, A2)));                   \
      float y = fmaf(r, c2 - rx, rx);                                     \
      *(__hip_bfloat16*)(Ob + ooff) = __float2bfloat16(y);                \
      ooff += OS;                                                         \
      c = c2;                                                             \
    }                                                                     \
  }

  LOADC(B0, R0);
  LOADC(B1, R1);
  LOADC(B2, R2);
  for (int cb = 0; cb < 64; cb += 4) {
    LOADC(B3, R3);
    COMPC(B0, R0);
    if (cb + 4 < 64) LOADC(B0, R0);
    COMPC(B1, R1);
    if (cb + 5 < 64) LOADC(B1, R1);
    COMPC(B2, R2);
    if (cb + 6 < 64) LOADC(B2, R2);
    COMPC(B3, R3);
  }
#undef LOADC
#undef COMPC
}

extern "C" void kernel_launch(void* const* d_in, const int* in_sizes, int n_in,
                              void* d_out, int out_size, void* d_ws, size_t ws_size,
                              hipStream_t stream) {
  const float* x        = (const float*)d_in[0];
  const float* conv0_w  = (const float*)d_in[1];
  const float* conv0_b  = (const float*)d_in[2];
  const float* rconv1_w = (const float*)d_in[3];
  const float* rconv1_b = (const float*)d_in[4];
  const float* rbn1_g   = (const float*)d_in[5];
  const float* rbn1_b   = (const float*)d_in[6];
  const float* rbn1_m   = (const float*)d_in[7];
  const float* rbn1_v   = (const float*)d_in[8];
  const float* rconv2_w = (const float*)d_in[9];
  const float* rconv2_b = (const float*)d_in[10];
  const float* rbn2_g   = (const float*)d_in[11];
  const float* rbn2_b   = (const float*)d_in[12];
  const float* rbn2_m   = (const float*)d_in[13];
  const float* rbn2_v   = (const float*)d_in[14];
  const float* ln0_g    = (const float*)d_in[15];
  const float* ln0_b    = (const float*)d_in[16];
  const float* wproj0   = (const float*)d_in[17];
  const float* w0       = (const float*)d_in[18];
  const float* vc0      = (const float*)d_in[19];
  const float* bias0    = (const float*)d_in[20];
  const float* ln_g     = (const float*)d_in[21];
  const float* ln_b     = (const float*)d_in[22];
  const float* wproj    = (const float*)d_in[23];
  const float* w        = (const float*)d_in[24];
  const float* vc       = (const float*)d_in[25];
  const float* bias     = (const float*)d_in[26];
  const float* cln_g    = (const float*)d_in[27];
  const float* cln_b    = (const float*)d_in[28];
  const float* cls_w    = (const float*)d_in[29];
  float* out = (float*)d_out;

  // Two 128 MiB arenas.
  float* Af = (float*)d_ws;
  float* Bf = Af + 33554432;
  __hip_bfloat16* Ah = (__hip_bfloat16*)Af;
  __hip_bfloat16* Bh = (__hip_bfloat16*)Bf;

  __hip_bfloat16* hA   = Ah;                   // NHWC h (67 MB)
  __hip_bfloat16* hB   = Bh;                   // NHWC temp
  __hip_bfloat16* wt1h = Ah + 62914560;        // 18 KB @ A+120MB
  __hip_bfloat16* wt2h = Ah + 62931952;        // next 18 KB

  conv_stem_nhwc<<<dim3(64, 16), 256, 0, stream>>>(x, conv0_w, conv0_b, hA);
  for (int i = 0; i < 3; ++i) {
    wtap_conv<<<36, 256, 0, stream>>>(rconv1_w + i * 9216, wt1h);
    conv_mfma<0><<<dim3(8, 16, 16), 256, 0, stream>>>(hA, wt1h,
        rconv1_b + i * 32, rbn1_g + i * 32, rbn1_b + i * 32,
        rbn1_m + i * 32, rbn1_v + i * 32, hB);
    wtap_conv<<<36, 256, 0, stream>>>(rconv2_w + i * 9216, wt2h);
    conv_mfma<1><<<dim3(8, 16, 16), 256, 0, stream>>>(hB, wt2h,
        rconv2_b + i * 32, rbn2_g + i * 32, rbn2_b + i * 32,
        rbn2_m + i * 32, rbn2_v + i * 32, hA);
  }

  // ---- SRU layer 0 (k=4, F=2048) ----
  __hip_bfloat16* xn0  = Bh;                   // 64 MB (hB dead)
  __hip_bfloat16* Wp0t = Ah + 52428800;        // 1 MB @ A+100MB
  __hip_bfloat16* tmp0 = Bh + 50331648;        // 8 MB @ B+96MB
  __hip_bfloat16* W0p  = Bh + 57671680;        // 2 MB @ B+110MB
  __hip_bfloat16* U    = Ah;                   // 128 MB (rows = 4096)
  __hip_bfloat16* s2h  = Bh;                   // 32 MB bf16

  ln_nhwc<<<16384, 256, 0, stream>>>(hA, ln0_g, ln0_b, xn0);
  wt_perm0<<<2048, 256, 0, stream>>>(wproj0, Wp0t);
  gemm_bf16<<<dim3(2, 128), 256, 0, stream>>>(xn0, Wp0t, tmp0, 16384, 256, 2048);
  wexp_prep<<<dim3(16, 8, 8), dim3(32, 8), 0, stream>>>(w0, W0p, 4);
  gemm_bf16<<<dim3(32, 128), 256, 0, stream>>>(tmp0, W0p, U, 16384, 4096, 256);
  sru_scan<1><<<256, 64, 0, stream>>>(U, nullptr, vc0, bias0, s2h);

  // ---- SRU layers 1..3 (k=3 padded to 4, F=1024) ----
  __hip_bfloat16* xn3  = Bh + 33554432;        // 32 MB @ B+64MB
  __hip_bfloat16* resT = Bh + 16777216;        // 32 MB @ B+32MB
  __hip_bfloat16* tmp3 = Bh + 50331648;        // 8 MB @ B+96MB
  __hip_bfloat16* W3p  = Bh + 54525952;        // 2 MB @ B+104MB
  __hip_bfloat16* Wpt3 = Bh + 55574528;        // 0.5 MB @ B+106MB
  for (int i = 0; i < 3; ++i) {
    ln_rows_h<<<16384, 256, 0, stream>>>(s2h, ln_g + i * 1024, ln_b + i * 1024, xn3);
    resT_pack<<<dim3(32, 32, 16), dim3(32, 8), 0, stream>>>(xn3, resT);
    wt_bf16<<<dim3(8, 32), dim3(32, 8), 0, stream>>>(wproj + i * 262144, Wpt3,
                                                     1024, 256);
    gemm_bf16<<<dim3(2, 128), 256, 0, stream>>>(xn3, Wpt3, tmp3, 16384, 256, 1024);
    wexp_prep<<<dim3(16, 8, 8), dim3(32, 8), 0, stream>>>(w + i * 786432, W3p, 3);
    gemm_bf16<<<dim3(32, 128), 256, 0, stream>>>(tmp3, W3p, U, 16384, 4096, 256);
    sru_scan<0><<<256, 64, 0, stream>>>(U, resT, vc + i * 2048, bias + i * 2048, s2h);
  }

  // ---- final LN + classifier (skinny MFMA GEMM) ----
  __hip_bfloat16* xnc = Bh + 16777216;         // 32 MB @ B+32MB (resT dead)
  __hip_bfloat16* Wct = Ah;                    // 64 KB (U dead)
  ln_rows_h<<<16384, 256, 0, stream>>>(s2h, cln_g, cln_b, xnc);
  wct_prep<<<128, 256, 0, stream>>>(cls_w, Wct);
  cls_gemm<<<256, 256, 0, stream>>>(xnc, Wct, out);
}